// Round 1
// 1115.147 us; speedup vs baseline: 2.1542x; 2.1542x over previous
//
#include <hip/hip_runtime.h>
#include <hip/hip_bf16.h>
#include <math.h>

// Problem constants
#define B_    2
#define T_    1024
#define D_    4096
#define H_    32
#define KVH_  8
#define HD_   128
#define GROUP_ 4

static constexpr float SCORE_SCALE = 0.08838834764831845f; // 1/sqrt(128)

typedef __bf16 bf16x8 __attribute__((ext_vector_type(8)));
typedef float  f32x4  __attribute__((ext_vector_type(4)));
typedef unsigned short u16;

__device__ inline float toF(const __hip_bfloat16 v) { return __bfloat162float(v); }
__device__ inline float toF(const float v)          { return v; }

__device__ inline void storeC(float* p, float v)          { *p = v; }
__device__ inline void storeC(__hip_bfloat16* p, float v) { *p = __float2bfloat16(v); }

// fp32 -> bf16 bit pattern, round-to-nearest-even (finite inputs)
__device__ inline unsigned short f2bf(float f) {
    union { float f; unsigned u; } v; v.f = f;
    unsigned r = v.u + 0x7FFFu + ((v.u >> 16) & 1u);
    return (unsigned short)(r >> 16);
}

// ===========================================================================
// NEW FAST PATH
// ===========================================================================

// ---------------------------------------------------------------------------
// Linear fp32 -> bf16 convert (8 elems/thread, float4 in, int4 out)
// ---------------------------------------------------------------------------
__global__ __launch_bounds__(256) void lconv(const float* __restrict__ S,
                                             u16* __restrict__ D, int n8) {
    int i = blockIdx.x * 256 + threadIdx.x;
    if (i >= n8) return;
    const float4 a = *(const float4*)(S + (size_t)i * 8);
    const float4 b = *(const float4*)(S + (size_t)i * 8 + 4);
    union { int4 v; u16 u[8]; } t;
    t.u[0] = f2bf(a.x); t.u[1] = f2bf(a.y); t.u[2] = f2bf(a.z); t.u[3] = f2bf(a.w);
    t.u[4] = f2bf(b.x); t.u[5] = f2bf(b.y); t.u[6] = f2bf(b.z); t.u[7] = f2bf(b.w);
    *(int4*)(D + (size_t)i * 8) = t.v;
}

// ---------------------------------------------------------------------------
// Transpose + convert: src fp32 [R][Cc] row-major -> dst bf16 [Cc][R].
// 64x64 tiles via LDS; coalesced read (float4) and coalesced write (int4).
// DUAL: blockIdx.z picks (S0,D0)/(S1,D1).
// ---------------------------------------------------------------------------
template <bool DUAL>
__global__ __launch_bounds__(256) void tconv(const float* __restrict__ S0,
                                             u16* __restrict__ D0,
                                             const float* __restrict__ S1,
                                             u16* __restrict__ D1,
                                             int R, int Cc) {
    const float* __restrict__ S = (DUAL && blockIdx.z) ? S1 : S0;
    u16* __restrict__ D         = (DUAL && blockIdx.z) ? D1 : D0;
    __shared__ u16 Tt[64][72];
    const int tid = threadIdx.x;
    const int r0 = blockIdx.y * 64, c0 = blockIdx.x * 64;
    {
        const int rr = tid >> 4, cc4 = (tid & 15) * 4;
#pragma unroll
        for (int e = 0; e < 4; ++e) {
            const int row = rr + e * 16;
            float4 v = *(const float4*)(S + (size_t)(r0 + row) * Cc + c0 + cc4);
            union { int2 w; u16 u[4]; } t;
            t.u[0] = f2bf(v.x); t.u[1] = f2bf(v.y); t.u[2] = f2bf(v.z); t.u[3] = f2bf(v.w);
            *(int2*)&Tt[row][cc4] = t.w;
        }
    }
    __syncthreads();
    {
        const int cc = tid >> 2, r8 = (tid & 3) * 8;
#pragma unroll
        for (int e = 0; e < 2; ++e) {
            const int rb = r8 + e * 32;
            union { int4 v; u16 u[8]; } t;
#pragma unroll
            for (int j = 0; j < 8; ++j) t.u[j] = Tt[rb + j][cc];
            *(int4*)(D + (size_t)(c0 + cc) * R + r0 + rb) = t.v;
        }
    }
}

// ---------------------------------------------------------------------------
// bf16 GEMM: C[M,N] = A[M,K] @ Bt[N,K]^T  (Bt = pre-transposed weights).
// BM=BN=128, BK=64, 4 waves x (64x64 as 4x4 mfma_f32_16x16x32_bf16).
// Reg-prefetch double buffer: next K-tile loaded to regs during MFMA block.
// LDS stride 72 ushorts: frag ds_read_b128 and staging ds_write_b128 are
// distribution-uniform across banks (no above-minimum conflicts).
// DUAL/TRC1 as in the legacy kernel (TRC1 stores C1 transposed -> V^T).
// ---------------------------------------------------------------------------
#define GSTR 72

template <typename TC, bool DUAL, bool TRC1>
__global__ __launch_bounds__(256) void gemm_bf16(const u16* __restrict__ A,
                                                 const u16* __restrict__ Bt0,
                                                 TC* __restrict__ C0,
                                                 const u16* __restrict__ Bt1,
                                                 TC* __restrict__ C1,
                                                 int M, int N, int K) {
    const u16* __restrict__ Bt = (DUAL && blockIdx.z) ? Bt1 : Bt0;
    TC* __restrict__ C         = (DUAL && blockIdx.z) ? C1 : C0;

    __shared__ u16 As[128 * GSTR];
    __shared__ u16 Bs[128 * GSTR];

    const int tid   = threadIdx.x;
    const int lane  = tid & 63;
    const int wvv   = tid >> 6;
    const int waveM = wvv >> 1;
    const int waveN = wvv & 1;
    const int lm    = lane & 15;
    const int quad  = lane >> 4;
    const int bm    = blockIdx.y * 128;
    const int bn    = blockIdx.x * 128;

    // staging coords: thread covers rows sr, sr+32, sr+64, sr+96; 16B in k
    const int sr = tid >> 3;
    const int sc = (tid & 7) * 8;

    const u16* ap = A  + (size_t)(bm + sr) * K + sc;
    const u16* bp = Bt + (size_t)(bn + sr) * K + sc;
    const size_t rstep = (size_t)32 * K;

    f32x4 acc[4][4];
#pragma unroll
    for (int i = 0; i < 4; ++i)
#pragma unroll
        for (int j = 0; j < 4; ++j) acc[i][j] = (f32x4){0.f, 0.f, 0.f, 0.f};

    int4 pa[4], pb[4];
#pragma unroll
    for (int e = 0; e < 4; ++e) {
        pa[e] = *(const int4*)(ap + e * rstep);
        pb[e] = *(const int4*)(bp + e * rstep);
    }
#pragma unroll
    for (int e = 0; e < 4; ++e) {
        *(int4*)&As[(sr + e * 32) * GSTR + sc] = pa[e];
        *(int4*)&Bs[(sr + e * 32) * GSTR + sc] = pb[e];
    }
    __syncthreads();

    for (int k0 = 64; ; k0 += 64) {
        const bool more = (k0 < K);
        if (more) {
#pragma unroll
            for (int e = 0; e < 4; ++e) {
                pa[e] = *(const int4*)(ap + k0 + e * rstep);
                pb[e] = *(const int4*)(bp + k0 + e * rstep);
            }
        }
#pragma unroll
        for (int ks = 0; ks < 2; ++ks) {
            bf16x8 af[4], bfv[4];
#pragma unroll
            for (int i = 0; i < 4; ++i)
                af[i] = *(const bf16x8*)&As[(waveM * 64 + i * 16 + lm) * GSTR + ks * 32 + quad * 8];
#pragma unroll
            for (int j = 0; j < 4; ++j)
                bfv[j] = *(const bf16x8*)&Bs[(waveN * 64 + j * 16 + lm) * GSTR + ks * 32 + quad * 8];
#pragma unroll
            for (int i = 0; i < 4; ++i)
#pragma unroll
                for (int j = 0; j < 4; ++j)
                    acc[i][j] = __builtin_amdgcn_mfma_f32_16x16x32_bf16(af[i], bfv[j], acc[i][j], 0, 0, 0);
        }
        if (!more) break;
        __syncthreads();
#pragma unroll
        for (int e = 0; e < 4; ++e) {
            *(int4*)&As[(sr + e * 32) * GSTR + sc] = pa[e];
            *(int4*)&Bs[(sr + e * 32) * GSTR + sc] = pb[e];
        }
        __syncthreads();
    }

    // C/D layout: col = lane&15, row = quad*4 + reg  [m89-verified]
    if (TRC1 && DUAL && blockIdx.z) {
#pragma unroll
        for (int i = 0; i < 4; ++i) {
            int row0 = bm + waveM * 64 + i * 16 + quad * 4;
#pragma unroll
            for (int j = 0; j < 4; ++j) {
                int col = bn + waveN * 64 + j * 16 + lm;
#pragma unroll
                for (int rr = 0; rr < 4; ++rr)
                    storeC(&C[(size_t)col * M + row0 + rr], acc[i][j][rr]);
            }
        }
    } else {
#pragma unroll
        for (int i = 0; i < 4; ++i) {
            int row0 = bm + waveM * 64 + i * 16 + quad * 4;
#pragma unroll
            for (int j = 0; j < 4; ++j) {
                int col = bn + waveN * 64 + j * 16 + lm;
#pragma unroll
                for (int rr = 0; rr < 4; ++rr)
                    storeC(&C[(size_t)(row0 + rr) * N + col], acc[i][j][rr]);
            }
        }
    }
}

// ===========================================================================
// LEGACY (fallback) GEMM — fused fp32->bf16 conversion, verbatim from the
// previous verified kernel. Used when ws_size < 56 MiB.
// ===========================================================================
#define LSTR 40

template <typename TA, typename TB, typename TC, bool DUAL, bool TRC1>
__global__ __launch_bounds__(256) void gemm_mfma(const TA* __restrict__ A,
                                                 const TB* __restrict__ B0,
                                                 TC* __restrict__ C0,
                                                 const TB* __restrict__ B1,
                                                 TC* __restrict__ C1,
                                                 int M, int N, int K) {
    const TB* __restrict__ B = (DUAL && blockIdx.z) ? B1 : B0;
    TC* __restrict__ C       = (DUAL && blockIdx.z) ? C1 : C0;

    __shared__ unsigned short As[128 * LSTR];
    __shared__ unsigned short Bs[128 * LSTR];

    const int tid   = threadIdx.x;
    const int lane  = tid & 63;
    const int wv    = tid >> 6;
    const int waveM = wv >> 1;
    const int waveN = wv & 1;
    const int lm    = lane & 15;
    const int quad  = lane >> 4;
    const int bm    = blockIdx.y * 128;
    const int bn    = blockIdx.x * 128;

    f32x4 acc[4][4];
#pragma unroll
    for (int i = 0; i < 4; ++i)
#pragma unroll
        for (int j = 0; j < 4; ++j) acc[i][j] = (f32x4){0.f, 0.f, 0.f, 0.f};

    for (int k0 = 0; k0 < K; k0 += 32) {
#pragma unroll
        for (int e = 0; e < 8; ++e) {
            int p  = tid + e * 256;
            int r  = p >> 4, c2 = (p & 15) * 2;
            const TA* ap = A + (size_t)(bm + r) * K + k0 + c2;
            ushort2 t;
            t.x = f2bf(toF(ap[0]));
            t.y = f2bf(toF(ap[1]));
            *(ushort2*)&As[r * LSTR + c2] = t;
        }
#pragma unroll
        for (int e = 0; e < 8; ++e) {
            int p  = tid + e * 256;
            int n  = p & 127, k2 = (p >> 7) * 2;
            const TB* bp = B + (size_t)(k0 + k2) * N + bn + n;
            ushort2 t;
            t.x = f2bf(toF(bp[0]));
            t.y = f2bf(toF(bp[N]));
            *(ushort2*)&Bs[n * LSTR + k2] = t;
        }
        __syncthreads();

        bf16x8 af[4], bfr[4];
#pragma unroll
        for (int i = 0; i < 4; ++i)
            af[i] = *(const bf16x8*)&As[(waveM * 64 + i * 16 + lm) * LSTR + quad * 8];
#pragma unroll
        for (int j = 0; j < 4; ++j)
            bfr[j] = *(const bf16x8*)&Bs[(waveN * 64 + j * 16 + lm) * LSTR + quad * 8];
#pragma unroll
        for (int i = 0; i < 4; ++i)
#pragma unroll
            for (int j = 0; j < 4; ++j)
                acc[i][j] = __builtin_amdgcn_mfma_f32_16x16x32_bf16(af[i], bfr[j], acc[i][j], 0, 0, 0);
        __syncthreads();
    }

    if (TRC1 && DUAL && blockIdx.z) {
#pragma unroll
        for (int i = 0; i < 4; ++i) {
            int row0 = bm + waveM * 64 + i * 16 + quad * 4;
#pragma unroll
            for (int j = 0; j < 4; ++j) {
                int col = bn + waveN * 64 + j * 16 + lm;
#pragma unroll
                for (int rr = 0; rr < 4; ++rr)
                    storeC(&C[(size_t)col * M + row0 + rr], acc[i][j][rr]);
            }
        }
    } else {
#pragma unroll
        for (int i = 0; i < 4; ++i) {
            int row0 = bm + waveM * 64 + i * 16 + quad * 4;
#pragma unroll
            for (int j = 0; j < 4; ++j) {
                int col = bn + waveN * 64 + j * 16 + lm;
#pragma unroll
                for (int rr = 0; rr < 4; ++rr)
                    storeC(&C[(size_t)(row0 + rr) * N + col], acc[i][j][rr]);
            }
        }
    }
}

// ---------------------------------------------------------------------------
// RoPE in-place on Q (fp32, [token][H*HD]) and K (bf16, [token][KVH*HD]).
// ---------------------------------------------------------------------------
template <typename TQ, typename TK>
__global__ __launch_bounds__(256) void rope_kernel(TQ* __restrict__ Q,
                                                   TK* __restrict__ Kt,
                                                   const int* __restrict__ start_pos) {
    int w    = blockIdx.x * 4 + (threadIdx.x >> 6);
    int lane = threadIdx.x & 63;
    int hh = w % (H_ + KVH_);
    int n  = w / (H_ + KVH_);
    int t  = n % T_;
    int pos = *start_pos + t;

    int e0 = 2 * lane, e1 = 2 * lane + 1;
    int j0 = e0 & 63,  j1 = e1 & 63;
    const double LN_BASE = 9.210340371976184; // ln(10000)
    double a0 = (double)pos * exp(-((double)(2 * j0) / 128.0) * LN_BASE);
    double a1 = (double)pos * exp(-((double)(2 * j1) / 128.0) * LN_BASE);
    float c0 = (float)cos(a0), s0 = (float)sin(a0);
    float c1 = (float)cos(a1), s1 = (float)sin(a1);

    if (hh < H_) {
        TQ* base = Q + (size_t)n * (H_ * HD_) + hh * HD_;
        float x0 = toF(base[e0]), x1 = toF(base[e1]);
        storeC(&base[e0], x0 * c0 - x1 * s0);
        storeC(&base[e1], x1 * c1 + x0 * s1);
    } else {
        TK* base = Kt + (size_t)n * (KVH_ * HD_) + (hh - H_) * HD_;
        float x0 = toF(base[e0]), x1 = toF(base[e1]);
        storeC(&base[e0], x0 * c0 - x1 * s0);
        storeC(&base[e1], x1 * c1 + x0 * s1);
    }
}

// ---------------------------------------------------------------------------
// Flash attention (causal, GQA) — unchanged from the verified kernel.
// ---------------------------------------------------------------------------
#define KSTR 136
#define VSTR 72
#define PSTR 72

__global__ __launch_bounds__(256, 2) void flash_attn(
        const float* __restrict__ Q,
        const __hip_bfloat16* __restrict__ K,
        const __hip_bfloat16* __restrict__ Vt,
        __hip_bfloat16* __restrict__ AO) {
    __shared__ unsigned short Ks[64 * KSTR];
    __shared__ unsigned short Vs[128 * VSTR];
    __shared__ unsigned short Ps[4][32 * PSTR];

    const int tid  = threadIdx.x;
    const int lane = tid & 63;
    const int w    = tid >> 6;
    const int quad = lane >> 4;
    const int lm   = lane & 15;

    const int qb  = blockIdx.x * 128;
    const int h   = blockIdx.y;
    const int b   = blockIdx.z;
    const int kvh = h >> 2;

    const int qw = qb + w * 32;

    bf16x8 qf[2][4];
#pragma unroll
    for (int mt = 0; mt < 2; ++mt) {
        const float* qrow = Q + (size_t)(b * T_ + qw + mt * 16 + lm) * (H_ * HD_) + h * HD_;
#pragma unroll
        for (int ks = 0; ks < 4; ++ks) {
            const float* p4 = qrow + ks * 32 + quad * 8;
            float4 f0 = *(const float4*)(p4);
            float4 f1 = *(const float4*)(p4 + 4);
            union { bf16x8 v; unsigned short u[8]; } t;
            t.u[0] = f2bf(f0.x * SCORE_SCALE); t.u[1] = f2bf(f0.y * SCORE_SCALE);
            t.u[2] = f2bf(f0.z * SCORE_SCALE); t.u[3] = f2bf(f0.w * SCORE_SCALE);
            t.u[4] = f2bf(f1.x * SCORE_SCALE); t.u[5] = f2bf(f1.y * SCORE_SCALE);
            t.u[6] = f2bf(f1.z * SCORE_SCALE); t.u[7] = f2bf(f1.w * SCORE_SCALE);
            qf[mt][ks] = t.v;
        }
    }

    float mI[2][4], lI[2][4];
    f32x4 o[2][8];
#pragma unroll
    for (int mt = 0; mt < 2; ++mt) {
#pragma unroll
        for (int rr = 0; rr < 4; ++rr) { mI[mt][rr] = -1e30f; lI[mt][rr] = 0.f; }
#pragma unroll
        for (int dc = 0; dc < 8; ++dc) o[mt][dc] = (f32x4){0.f, 0.f, 0.f, 0.f};
    }

    const int nkt  = (qb + 128) / 64;
    const int qmax = qw + 31;

    for (int kt = 0; kt < nkt; ++kt) {
        const int t0 = kt * 64;
#pragma unroll
        for (int e = 0; e < 4; ++e) {
            int p = tid + e * 256;
            int tt = p >> 4, d0 = (p & 15) * 8;
            int4 v = *(const int4*)(K + (size_t)(b * T_ + t0 + tt) * (KVH_ * HD_) + kvh * HD_ + d0);
            *(int4*)&Ks[tt * KSTR + d0] = v;
        }
#pragma unroll
        for (int e = 0; e < 4; ++e) {
            int p = tid + e * 256;
            int d = p >> 3, tm = (p & 7) * 8;
            int4 v = *(const int4*)(Vt + (size_t)(kvh * HD_ + d) * (B_ * T_) + b * T_ + t0 + tm);
            *(int4*)&Vs[d * VSTR + tm] = v;
        }
        __syncthreads();

        if (t0 <= qmax) {
            f32x4 s[2][4];
#pragma unroll
            for (int mt = 0; mt < 2; ++mt)
#pragma unroll
                for (int tc = 0; tc < 4; ++tc) s[mt][tc] = (f32x4){0.f, 0.f, 0.f, 0.f};
#pragma unroll
            for (int ks = 0; ks < 4; ++ks) {
                bf16x8 kf[4];
#pragma unroll
                for (int tc = 0; tc < 4; ++tc)
                    kf[tc] = *(const bf16x8*)&Ks[(tc * 16 + lm) * KSTR + ks * 32 + quad * 8];
#pragma unroll
                for (int mt = 0; mt < 2; ++mt)
#pragma unroll
                    for (int tc = 0; tc < 4; ++tc)
                        s[mt][tc] = __builtin_amdgcn_mfma_f32_16x16x32_bf16(qf[mt][ks], kf[tc], s[mt][tc], 0, 0, 0);
            }

            if (t0 + 63 > qw) {
#pragma unroll
                for (int mt = 0; mt < 2; ++mt) {
                    int qrow = qw + mt * 16 + quad * 4;
#pragma unroll
                    for (int tc = 0; tc < 4; ++tc) {
                        int tcol = t0 + tc * 16 + lm;
#pragma unroll
                        for (int rr = 0; rr < 4; ++rr)
                            if (tcol > qrow + rr) s[mt][tc][rr] = -1e30f;
                    }
                }
            }

#pragma unroll
            for (int mt = 0; mt < 2; ++mt) {
#pragma unroll
                for (int rr = 0; rr < 4; ++rr) {
                    float tmx = fmaxf(fmaxf(s[mt][0][rr], s[mt][1][rr]),
                                      fmaxf(s[mt][2][rr], s[mt][3][rr]));
#pragma unroll
                    for (int off = 8; off >= 1; off >>= 1)
                        tmx = fmaxf(tmx, __shfl_xor(tmx, off, 64));
                    float mn    = fmaxf(mI[mt][rr], tmx);
                    float alpha = __expf(mI[mt][rr] - mn);
                    mI[mt][rr]  = mn;
                    float rs = 0.f;
#pragma unroll
                    for (int tc = 0; tc < 4; ++tc) {
                        float p = __expf(s[mt][tc][rr] - mn);
                        s[mt][tc][rr] = p;
                        rs += p;
                    }
#pragma unroll
                    for (int off = 8; off >= 1; off >>= 1)
                        rs += __shfl_xor(rs, off, 64);
                    lI[mt][rr] = lI[mt][rr] * alpha + rs;
#pragma unroll
                    for (int dc = 0; dc < 8; ++dc)
                        o[mt][dc][rr] *= alpha;
                }
            }

#pragma unroll
            for (int mt = 0; mt < 2; ++mt)
#pragma unroll
                for (int tc = 0; tc < 4; ++tc)
#pragma unroll
                    for (int rr = 0; rr < 4; ++rr)
                        Ps[w][(mt * 16 + quad * 4 + rr) * PSTR + tc * 16 + lm] = f2bf(s[mt][tc][rr]);

#pragma unroll
            for (int ss = 0; ss < 2; ++ss) {
                bf16x8 pf[2];
#pragma unroll
                for (int mt = 0; mt < 2; ++mt)
                    pf[mt] = *(const bf16x8*)&Ps[w][(mt * 16 + lm) * PSTR + ss * 32 + quad * 8];
#pragma unroll
                for (int dc = 0; dc < 8; ++dc) {
                    bf16x8 vf = *(const bf16x8*)&Vs[(dc * 16 + lm) * VSTR + ss * 32 + quad * 8];
#pragma unroll
                    for (int mt = 0; mt < 2; ++mt)
                        o[mt][dc] = __builtin_amdgcn_mfma_f32_16x16x32_bf16(pf[mt], vf, o[mt][dc], 0, 0, 0);
                }
            }
        }
        __syncthreads();
    }

#pragma unroll
    for (int mt = 0; mt < 2; ++mt) {
#pragma unroll
        for (int rr = 0; rr < 4; ++rr) {
            float inv = 1.f / lI[mt][rr];
            size_t row = (size_t)(b * T_ + qw + mt * 16 + quad * 4 + rr) * (H_ * HD_) + h * HD_;
#pragma unroll
            for (int dc = 0; dc < 8; ++dc)
                AO[row + dc * 16 + lm] = __float2bfloat16(o[mt][dc][rr] * inv);
        }
    }
}

// ---------------------------------------------------------------------------
extern "C" void kernel_launch(void* const* d_in, const int* in_sizes, int n_in,
                              void* d_out, int out_size, void* d_ws, size_t ws_size,
                              hipStream_t stream) {
    const float* x  = (const float*)d_in[0];
    const float* wq = (const float*)d_in[1];
    const float* wk = (const float*)d_in[2];
    const float* wv = (const float*)d_in[3];
    const float* wo = (const float*)d_in[4];
    const int* start_pos = (const int*)d_in[5];
    float* out = (float*)d_out;

    dim3 blk(256);
    const int M   = B_ * T_;      // 2048
    const int NQ  = H_ * HD_;     // 4096
    const int NKV = KVH_ * HD_;   // 1024

    // Fast path needs: Kb(4MiB) Vtb(4MiB) [xb->AOb](16MiB) [wqb->wkb+wvb->wob](32MiB)
    const size_t NEED = 58720256; // 56 MiB

    if (ws_size >= NEED) {
        char* w = (char*)d_ws;
        __hip_bfloat16* Kb  = (__hip_bfloat16*)(w);                     // [2048][1024]
        __hip_bfloat16* Vtb = (__hip_bfloat16*)(w + (4u  << 20));       // [1024][2048]
        u16*            xb  = (u16*)(w + (8u  << 20));                  // [2048][4096]
        __hip_bfloat16* AOb = (__hip_bfloat16*)(w + (8u  << 20));       // reuses xb slot
        u16*            wS  = (u16*)(w + (24u << 20));                  // 32 MiB shared slot
        u16* wqb = wS;                       // [4096][4096] transposed
        u16* wkb = wS;                       // [1024][4096] transposed
        u16* wvb = wS + (size_t)NKV * D_;    // [1024][4096] transposed
        u16* wob = wS;                       // [4096][4096] transposed
        float* Qf = out;                     // Q fp32 in d_out (dead before out-proj)

        // 1. x -> bf16
        lconv<<<(M * D_ / 8 + 255) / 256, blk, 0, stream>>>(x, xb, M * D_ / 8);
        // 2. wq -> bf16 transposed
        tconv<false><<<dim3(NQ / 64, D_ / 64, 1), blk, 0, stream>>>(wq, wqb, nullptr, nullptr, D_, NQ);
        // 3. Q projection: 2048x4096x4096 -> fp32 Qf
        gemm_bf16<float, false, false>
            <<<dim3(NQ / 128, M / 128, 1), blk, 0, stream>>>(xb, wqb, Qf, nullptr, nullptr, M, NQ, D_);
        // 4. wk, wv -> bf16 transposed (wqb slot now dead)
        tconv<true><<<dim3(NKV / 64, D_ / 64, 2), blk, 0, stream>>>(wk, wkb, wv, wvb, D_, NKV);
        // 5. K and V projections fused; V stored transposed
        gemm_bf16<__hip_bfloat16, true, true>
            <<<dim3(NKV / 128, M / 128, 2), blk, 0, stream>>>(xb, wkb, Kb, wvb, Vtb, M, NKV, D_);
        // 6. RoPE on Q and K
        rope_kernel<<<(M * (H_ + KVH_)) / 4, blk, 0, stream>>>(Qf, Kb, start_pos);
        // 7. wo -> bf16 transposed (wkb/wvb dead)
        tconv<false><<<dim3(NQ / 64, NQ / 64, 1), blk, 0, stream>>>(wo, wob, nullptr, nullptr, NQ, D_);
        // 8. Flash attention -> AOb (xb slot now dead)
        flash_attn<<<dim3(T_ / 128, H_, B_), blk, 0, stream>>>(Qf, Kb, Vtb, AOb);
        // 9. Output projection -> fp32 out
        gemm_bf16<float, false, false>
            <<<dim3(D_ / 128, M / 128, 1), blk, 0, stream>>>((const u16*)AOb, wob, out, nullptr, nullptr, M, D_, NQ);
    } else {
        // ------- legacy fallback (previous verified path, 24 MiB ws) -------
        float* Qf           = out;
        __hip_bfloat16* Kb  = (__hip_bfloat16*)d_ws;
        __hip_bfloat16* Vtb = Kb + (size_t)B_ * T_ * KVH_ * HD_;
        __hip_bfloat16* AOb = Vtb + (size_t)B_ * T_ * KVH_ * HD_;

        gemm_mfma<float, float, float, false, false>
            <<<dim3(NQ / 128, M / 128, 1), blk, 0, stream>>>(x, wq, Qf, nullptr, nullptr, M, NQ, D_);
        gemm_mfma<float, float, __hip_bfloat16, true, true>
            <<<dim3(NKV / 128, M / 128, 2), blk, 0, stream>>>(x, wk, Kb, wv, Vtb, M, NKV, D_);
        rope_kernel<<<(M * (H_ + KVH_)) / 4, blk, 0, stream>>>(Qf, Kb, start_pos);
        flash_attn<<<dim3(T_ / 128, H_, B_), blk, 0, stream>>>(Qf, Kb, Vtb, AOb);
        gemm_mfma<__hip_bfloat16, float, float, false, false>
            <<<dim3(D_ / 128, M / 128, 1), blk, 0, stream>>>(AOb, wo, out, nullptr, nullptr, M, D_, NQ);
    }
}

// Round 2
// 607.866 us; speedup vs baseline: 3.9520x; 1.8345x over previous
//
#include <hip/hip_runtime.h>
#include <hip/hip_bf16.h>
#include <math.h>

// Problem constants
#define B_    2
#define T_    1024
#define D_    4096
#define H_    32
#define KVH_  8
#define HD_   128
#define GROUP_ 4

static constexpr float SCORE_SCALE = 0.08838834764831845f; // 1/sqrt(128)

typedef __bf16 bf16x8 __attribute__((ext_vector_type(8)));
typedef float  f32x4  __attribute__((ext_vector_type(4)));
typedef unsigned short u16;

__device__ inline float toF(const __hip_bfloat16 v) { return __bfloat162float(v); }
__device__ inline float toF(const float v)          { return v; }

__device__ inline void storeC(float* p, float v)          { *p = v; }
__device__ inline void storeC(__hip_bfloat16* p, float v) { *p = __float2bfloat16(v); }

// fp32 -> bf16 bit pattern, round-to-nearest-even (finite inputs)
__device__ inline unsigned short f2bf(float f) {
    union { float f; unsigned u; } v; v.f = f;
    unsigned r = v.u + 0x7FFFu + ((v.u >> 16) & 1u);
    return (unsigned short)(r >> 16);
}

// Direct global->LDS async copy, 16 B per lane. LDS dest is WAVE-UNIFORM
// base; HW adds lane*16. Global src is per-lane. [m97 pattern]
__device__ inline void gload_lds16(const u16* g, u16* l) {
    __builtin_amdgcn_global_load_lds(
        (const __attribute__((address_space(1))) void*)g,
        (__attribute__((address_space(3))) void*)l, 16, 0, 0);
}

// ===========================================================================
// FAST PATH
// ===========================================================================

// ---------------------------------------------------------------------------
// Linear fp32 -> bf16 convert (8 elems/thread, float4 in, int4 out)
// ---------------------------------------------------------------------------
__global__ __launch_bounds__(256) void lconv(const float* __restrict__ S,
                                             u16* __restrict__ D, int n8) {
    int i = blockIdx.x * 256 + threadIdx.x;
    if (i >= n8) return;
    const float4 a = *(const float4*)(S + (size_t)i * 8);
    const float4 b = *(const float4*)(S + (size_t)i * 8 + 4);
    union { int4 v; u16 u[8]; } t;
    t.u[0] = f2bf(a.x); t.u[1] = f2bf(a.y); t.u[2] = f2bf(a.z); t.u[3] = f2bf(a.w);
    t.u[4] = f2bf(b.x); t.u[5] = f2bf(b.y); t.u[6] = f2bf(b.z); t.u[7] = f2bf(b.w);
    *(int4*)(D + (size_t)i * 8) = t.v;
}

// ---------------------------------------------------------------------------
// Transpose + convert: src fp32 [R][Cc] row-major -> dst bf16 [Cc][R].
// 64x64 tiles via LDS; coalesced read (float4) and coalesced write (int4).
// ---------------------------------------------------------------------------
template <bool DUAL>
__global__ __launch_bounds__(256) void tconv(const float* __restrict__ S0,
                                             u16* __restrict__ D0,
                                             const float* __restrict__ S1,
                                             u16* __restrict__ D1,
                                             int R, int Cc) {
    const float* __restrict__ S = (DUAL && blockIdx.z) ? S1 : S0;
    u16* __restrict__ D         = (DUAL && blockIdx.z) ? D1 : D0;
    __shared__ u16 Tt[64][72];
    const int tid = threadIdx.x;
    const int r0 = blockIdx.y * 64, c0 = blockIdx.x * 64;
    {
        const int rr = tid >> 4, cc4 = (tid & 15) * 4;
#pragma unroll
        for (int e = 0; e < 4; ++e) {
            const int row = rr + e * 16;
            float4 v = *(const float4*)(S + (size_t)(r0 + row) * Cc + c0 + cc4);
            union { int2 w; u16 u[4]; } t;
            t.u[0] = f2bf(v.x); t.u[1] = f2bf(v.y); t.u[2] = f2bf(v.z); t.u[3] = f2bf(v.w);
            *(int2*)&Tt[row][cc4] = t.w;
        }
    }
    __syncthreads();
    {
        const int cc = tid >> 2, r8 = (tid & 3) * 8;
#pragma unroll
        for (int e = 0; e < 2; ++e) {
            const int rb = r8 + e * 32;
            union { int4 v; u16 u[8]; } t;
#pragma unroll
            for (int j = 0; j < 8; ++j) t.u[j] = Tt[rb + j][cc];
            *(int4*)(D + (size_t)(c0 + cc) * R + r0 + rb) = t.v;
        }
    }
}

// ---------------------------------------------------------------------------
// bf16 GEMM (m97 structure): C[M,N] = A[M,K] @ Bt[N,K]^T.
// BM=BN=128, BK=32, 4 waves x (64x64 as 4x4 mfma_f32_16x16x32_bf16).
// Staging via global_load_lds width=16 (no staging regs, no spill risk,
// no staging VALU). LDS tiles linear [128][32] u16 (required by
// global_load_lds: wave-uniform dest + lane*16).
// DUAL: blockIdx.z picks (Bt0,C0)/(Bt1,C1). TRC1: z=1 output transposed.
// ---------------------------------------------------------------------------
template <typename TC, bool DUAL, bool TRC1>
__global__ __launch_bounds__(256, 2) void gemm_bf16(const u16* __restrict__ A,
                                                    const u16* __restrict__ Bt0,
                                                    TC* __restrict__ C0,
                                                    const u16* __restrict__ Bt1,
                                                    TC* __restrict__ C1,
                                                    int M, int N, int K) {
    const u16* __restrict__ Bt = (DUAL && blockIdx.z) ? Bt1 : Bt0;
    TC* __restrict__ C         = (DUAL && blockIdx.z) ? C1 : C0;

    __shared__ u16 As[128 * 32];   // 8 KiB
    __shared__ u16 Bs[128 * 32];   // 8 KiB

    const int tid   = threadIdx.x;
    const int lane  = tid & 63;
    const int w     = tid >> 6;
    const int waveM = w >> 1;
    const int waveN = w & 1;
    const int lm    = lane & 15;
    const int quad  = lane >> 4;
    const int bm    = blockIdx.y * 128;
    const int bn    = blockIdx.x * 128;

    // Staging geometry: per issue, wave w covers 16 rows (w*16 + lane/4),
    // each lane writes 16 B (8 u16) at k-offset (lane&3)*8. Two issues per
    // matrix (row blocks +0, +64). LDS byte dest = row*64 + (lane&3)*16
    // = waveBase + lane*16  (wave-uniform base, as required).
    const int srow = w * 16 + (lane >> 2);
    const int scol = (lane & 3) * 8;

    const u16* agp0 = A  + (size_t)(bm + srow)      * K + scol;
    const u16* agp1 = A  + (size_t)(bm + srow + 64) * K + scol;
    const u16* bgp0 = Bt + (size_t)(bn + srow)      * K + scol;
    const u16* bgp1 = Bt + (size_t)(bn + srow + 64) * K + scol;

    u16* al0 = &As[(w * 16)      * 32];
    u16* al1 = &As[(w * 16 + 64) * 32];
    u16* bl0 = &Bs[(w * 16)      * 32];
    u16* bl1 = &Bs[(w * 16 + 64) * 32];

    f32x4 acc[4][4];
#pragma unroll
    for (int i = 0; i < 4; ++i)
#pragma unroll
        for (int j = 0; j < 4; ++j) acc[i][j] = (f32x4){0.f, 0.f, 0.f, 0.f};

    for (int k0 = 0; k0 < K; k0 += 32) {
        gload_lds16(agp0 + k0, al0);
        gload_lds16(agp1 + k0, al1);
        gload_lds16(bgp0 + k0, bl0);
        gload_lds16(bgp1 + k0, bl1);
        __syncthreads();   // drains vmcnt -> tiles resident

        bf16x8 af[4], bfv[4];
#pragma unroll
        for (int i = 0; i < 4; ++i)
            af[i] = *(const bf16x8*)&As[(waveM * 64 + i * 16 + lm) * 32 + quad * 8];
#pragma unroll
        for (int j = 0; j < 4; ++j)
            bfv[j] = *(const bf16x8*)&Bs[(waveN * 64 + j * 16 + lm) * 32 + quad * 8];
#pragma unroll
        for (int i = 0; i < 4; ++i)
#pragma unroll
            for (int j = 0; j < 4; ++j)
                acc[i][j] = __builtin_amdgcn_mfma_f32_16x16x32_bf16(af[i], bfv[j], acc[i][j], 0, 0, 0);
        __syncthreads();   // frags consumed -> safe to overwrite
    }

    // C/D layout: col = lane&15, row = quad*4 + reg  [m89-verified]
    if (TRC1 && DUAL && blockIdx.z) {
#pragma unroll
        for (int i = 0; i < 4; ++i) {
            int row0 = bm + waveM * 64 + i * 16 + quad * 4;
#pragma unroll
            for (int j = 0; j < 4; ++j) {
                int col = bn + waveN * 64 + j * 16 + lm;
#pragma unroll
                for (int rr = 0; rr < 4; ++rr)
                    storeC(&C[(size_t)col * M + row0 + rr], acc[i][j][rr]);
            }
        }
    } else {
#pragma unroll
        for (int i = 0; i < 4; ++i) {
            int row0 = bm + waveM * 64 + i * 16 + quad * 4;
#pragma unroll
            for (int j = 0; j < 4; ++j) {
                int col = bn + waveN * 64 + j * 16 + lm;
#pragma unroll
                for (int rr = 0; rr < 4; ++rr)
                    storeC(&C[(size_t)(row0 + rr) * N + col], acc[i][j][rr]);
            }
        }
    }
}

// ===========================================================================
// LEGACY (fallback) GEMM — fused fp32->bf16 conversion. Used when
// ws_size < 56 MiB.
// ===========================================================================
#define LSTR 40

template <typename TA, typename TB, typename TC, bool DUAL, bool TRC1>
__global__ __launch_bounds__(256) void gemm_mfma(const TA* __restrict__ A,
                                                 const TB* __restrict__ B0,
                                                 TC* __restrict__ C0,
                                                 const TB* __restrict__ B1,
                                                 TC* __restrict__ C1,
                                                 int M, int N, int K) {
    const TB* __restrict__ B = (DUAL && blockIdx.z) ? B1 : B0;
    TC* __restrict__ C       = (DUAL && blockIdx.z) ? C1 : C0;

    __shared__ unsigned short As[128 * LSTR];
    __shared__ unsigned short Bs[128 * LSTR];

    const int tid   = threadIdx.x;
    const int lane  = tid & 63;
    const int wv    = tid >> 6;
    const int waveM = wv >> 1;
    const int waveN = wv & 1;
    const int lm    = lane & 15;
    const int quad  = lane >> 4;
    const int bm    = blockIdx.y * 128;
    const int bn    = blockIdx.x * 128;

    f32x4 acc[4][4];
#pragma unroll
    for (int i = 0; i < 4; ++i)
#pragma unroll
        for (int j = 0; j < 4; ++j) acc[i][j] = (f32x4){0.f, 0.f, 0.f, 0.f};

    for (int k0 = 0; k0 < K; k0 += 32) {
#pragma unroll
        for (int e = 0; e < 8; ++e) {
            int p  = tid + e * 256;
            int r  = p >> 4, c2 = (p & 15) * 2;
            const TA* ap = A + (size_t)(bm + r) * K + k0 + c2;
            ushort2 t;
            t.x = f2bf(toF(ap[0]));
            t.y = f2bf(toF(ap[1]));
            *(ushort2*)&As[r * LSTR + c2] = t;
        }
#pragma unroll
        for (int e = 0; e < 8; ++e) {
            int p  = tid + e * 256;
            int n  = p & 127, k2 = (p >> 7) * 2;
            const TB* bp = B + (size_t)(k0 + k2) * N + bn + n;
            ushort2 t;
            t.x = f2bf(toF(bp[0]));
            t.y = f2bf(toF(bp[N]));
            *(ushort2*)&Bs[n * LSTR + k2] = t;
        }
        __syncthreads();

        bf16x8 af[4], bfr[4];
#pragma unroll
        for (int i = 0; i < 4; ++i)
            af[i] = *(const bf16x8*)&As[(waveM * 64 + i * 16 + lm) * LSTR + quad * 8];
#pragma unroll
        for (int j = 0; j < 4; ++j)
            bfr[j] = *(const bf16x8*)&Bs[(waveN * 64 + j * 16 + lm) * LSTR + quad * 8];
#pragma unroll
        for (int i = 0; i < 4; ++i)
#pragma unroll
            for (int j = 0; j < 4; ++j)
                acc[i][j] = __builtin_amdgcn_mfma_f32_16x16x32_bf16(af[i], bfr[j], acc[i][j], 0, 0, 0);
        __syncthreads();
    }

    if (TRC1 && DUAL && blockIdx.z) {
#pragma unroll
        for (int i = 0; i < 4; ++i) {
            int row0 = bm + waveM * 64 + i * 16 + quad * 4;
#pragma unroll
            for (int j = 0; j < 4; ++j) {
                int col = bn + waveN * 64 + j * 16 + lm;
#pragma unroll
                for (int rr = 0; rr < 4; ++rr)
                    storeC(&C[(size_t)col * M + row0 + rr], acc[i][j][rr]);
            }
        }
    } else {
#pragma unroll
        for (int i = 0; i < 4; ++i) {
            int row0 = bm + waveM * 64 + i * 16 + quad * 4;
#pragma unroll
            for (int j = 0; j < 4; ++j) {
                int col = bn + waveN * 64 + j * 16 + lm;
#pragma unroll
                for (int rr = 0; rr < 4; ++rr)
                    storeC(&C[(size_t)(row0 + rr) * N + col], acc[i][j][rr]);
            }
        }
    }
}

// ---------------------------------------------------------------------------
// RoPE in-place on Q (fp32, [token][H*HD]) and K (bf16, [token][KVH*HD]).
// ---------------------------------------------------------------------------
template <typename TQ, typename TK>
__global__ __launch_bounds__(256) void rope_kernel(TQ* __restrict__ Q,
                                                   TK* __restrict__ Kt,
                                                   const int* __restrict__ start_pos) {
    int w    = blockIdx.x * 4 + (threadIdx.x >> 6);
    int lane = threadIdx.x & 63;
    int hh = w % (H_ + KVH_);
    int n  = w / (H_ + KVH_);
    int t  = n % T_;
    int pos = *start_pos + t;

    int e0 = 2 * lane, e1 = 2 * lane + 1;
    int j0 = e0 & 63,  j1 = e1 & 63;
    const double LN_BASE = 9.210340371976184; // ln(10000)
    double a0 = (double)pos * exp(-((double)(2 * j0) / 128.0) * LN_BASE);
    double a1 = (double)pos * exp(-((double)(2 * j1) / 128.0) * LN_BASE);
    float c0 = (float)cos(a0), s0 = (float)sin(a0);
    float c1 = (float)cos(a1), s1 = (float)sin(a1);

    if (hh < H_) {
        TQ* base = Q + (size_t)n * (H_ * HD_) + hh * HD_;
        float x0 = toF(base[e0]), x1 = toF(base[e1]);
        storeC(&base[e0], x0 * c0 - x1 * s0);
        storeC(&base[e1], x1 * c1 + x0 * s1);
    } else {
        TK* base = Kt + (size_t)n * (KVH_ * HD_) + (hh - H_) * HD_;
        float x0 = toF(base[e0]), x1 = toF(base[e1]);
        storeC(&base[e0], x0 * c0 - x1 * s0);
        storeC(&base[e1], x1 * c1 + x0 * s1);
    }
}

// ---------------------------------------------------------------------------
// Flash attention (causal, GQA) — unchanged from the verified kernel.
// ---------------------------------------------------------------------------
#define KSTR 136
#define VSTR 72
#define PSTR 72

__global__ __launch_bounds__(256, 2) void flash_attn(
        const float* __restrict__ Q,
        const __hip_bfloat16* __restrict__ K,
        const __hip_bfloat16* __restrict__ Vt,
        __hip_bfloat16* __restrict__ AO) {
    __shared__ unsigned short Ks[64 * KSTR];
    __shared__ unsigned short Vs[128 * VSTR];
    __shared__ unsigned short Ps[4][32 * PSTR];

    const int tid  = threadIdx.x;
    const int lane = tid & 63;
    const int w    = tid >> 6;
    const int quad = lane >> 4;
    const int lm   = lane & 15;

    const int qb  = blockIdx.x * 128;
    const int h   = blockIdx.y;
    const int b   = blockIdx.z;
    const int kvh = h >> 2;

    const int qw = qb + w * 32;

    bf16x8 qf[2][4];
#pragma unroll
    for (int mt = 0; mt < 2; ++mt) {
        const float* qrow = Q + (size_t)(b * T_ + qw + mt * 16 + lm) * (H_ * HD_) + h * HD_;
#pragma unroll
        for (int ks = 0; ks < 4; ++ks) {
            const float* p4 = qrow + ks * 32 + quad * 8;
            float4 f0 = *(const float4*)(p4);
            float4 f1 = *(const float4*)(p4 + 4);
            union { bf16x8 v; unsigned short u[8]; } t;
            t.u[0] = f2bf(f0.x * SCORE_SCALE); t.u[1] = f2bf(f0.y * SCORE_SCALE);
            t.u[2] = f2bf(f0.z * SCORE_SCALE); t.u[3] = f2bf(f0.w * SCORE_SCALE);
            t.u[4] = f2bf(f1.x * SCORE_SCALE); t.u[5] = f2bf(f1.y * SCORE_SCALE);
            t.u[6] = f2bf(f1.z * SCORE_SCALE); t.u[7] = f2bf(f1.w * SCORE_SCALE);
            qf[mt][ks] = t.v;
        }
    }

    float mI[2][4], lI[2][4];
    f32x4 o[2][8];
#pragma unroll
    for (int mt = 0; mt < 2; ++mt) {
#pragma unroll
        for (int rr = 0; rr < 4; ++rr) { mI[mt][rr] = -1e30f; lI[mt][rr] = 0.f; }
#pragma unroll
        for (int dc = 0; dc < 8; ++dc) o[mt][dc] = (f32x4){0.f, 0.f, 0.f, 0.f};
    }

    const int nkt  = (qb + 128) / 64;
    const int qmax = qw + 31;

    for (int kt = 0; kt < nkt; ++kt) {
        const int t0 = kt * 64;
#pragma unroll
        for (int e = 0; e < 4; ++e) {
            int p = tid + e * 256;
            int tt = p >> 4, d0 = (p & 15) * 8;
            int4 v = *(const int4*)(K + (size_t)(b * T_ + t0 + tt) * (KVH_ * HD_) + kvh * HD_ + d0);
            *(int4*)&Ks[tt * KSTR + d0] = v;
        }
#pragma unroll
        for (int e = 0; e < 4; ++e) {
            int p = tid + e * 256;
            int d = p >> 3, tm = (p & 7) * 8;
            int4 v = *(const int4*)(Vt + (size_t)(kvh * HD_ + d) * (B_ * T_) + b * T_ + t0 + tm);
            *(int4*)&Vs[d * VSTR + tm] = v;
        }
        __syncthreads();

        if (t0 <= qmax) {
            f32x4 s[2][4];
#pragma unroll
            for (int mt = 0; mt < 2; ++mt)
#pragma unroll
                for (int tc = 0; tc < 4; ++tc) s[mt][tc] = (f32x4){0.f, 0.f, 0.f, 0.f};
#pragma unroll
            for (int ks = 0; ks < 4; ++ks) {
                bf16x8 kf[4];
#pragma unroll
                for (int tc = 0; tc < 4; ++tc)
                    kf[tc] = *(const bf16x8*)&Ks[(tc * 16 + lm) * KSTR + ks * 32 + quad * 8];
#pragma unroll
                for (int mt = 0; mt < 2; ++mt)
#pragma unroll
                    for (int tc = 0; tc < 4; ++tc)
                        s[mt][tc] = __builtin_amdgcn_mfma_f32_16x16x32_bf16(qf[mt][ks], kf[tc], s[mt][tc], 0, 0, 0);
            }

            if (t0 + 63 > qw) {
#pragma unroll
                for (int mt = 0; mt < 2; ++mt) {
                    int qrow = qw + mt * 16 + quad * 4;
#pragma unroll
                    for (int tc = 0; tc < 4; ++tc) {
                        int tcol = t0 + tc * 16 + lm;
#pragma unroll
                        for (int rr = 0; rr < 4; ++rr)
                            if (tcol > qrow + rr) s[mt][tc][rr] = -1e30f;
                    }
                }
            }

#pragma unroll
            for (int mt = 0; mt < 2; ++mt) {
#pragma unroll
                for (int rr = 0; rr < 4; ++rr) {
                    float tmx = fmaxf(fmaxf(s[mt][0][rr], s[mt][1][rr]),
                                      fmaxf(s[mt][2][rr], s[mt][3][rr]));
#pragma unroll
                    for (int off = 8; off >= 1; off >>= 1)
                        tmx = fmaxf(tmx, __shfl_xor(tmx, off, 64));
                    float mn    = fmaxf(mI[mt][rr], tmx);
                    float alpha = __expf(mI[mt][rr] - mn);
                    mI[mt][rr]  = mn;
                    float rs = 0.f;
#pragma unroll
                    for (int tc = 0; tc < 4; ++tc) {
                        float p = __expf(s[mt][tc][rr] - mn);
                        s[mt][tc][rr] = p;
                        rs += p;
                    }
#pragma unroll
                    for (int off = 8; off >= 1; off >>= 1)
                        rs += __shfl_xor(rs, off, 64);
                    lI[mt][rr] = lI[mt][rr] * alpha + rs;
#pragma unroll
                    for (int dc = 0; dc < 8; ++dc)
                        o[mt][dc][rr] *= alpha;
                }
            }

#pragma unroll
            for (int mt = 0; mt < 2; ++mt)
#pragma unroll
                for (int tc = 0; tc < 4; ++tc)
#pragma unroll
                    for (int rr = 0; rr < 4; ++rr)
                        Ps[w][(mt * 16 + quad * 4 + rr) * PSTR + tc * 16 + lm] = f2bf(s[mt][tc][rr]);

#pragma unroll
            for (int ss = 0; ss < 2; ++ss) {
                bf16x8 pf[2];
#pragma unroll
                for (int mt = 0; mt < 2; ++mt)
                    pf[mt] = *(const bf16x8*)&Ps[w][(mt * 16 + lm) * PSTR + ss * 32 + quad * 8];
#pragma unroll
                for (int dc = 0; dc < 8; ++dc) {
                    bf16x8 vf = *(const bf16x8*)&Vs[(dc * 16 + lm) * VSTR + ss * 32 + quad * 8];
#pragma unroll
                    for (int mt = 0; mt < 2; ++mt)
                        o[mt][dc] = __builtin_amdgcn_mfma_f32_16x16x32_bf16(pf[mt], vf, o[mt][dc], 0, 0, 0);
                }
            }
        }
        __syncthreads();
    }

#pragma unroll
    for (int mt = 0; mt < 2; ++mt) {
#pragma unroll
        for (int rr = 0; rr < 4; ++rr) {
            float inv = 1.f / lI[mt][rr];
            size_t row = (size_t)(b * T_ + qw + mt * 16 + quad * 4 + rr) * (H_ * HD_) + h * HD_;
#pragma unroll
            for (int dc = 0; dc < 8; ++dc)
                AO[row + dc * 16 + lm] = __float2bfloat16(o[mt][dc][rr] * inv);
        }
    }
}

// ---------------------------------------------------------------------------
extern "C" void kernel_launch(void* const* d_in, const int* in_sizes, int n_in,
                              void* d_out, int out_size, void* d_ws, size_t ws_size,
                              hipStream_t stream) {
    const float* x  = (const float*)d_in[0];
    const float* wq = (const float*)d_in[1];
    const float* wk = (const float*)d_in[2];
    const float* wv = (const float*)d_in[3];
    const float* wo = (const float*)d_in[4];
    const int* start_pos = (const int*)d_in[5];
    float* out = (float*)d_out;

    dim3 blk(256);
    const int M   = B_ * T_;      // 2048
    const int NQ  = H_ * HD_;     // 4096
    const int NKV = KVH_ * HD_;   // 1024

    // Fast path needs: Kb(4MiB) Vtb(4MiB) [xb->AOb](16MiB) [wqb->wkb+wvb->wob](32MiB)
    const size_t NEED = 58720256; // 56 MiB

    if (ws_size >= NEED) {
        char* w = (char*)d_ws;
        __hip_bfloat16* Kb  = (__hip_bfloat16*)(w);                     // [2048][1024]
        __hip_bfloat16* Vtb = (__hip_bfloat16*)(w + (4u  << 20));       // [1024][2048]
        u16*            xb  = (u16*)(w + (8u  << 20));                  // [2048][4096]
        __hip_bfloat16* AOb = (__hip_bfloat16*)(w + (8u  << 20));       // reuses xb slot
        u16*            wS  = (u16*)(w + (24u << 20));                  // 32 MiB shared slot
        u16* wqb = wS;                       // [4096][4096] transposed
        u16* wkb = wS;                       // [1024][4096] transposed
        u16* wvb = wS + (size_t)NKV * D_;    // [1024][4096] transposed
        u16* wob = wS;                       // [4096][4096] transposed
        float* Qf = out;                     // Q fp32 in d_out (dead before out-proj)

        // 1. x -> bf16
        lconv<<<(M * D_ / 8 + 255) / 256, blk, 0, stream>>>(x, xb, M * D_ / 8);
        // 2. wq -> bf16 transposed
        tconv<false><<<dim3(NQ / 64, D_ / 64, 1), blk, 0, stream>>>(wq, wqb, nullptr, nullptr, D_, NQ);
        // 3. Q projection: 2048x4096x4096 -> fp32 Qf
        gemm_bf16<float, false, false>
            <<<dim3(NQ / 128, M / 128, 1), blk, 0, stream>>>(xb, wqb, Qf, nullptr, nullptr, M, NQ, D_);
        // 4. wk, wv -> bf16 transposed (wqb slot now dead)
        tconv<true><<<dim3(NKV / 64, D_ / 64, 2), blk, 0, stream>>>(wk, wkb, wv, wvb, D_, NKV);
        // 5. K and V projections fused; V stored transposed
        gemm_bf16<__hip_bfloat16, true, true>
            <<<dim3(NKV / 128, M / 128, 2), blk, 0, stream>>>(xb, wkb, Kb, wvb, Vtb, M, NKV, D_);
        // 6. RoPE on Q and K
        rope_kernel<<<(M * (H_ + KVH_)) / 4, blk, 0, stream>>>(Qf, Kb, start_pos);
        // 7. wo -> bf16 transposed (wkb/wvb dead)
        tconv<false><<<dim3(NQ / 64, NQ / 64, 1), blk, 0, stream>>>(wo, wob, nullptr, nullptr, NQ, D_);
        // 8. Flash attention -> AOb (xb slot now dead)
        flash_attn<<<dim3(T_ / 128, H_, B_), blk, 0, stream>>>(Qf, Kb, Vtb, AOb);
        // 9. Output projection -> fp32 out
        gemm_bf16<float, false, false>
            <<<dim3(D_ / 128, M / 128, 1), blk, 0, stream>>>((const u16*)AOb, wob, out, nullptr, nullptr, M, D_, NQ);
    } else {
        // ------- legacy fallback (previous verified path, 24 MiB ws) -------
        float* Qf           = out;
        __hip_bfloat16* Kb  = (__hip_bfloat16*)d_ws;
        __hip_bfloat16* Vtb = Kb + (size_t)B_ * T_ * KVH_ * HD_;
        __hip_bfloat16* AOb = Vtb + (size_t)B_ * T_ * KVH_ * HD_;

        gemm_mfma<float, float, float, false, false>
            <<<dim3(NQ / 128, M / 128, 1), blk, 0, stream>>>(x, wq, Qf, nullptr, nullptr, M, NQ, D_);
        gemm_mfma<float, float, __hip_bfloat16, true, true>
            <<<dim3(NKV / 128, M / 128, 2), blk, 0, stream>>>(x, wk, Kb, wv, Vtb, M, NKV, D_);
        rope_kernel<<<(M * (H_ + KVH_)) / 4, blk, 0, stream>>>(Qf, Kb, start_pos);
        flash_attn<<<dim3(T_ / 128, H_, B_), blk, 0, stream>>>(Qf, Kb, Vtb, AOb);
        gemm_mfma<__hip_bfloat16, float, float, false, false>
            <<<dim3(D_ / 128, M / 128, 1), blk, 0, stream>>>(AOb, wo, out, nullptr, nullptr, M, D_, NQ);
    }
}

// Round 3
// 589.694 us; speedup vs baseline: 4.0737x; 1.0308x over previous
//
#include <hip/hip_runtime.h>
#include <hip/hip_bf16.h>
#include <math.h>

// Problem constants
#define B_    2
#define T_    1024
#define D_    4096
#define H_    32
#define KVH_  8
#define HD_   128
#define GROUP_ 4

static constexpr float SCORE_SCALE = 0.08838834764831845f; // 1/sqrt(128)

typedef __bf16 bf16x8 __attribute__((ext_vector_type(8)));
typedef float  f32x4  __attribute__((ext_vector_type(4)));
typedef unsigned short u16;

__device__ inline float toF(const __hip_bfloat16 v) { return __bfloat162float(v); }
__device__ inline float toF(const float v)          { return v; }

__device__ inline void storeC(float* p, float v)          { *p = v; }
__device__ inline void storeC(__hip_bfloat16* p, float v) { *p = __float2bfloat16(v); }

// fp32 -> bf16 bit pattern, round-to-nearest-even (finite inputs)
__device__ inline unsigned short f2bf(float f) {
    union { float f; unsigned u; } v; v.f = f;
    unsigned r = v.u + 0x7FFFu + ((v.u >> 16) & 1u);
    return (unsigned short)(r >> 16);
}

// Direct global->LDS async copy, 16 B per lane. LDS dest is WAVE-UNIFORM
// base; HW adds lane*16. Global src is per-lane. [m97 pattern]
__device__ inline void gload_lds16(const u16* g, u16* l) {
    __builtin_amdgcn_global_load_lds(
        (const __attribute__((address_space(1))) void*)g,
        (__attribute__((address_space(3))) void*)l, 16, 0, 0);
}

// ===========================================================================
// FAST PATH
// ===========================================================================

// ---------------------------------------------------------------------------
// Linear fp32 -> bf16 convert (8 elems/thread, float4 in, int4 out)
// ---------------------------------------------------------------------------
__global__ __launch_bounds__(256) void lconv(const float* __restrict__ S,
                                             u16* __restrict__ D, int n8) {
    int i = blockIdx.x * 256 + threadIdx.x;
    if (i >= n8) return;
    const float4 a = *(const float4*)(S + (size_t)i * 8);
    const float4 b = *(const float4*)(S + (size_t)i * 8 + 4);
    union { int4 v; u16 u[8]; } t;
    t.u[0] = f2bf(a.x); t.u[1] = f2bf(a.y); t.u[2] = f2bf(a.z); t.u[3] = f2bf(a.w);
    t.u[4] = f2bf(b.x); t.u[5] = f2bf(b.y); t.u[6] = f2bf(b.z); t.u[7] = f2bf(b.w);
    *(int4*)(D + (size_t)i * 8) = t.v;
}

// ---------------------------------------------------------------------------
// Transpose + convert: src fp32 [R][Cc] row-major -> dst bf16 [Cc][R].
// ---------------------------------------------------------------------------
template <bool DUAL>
__global__ __launch_bounds__(256) void tconv(const float* __restrict__ S0,
                                             u16* __restrict__ D0,
                                             const float* __restrict__ S1,
                                             u16* __restrict__ D1,
                                             int R, int Cc) {
    const float* __restrict__ S = (DUAL && blockIdx.z) ? S1 : S0;
    u16* __restrict__ D         = (DUAL && blockIdx.z) ? D1 : D0;
    __shared__ u16 Tt[64][72];
    const int tid = threadIdx.x;
    const int r0 = blockIdx.y * 64, c0 = blockIdx.x * 64;
    {
        const int rr = tid >> 4, cc4 = (tid & 15) * 4;
#pragma unroll
        for (int e = 0; e < 4; ++e) {
            const int row = rr + e * 16;
            float4 v = *(const float4*)(S + (size_t)(r0 + row) * Cc + c0 + cc4);
            union { int2 w; u16 u[4]; } t;
            t.u[0] = f2bf(v.x); t.u[1] = f2bf(v.y); t.u[2] = f2bf(v.z); t.u[3] = f2bf(v.w);
            *(int2*)&Tt[row][cc4] = t.w;
        }
    }
    __syncthreads();
    {
        const int cc = tid >> 2, r8 = (tid & 3) * 8;
#pragma unroll
        for (int e = 0; e < 2; ++e) {
            const int rb = r8 + e * 32;
            union { int4 v; u16 u[8]; } t;
#pragma unroll
            for (int j = 0; j < 8; ++j) t.u[j] = Tt[rb + j][cc];
            *(int4*)(D + (size_t)(c0 + cc) * R + r0 + rb) = t.v;
        }
    }
}

// ---------------------------------------------------------------------------
// bf16 GEMM (m97 structure): C[M,N] = A[M,K] @ Bt[N,K]^T.
// BM=BN=128, BK=32, global_load_lds width=16 staging, linear LDS.
// ---------------------------------------------------------------------------
template <typename TC, bool DUAL, bool TRC1>
__global__ __launch_bounds__(256, 2) void gemm_bf16(const u16* __restrict__ A,
                                                    const u16* __restrict__ Bt0,
                                                    TC* __restrict__ C0,
                                                    const u16* __restrict__ Bt1,
                                                    TC* __restrict__ C1,
                                                    int M, int N, int K) {
    const u16* __restrict__ Bt = (DUAL && blockIdx.z) ? Bt1 : Bt0;
    TC* __restrict__ C         = (DUAL && blockIdx.z) ? C1 : C0;

    __shared__ u16 As[128 * 32];   // 8 KiB
    __shared__ u16 Bs[128 * 32];   // 8 KiB

    const int tid   = threadIdx.x;
    const int lane  = tid & 63;
    const int w     = tid >> 6;
    const int waveM = w >> 1;
    const int waveN = w & 1;
    const int lm    = lane & 15;
    const int quad  = lane >> 4;
    const int bm    = blockIdx.y * 128;
    const int bn    = blockIdx.x * 128;

    const int srow = w * 16 + (lane >> 2);
    const int scol = (lane & 3) * 8;

    const u16* agp0 = A  + (size_t)(bm + srow)      * K + scol;
    const u16* agp1 = A  + (size_t)(bm + srow + 64) * K + scol;
    const u16* bgp0 = Bt + (size_t)(bn + srow)      * K + scol;
    const u16* bgp1 = Bt + (size_t)(bn + srow + 64) * K + scol;

    u16* al0 = &As[(w * 16)      * 32];
    u16* al1 = &As[(w * 16 + 64) * 32];
    u16* bl0 = &Bs[(w * 16)      * 32];
    u16* bl1 = &Bs[(w * 16 + 64) * 32];

    f32x4 acc[4][4];
#pragma unroll
    for (int i = 0; i < 4; ++i)
#pragma unroll
        for (int j = 0; j < 4; ++j) acc[i][j] = (f32x4){0.f, 0.f, 0.f, 0.f};

    for (int k0 = 0; k0 < K; k0 += 32) {
        gload_lds16(agp0 + k0, al0);
        gload_lds16(agp1 + k0, al1);
        gload_lds16(bgp0 + k0, bl0);
        gload_lds16(bgp1 + k0, bl1);
        __syncthreads();   // drains vmcnt -> tiles resident

        bf16x8 af[4], bfv[4];
#pragma unroll
        for (int i = 0; i < 4; ++i)
            af[i] = *(const bf16x8*)&As[(waveM * 64 + i * 16 + lm) * 32 + quad * 8];
#pragma unroll
        for (int j = 0; j < 4; ++j)
            bfv[j] = *(const bf16x8*)&Bs[(waveN * 64 + j * 16 + lm) * 32 + quad * 8];
#pragma unroll
        for (int i = 0; i < 4; ++i)
#pragma unroll
            for (int j = 0; j < 4; ++j)
                acc[i][j] = __builtin_amdgcn_mfma_f32_16x16x32_bf16(af[i], bfv[j], acc[i][j], 0, 0, 0);
        __syncthreads();   // frags consumed -> safe to overwrite
    }

    // C/D layout: col = lane&15, row = quad*4 + reg  [m89-verified]
    if (TRC1 && DUAL && blockIdx.z) {
#pragma unroll
        for (int i = 0; i < 4; ++i) {
            int row0 = bm + waveM * 64 + i * 16 + quad * 4;
#pragma unroll
            for (int j = 0; j < 4; ++j) {
                int col = bn + waveN * 64 + j * 16 + lm;
#pragma unroll
                for (int rr = 0; rr < 4; ++rr)
                    storeC(&C[(size_t)col * M + row0 + rr], acc[i][j][rr]);
            }
        }
    } else {
#pragma unroll
        for (int i = 0; i < 4; ++i) {
            int row0 = bm + waveM * 64 + i * 16 + quad * 4;
#pragma unroll
            for (int j = 0; j < 4; ++j) {
                int col = bn + waveN * 64 + j * 16 + lm;
#pragma unroll
                for (int rr = 0; rr < 4; ++rr)
                    storeC(&C[(size_t)(row0 + rr) * N + col], acc[i][j][rr]);
            }
        }
    }
}

// ===========================================================================
// LEGACY (fallback) GEMM — fused fp32->bf16 conversion. ws_size < 56 MiB.
// ===========================================================================
#define LSTR 40

template <typename TA, typename TB, typename TC, bool DUAL, bool TRC1>
__global__ __launch_bounds__(256) void gemm_mfma(const TA* __restrict__ A,
                                                 const TB* __restrict__ B0,
                                                 TC* __restrict__ C0,
                                                 const TB* __restrict__ B1,
                                                 TC* __restrict__ C1,
                                                 int M, int N, int K) {
    const TB* __restrict__ B = (DUAL && blockIdx.z) ? B1 : B0;
    TC* __restrict__ C       = (DUAL && blockIdx.z) ? C1 : C0;

    __shared__ unsigned short As[128 * LSTR];
    __shared__ unsigned short Bs[128 * LSTR];

    const int tid   = threadIdx.x;
    const int lane  = tid & 63;
    const int wv    = tid >> 6;
    const int waveM = wv >> 1;
    const int waveN = wv & 1;
    const int lm    = lane & 15;
    const int quad  = lane >> 4;
    const int bm    = blockIdx.y * 128;
    const int bn    = blockIdx.x * 128;

    f32x4 acc[4][4];
#pragma unroll
    for (int i = 0; i < 4; ++i)
#pragma unroll
        for (int j = 0; j < 4; ++j) acc[i][j] = (f32x4){0.f, 0.f, 0.f, 0.f};

    for (int k0 = 0; k0 < K; k0 += 32) {
#pragma unroll
        for (int e = 0; e < 8; ++e) {
            int p  = tid + e * 256;
            int r  = p >> 4, c2 = (p & 15) * 2;
            const TA* ap = A + (size_t)(bm + r) * K + k0 + c2;
            ushort2 t;
            t.x = f2bf(toF(ap[0]));
            t.y = f2bf(toF(ap[1]));
            *(ushort2*)&As[r * LSTR + c2] = t;
        }
#pragma unroll
        for (int e = 0; e < 8; ++e) {
            int p  = tid + e * 256;
            int n  = p & 127, k2 = (p >> 7) * 2;
            const TB* bp = B + (size_t)(k0 + k2) * N + bn + n;
            ushort2 t;
            t.x = f2bf(toF(bp[0]));
            t.y = f2bf(toF(bp[N]));
            *(ushort2*)&Bs[n * LSTR + k2] = t;
        }
        __syncthreads();

        bf16x8 af[4], bfr[4];
#pragma unroll
        for (int i = 0; i < 4; ++i)
            af[i] = *(const bf16x8*)&As[(waveM * 64 + i * 16 + lm) * LSTR + quad * 8];
#pragma unroll
        for (int j = 0; j < 4; ++j)
            bfr[j] = *(const bf16x8*)&Bs[(waveN * 64 + j * 16 + lm) * LSTR + quad * 8];
#pragma unroll
        for (int i = 0; i < 4; ++i)
#pragma unroll
            for (int j = 0; j < 4; ++j)
                acc[i][j] = __builtin_amdgcn_mfma_f32_16x16x32_bf16(af[i], bfr[j], acc[i][j], 0, 0, 0);
        __syncthreads();
    }

    if (TRC1 && DUAL && blockIdx.z) {
#pragma unroll
        for (int i = 0; i < 4; ++i) {
            int row0 = bm + waveM * 64 + i * 16 + quad * 4;
#pragma unroll
            for (int j = 0; j < 4; ++j) {
                int col = bn + waveN * 64 + j * 16 + lm;
#pragma unroll
                for (int rr = 0; rr < 4; ++rr)
                    storeC(&C[(size_t)col * M + row0 + rr], acc[i][j][rr]);
            }
        }
    } else {
#pragma unroll
        for (int i = 0; i < 4; ++i) {
            int row0 = bm + waveM * 64 + i * 16 + quad * 4;
#pragma unroll
            for (int j = 0; j < 4; ++j) {
                int col = bn + waveN * 64 + j * 16 + lm;
#pragma unroll
                for (int rr = 0; rr < 4; ++rr)
                    storeC(&C[(size_t)(row0 + rr) * N + col], acc[i][j][rr]);
            }
        }
    }
}

// ---------------------------------------------------------------------------
// RoPE in-place on Q (fp32) and K (bf16).
// ---------------------------------------------------------------------------
template <typename TQ, typename TK>
__global__ __launch_bounds__(256) void rope_kernel(TQ* __restrict__ Q,
                                                   TK* __restrict__ Kt,
                                                   const int* __restrict__ start_pos) {
    int w    = blockIdx.x * 4 + (threadIdx.x >> 6);
    int lane = threadIdx.x & 63;
    int hh = w % (H_ + KVH_);
    int n  = w / (H_ + KVH_);
    int t  = n % T_;
    int pos = *start_pos + t;

    int e0 = 2 * lane, e1 = 2 * lane + 1;
    int j0 = e0 & 63,  j1 = e1 & 63;
    const double LN_BASE = 9.210340371976184; // ln(10000)
    double a0 = (double)pos * exp(-((double)(2 * j0) / 128.0) * LN_BASE);
    double a1 = (double)pos * exp(-((double)(2 * j1) / 128.0) * LN_BASE);
    float c0 = (float)cos(a0), s0 = (float)sin(a0);
    float c1 = (float)cos(a1), s1 = (float)sin(a1);

    if (hh < H_) {
        TQ* base = Q + (size_t)n * (H_ * HD_) + hh * HD_;
        float x0 = toF(base[e0]), x1 = toF(base[e1]);
        storeC(&base[e0], x0 * c0 - x1 * s0);
        storeC(&base[e1], x1 * c1 + x0 * s1);
    } else {
        TK* base = Kt + (size_t)n * (KVH_ * HD_) + (hh - H_) * HD_;
        float x0 = toF(base[e0]), x1 = toF(base[e1]);
        storeC(&base[e0], x0 * c0 - x1 * s0);
        storeC(&base[e1], x1 * c1 + x0 * s1);
    }
}

// ---------------------------------------------------------------------------
// Flash attention (causal, GQA) — 64-q-row blocks for causal load balance.
// Grid (T/64=16, H, B) = 1024 blocks; q-tile decorrelated from XCD via
// qt=(bx+by)&15 (XCD round-robin would otherwise pin q-tile==XCD: 8x skew).
// 4 waves x 16 q-rows; K-tiles of 64 positions; all waves active on every
// staged tile (last tile edge-masked). LDS 44 KiB -> 3 blocks/CU resident,
// 4/CU queued -> dynamic backfill balances residual skew.
// ---------------------------------------------------------------------------
#define KSTR 136   // Ks row stride (ushorts)
#define VSTR 72    // Vs row stride
#define PSTR 72    // Ps row stride

__global__ __launch_bounds__(256, 2) void flash_attn(
        const float* __restrict__ Q,
        const __hip_bfloat16* __restrict__ K,
        const __hip_bfloat16* __restrict__ Vt,
        __hip_bfloat16* __restrict__ AO) {
    __shared__ unsigned short Ks[64 * KSTR];       // 17408 B
    __shared__ unsigned short Vs[128 * VSTR];      // 18432 B
    __shared__ unsigned short Ps[4][16 * PSTR];    //  9216 B (per-wave private)

    const int tid  = threadIdx.x;
    const int lane = tid & 63;
    const int w    = tid >> 6;
    const int quad = lane >> 4;
    const int lm   = lane & 15;

    const int qt  = (blockIdx.x + blockIdx.y) & 15;  // XCD-decorrelated q-tile
    const int qb  = qt * 64;
    const int h   = blockIdx.y;
    const int b   = blockIdx.z;
    const int kvh = h >> 2;           // GROUP_=4 query heads per KV head

    const int qw = qb + w * 16;       // wave's 16 q-rows: qw..qw+15

    // Q fragment in registers (A-layout: m=lm, k=quad*8+j), pre-scaled.
    bf16x8 qf[4];
    {
        const float* qrow = Q + (size_t)(b * T_ + qw + lm) * (H_ * HD_) + h * HD_;
#pragma unroll
        for (int ks = 0; ks < 4; ++ks) {
            const float* p4 = qrow + ks * 32 + quad * 8;
            float4 f0 = *(const float4*)(p4);
            float4 f1 = *(const float4*)(p4 + 4);
            union { bf16x8 v; unsigned short u[8]; } t;
            t.u[0] = f2bf(f0.x * SCORE_SCALE); t.u[1] = f2bf(f0.y * SCORE_SCALE);
            t.u[2] = f2bf(f0.z * SCORE_SCALE); t.u[3] = f2bf(f0.w * SCORE_SCALE);
            t.u[4] = f2bf(f1.x * SCORE_SCALE); t.u[5] = f2bf(f1.y * SCORE_SCALE);
            t.u[6] = f2bf(f1.z * SCORE_SCALE); t.u[7] = f2bf(f1.w * SCORE_SCALE);
            qf[ks] = t.v;
        }
    }

    float mI[4], lI[4];
    f32x4 o[8];
#pragma unroll
    for (int rr = 0; rr < 4; ++rr) { mI[rr] = -1e30f; lI[rr] = 0.f; }
#pragma unroll
    for (int dc = 0; dc < 8; ++dc) o[dc] = (f32x4){0.f, 0.f, 0.f, 0.f};

    const int nkt = qt + 1;   // k-tiles covering t <= qb+63

    for (int kt = 0; kt < nkt; ++kt) {
        const int t0 = kt * 64;
        // --- cooperative staging: K tile [64][128], V^T tile [128][64] -------
#pragma unroll
        for (int e = 0; e < 4; ++e) {
            int p = tid + e * 256;
            int tt = p >> 4, d0 = (p & 15) * 8;
            int4 v = *(const int4*)(K + (size_t)(b * T_ + t0 + tt) * (KVH_ * HD_) + kvh * HD_ + d0);
            *(int4*)&Ks[tt * KSTR + d0] = v;
        }
#pragma unroll
        for (int e = 0; e < 4; ++e) {
            int p = tid + e * 256;
            int d = p >> 3, tm = (p & 7) * 8;
            int4 v = *(const int4*)(Vt + (size_t)(kvh * HD_ + d) * (B_ * T_) + b * T_ + t0 + tm);
            *(int4*)&Vs[d * VSTR + tm] = v;
        }
        __syncthreads();

        // --- S = Q K^T ------------------------------------------------------
        f32x4 s[4];
#pragma unroll
        for (int tc = 0; tc < 4; ++tc) s[tc] = (f32x4){0.f, 0.f, 0.f, 0.f};
        __builtin_amdgcn_s_setprio(1);
#pragma unroll
        for (int ks = 0; ks < 4; ++ks) {
            bf16x8 kf[4];
#pragma unroll
            for (int tc = 0; tc < 4; ++tc)
                kf[tc] = *(const bf16x8*)&Ks[(tc * 16 + lm) * KSTR + ks * 32 + quad * 8];
#pragma unroll
            for (int tc = 0; tc < 4; ++tc)
                s[tc] = __builtin_amdgcn_mfma_f32_16x16x32_bf16(qf[ks], kf[tc], s[tc], 0, 0, 0);
        }
        __builtin_amdgcn_s_setprio(0);

        // --- causal mask (last tile only) -----------------------------------
        if (t0 + 63 > qw) {
            int qrow = qw + quad * 4;
#pragma unroll
            for (int tc = 0; tc < 4; ++tc) {
                int tcol = t0 + tc * 16 + lm;
#pragma unroll
                for (int rr = 0; rr < 4; ++rr)
                    if (tcol > qrow + rr) s[tc][rr] = -1e30f;
            }
        }

        // --- online softmax -------------------------------------------------
#pragma unroll
        for (int rr = 0; rr < 4; ++rr) {
            float tmx = fmaxf(fmaxf(s[0][rr], s[1][rr]),
                              fmaxf(s[2][rr], s[3][rr]));
#pragma unroll
            for (int off = 8; off >= 1; off >>= 1)
                tmx = fmaxf(tmx, __shfl_xor(tmx, off, 64));
            float mn    = fmaxf(mI[rr], tmx);
            float alpha = __expf(mI[rr] - mn);
            mI[rr]  = mn;
            float rs = 0.f;
#pragma unroll
            for (int tc = 0; tc < 4; ++tc) {
                float p = __expf(s[tc][rr] - mn);
                s[tc][rr] = p;
                rs += p;
            }
#pragma unroll
            for (int off = 8; off >= 1; off >>= 1)
                rs += __shfl_xor(rs, off, 64);
            lI[rr] = lI[rr] * alpha + rs;
#pragma unroll
            for (int dc = 0; dc < 8; ++dc)
                o[dc][rr] *= alpha;
        }

        // --- P -> LDS (C/D layout -> A layout round trip) -------------------
#pragma unroll
        for (int tc = 0; tc < 4; ++tc)
#pragma unroll
            for (int rr = 0; rr < 4; ++rr)
                Ps[w][(quad * 4 + rr) * PSTR + tc * 16 + lm] = f2bf(s[tc][rr]);

        // --- O += P V -------------------------------------------------------
        __builtin_amdgcn_s_setprio(1);
#pragma unroll
        for (int ss = 0; ss < 2; ++ss) {
            bf16x8 pf = *(const bf16x8*)&Ps[w][lm * PSTR + ss * 32 + quad * 8];
#pragma unroll
            for (int dc = 0; dc < 8; ++dc) {
                bf16x8 vf = *(const bf16x8*)&Vs[(dc * 16 + lm) * VSTR + ss * 32 + quad * 8];
                o[dc] = __builtin_amdgcn_mfma_f32_16x16x32_bf16(pf, vf, o[dc], 0, 0, 0);
            }
        }
        __builtin_amdgcn_s_setprio(0);
        __syncthreads();
    }

    // --- epilogue: O /= l, store bf16 ---------------------------------------
#pragma unroll
    for (int rr = 0; rr < 4; ++rr) {
        float inv = 1.f / lI[rr];
        size_t row = (size_t)(b * T_ + qw + quad * 4 + rr) * (H_ * HD_) + h * HD_;
#pragma unroll
        for (int dc = 0; dc < 8; ++dc)
            AO[row + dc * 16 + lm] = __float2bfloat16(o[dc][rr] * inv);
    }
}

// ---------------------------------------------------------------------------
extern "C" void kernel_launch(void* const* d_in, const int* in_sizes, int n_in,
                              void* d_out, int out_size, void* d_ws, size_t ws_size,
                              hipStream_t stream) {
    const float* x  = (const float*)d_in[0];
    const float* wq = (const float*)d_in[1];
    const float* wk = (const float*)d_in[2];
    const float* wv = (const float*)d_in[3];
    const float* wo = (const float*)d_in[4];
    const int* start_pos = (const int*)d_in[5];
    float* out = (float*)d_out;

    dim3 blk(256);
    const int M   = B_ * T_;      // 2048
    const int NQ  = H_ * HD_;     // 4096
    const int NKV = KVH_ * HD_;   // 1024

    const size_t NEED = 58720256; // 56 MiB

    if (ws_size >= NEED) {
        char* w = (char*)d_ws;
        __hip_bfloat16* Kb  = (__hip_bfloat16*)(w);                     // [2048][1024]
        __hip_bfloat16* Vtb = (__hip_bfloat16*)(w + (4u  << 20));       // [1024][2048]
        u16*            xb  = (u16*)(w + (8u  << 20));                  // [2048][4096]
        __hip_bfloat16* AOb = (__hip_bfloat16*)(w + (8u  << 20));       // reuses xb slot
        u16*            wS  = (u16*)(w + (24u << 20));                  // 32 MiB shared slot
        u16* wqb = wS;                       // [4096][4096] transposed
        u16* wkb = wS;                       // [1024][4096] transposed
        u16* wvb = wS + (size_t)NKV * D_;    // [1024][4096] transposed
        u16* wob = wS;                       // [4096][4096] transposed
        float* Qf = out;                     // Q fp32 in d_out (dead before out-proj)

        // 1. x -> bf16
        lconv<<<(M * D_ / 8 + 255) / 256, blk, 0, stream>>>(x, xb, M * D_ / 8);
        // 2. wq -> bf16 transposed
        tconv<false><<<dim3(NQ / 64, D_ / 64, 1), blk, 0, stream>>>(wq, wqb, nullptr, nullptr, D_, NQ);
        // 3. Q projection
        gemm_bf16<float, false, false>
            <<<dim3(NQ / 128, M / 128, 1), blk, 0, stream>>>(xb, wqb, Qf, nullptr, nullptr, M, NQ, D_);
        // 4. wk, wv -> bf16 transposed (wqb slot dead)
        tconv<true><<<dim3(NKV / 64, D_ / 64, 2), blk, 0, stream>>>(wk, wkb, wv, wvb, D_, NKV);
        // 5. K and V projections fused; V stored transposed
        gemm_bf16<__hip_bfloat16, true, true>
            <<<dim3(NKV / 128, M / 128, 2), blk, 0, stream>>>(xb, wkb, Kb, wvb, Vtb, M, NKV, D_);
        // 6. RoPE on Q and K
        rope_kernel<<<(M * (H_ + KVH_)) / 4, blk, 0, stream>>>(Qf, Kb, start_pos);
        // 7. wo -> bf16 transposed (wkb/wvb dead)
        tconv<false><<<dim3(NQ / 64, NQ / 64, 1), blk, 0, stream>>>(wo, wob, nullptr, nullptr, NQ, D_);
        // 8. Flash attention -> AOb (xb slot dead). Grid (T/64, H, B).
        flash_attn<<<dim3(T_ / 64, H_, B_), blk, 0, stream>>>(Qf, Kb, Vtb, AOb);
        // 9. Output projection -> fp32 out
        gemm_bf16<float, false, false>
            <<<dim3(D_ / 128, M / 128, 1), blk, 0, stream>>>((const u16*)AOb, wob, out, nullptr, nullptr, M, D_, NQ);
    } else {
        // ------- legacy fallback (24 MiB ws) -------
        float* Qf           = out;
        __hip_bfloat16* Kb  = (__hip_bfloat16*)d_ws;
        __hip_bfloat16* Vtb = Kb + (size_t)B_ * T_ * KVH_ * HD_;
        __hip_bfloat16* AOb = Vtb + (size_t)B_ * T_ * KVH_ * HD_;

        gemm_mfma<float, float, float, false, false>
            <<<dim3(NQ / 128, M / 128, 1), blk, 0, stream>>>(x, wq, Qf, nullptr, nullptr, M, NQ, D_);
        gemm_mfma<float, float, __hip_bfloat16, true, true>
            <<<dim3(NKV / 128, M / 128, 2), blk, 0, stream>>>(x, wk, Kb, wv, Vtb, M, NKV, D_);
        rope_kernel<<<(M * (H_ + KVH_)) / 4, blk, 0, stream>>>(Qf, Kb, start_pos);
        flash_attn<<<dim3(T_ / 64, H_, B_), blk, 0, stream>>>(Qf, Kb, Vtb, AOb);
        gemm_mfma<__hip_bfloat16, float, float, false, false>
            <<<dim3(D_ / 128, M / 128, 1), blk, 0, stream>>>(AOb, wo, out, nullptr, nullptr, M, D_, NQ);
    }
}

// Round 6
// 547.483 us; speedup vs baseline: 4.3878x; 1.0771x over previous
//
#include <hip/hip_runtime.h>
#include <hip/hip_bf16.h>
#include <math.h>

// Problem constants
#define B_    2
#define T_    1024
#define D_    4096
#define H_    32
#define KVH_  8
#define HD_   128
#define GROUP_ 4

static constexpr float SCORE_SCALE = 0.08838834764831845f; // 1/sqrt(128)

typedef __bf16 bf16x8 __attribute__((ext_vector_type(8)));
typedef float  f32x4  __attribute__((ext_vector_type(4)));
typedef unsigned short u16;

__device__ inline float toF(const __hip_bfloat16 v) { return __bfloat162float(v); }
__device__ inline float toF(const float v)          { return v; }

__device__ inline void storeC(float* p, float v)          { *p = v; }
__device__ inline void storeC(__hip_bfloat16* p, float v) { *p = __float2bfloat16(v); }

// fp32 -> bf16 bit pattern, round-to-nearest-even (finite inputs)
__device__ inline unsigned short f2bf(float f) {
    union { float f; unsigned u; } v; v.f = f;
    unsigned r = v.u + 0x7FFFu + ((v.u >> 16) & 1u);
    return (unsigned short)(r >> 16);
}

__device__ inline float bf2f(u16 u) {
    union { float f; unsigned u; } v; v.u = (unsigned)u << 16; return v.f;
}

// Direct global->LDS async copy, 16 B per lane. LDS dest is WAVE-UNIFORM
// base; HW adds lane*16. Global src is per-lane. [m97 pattern]
__device__ inline void gload_lds16(const u16* g, u16* l) {
    __builtin_amdgcn_global_load_lds(
        (const __attribute__((address_space(1))) void*)g,
        (__attribute__((address_space(3))) void*)l, 16, 0, 0);
}

// ===========================================================================
// FAST PATH
// ===========================================================================

// ---------------------------------------------------------------------------
// Linear fp32 -> bf16 convert (8 elems/thread, float4 in, int4 out)
// ---------------------------------------------------------------------------
__global__ __launch_bounds__(256) void lconv(const float* __restrict__ S,
                                             u16* __restrict__ D, int n8) {
    int i = blockIdx.x * 256 + threadIdx.x;
    if (i >= n8) return;
    const float4 a = *(const float4*)(S + (size_t)i * 8);
    const float4 b = *(const float4*)(S + (size_t)i * 8 + 4);
    union { int4 v; u16 u[8]; } t;
    t.u[0] = f2bf(a.x); t.u[1] = f2bf(a.y); t.u[2] = f2bf(a.z); t.u[3] = f2bf(a.w);
    t.u[4] = f2bf(b.x); t.u[5] = f2bf(b.y); t.u[6] = f2bf(b.z); t.u[7] = f2bf(b.w);
    *(int4*)(D + (size_t)i * 8) = t.v;
}

// ---------------------------------------------------------------------------
// Transpose + convert: src fp32 [R][Cc] row-major -> dst bf16 [Cc][R].
// 64x64 tiles via LDS; coalesced read (float4) and coalesced write (int4).
// ---------------------------------------------------------------------------
template <bool DUAL>
__global__ __launch_bounds__(256) void tconv(const float* __restrict__ S0,
                                             u16* __restrict__ D0,
                                             const float* __restrict__ S1,
                                             u16* __restrict__ D1,
                                             int R, int Cc) {
    const float* __restrict__ S = (DUAL && blockIdx.z) ? S1 : S0;
    u16* __restrict__ D         = (DUAL && blockIdx.z) ? D1 : D0;
    __shared__ u16 Tt[64][72];
    const int tid = threadIdx.x;
    const int r0 = blockIdx.y * 64, c0 = blockIdx.x * 64;
    {
        const int rr = tid >> 4, cc4 = (tid & 15) * 4;
#pragma unroll
        for (int e = 0; e < 4; ++e) {
            const int row = rr + e * 16;
            float4 v = *(const float4*)(S + (size_t)(r0 + row) * Cc + c0 + cc4);
            union { int2 w; u16 u[4]; } t;
            t.u[0] = f2bf(v.x); t.u[1] = f2bf(v.y); t.u[2] = f2bf(v.z); t.u[3] = f2bf(v.w);
            *(int2*)&Tt[row][cc4] = t.w;
        }
    }
    __syncthreads();
    {
        const int cc = tid >> 2, r8 = (tid & 3) * 8;
#pragma unroll
        for (int e = 0; e < 2; ++e) {
            const int rb = r8 + e * 32;
            union { int4 v; u16 u[8]; } t;
#pragma unroll
            for (int j = 0; j < 8; ++j) t.u[j] = Tt[rb + j][cc];
            *(int4*)(D + (size_t)(c0 + cc) * R + r0 + rb) = t.v;
        }
    }
}

// ---------------------------------------------------------------------------
// bf16 GEMM (m97 structure): C[M,N] = A[M,K] @ Bt[N,K]^T.
// BM=BN=128, BK=32, global_load_lds width=16 staging, linear LDS.
// DUAL: blockIdx.z picks (Bt0,C0)/(Bt1,C1). TRC1: z=1 output transposed.
// ---------------------------------------------------------------------------
template <typename TC, bool DUAL, bool TRC1>
__global__ __launch_bounds__(256, 2) void gemm_bf16(const u16* __restrict__ A,
                                                    const u16* __restrict__ Bt0,
                                                    TC* __restrict__ C0,
                                                    const u16* __restrict__ Bt1,
                                                    TC* __restrict__ C1,
                                                    int M, int N, int K) {
    const u16* __restrict__ Bt = (DUAL && blockIdx.z) ? Bt1 : Bt0;
    TC* __restrict__ C         = (DUAL && blockIdx.z) ? C1 : C0;

    __shared__ u16 As[128 * 32];   // 8 KiB
    __shared__ u16 Bs[128 * 32];   // 8 KiB

    const int tid   = threadIdx.x;
    const int lane  = tid & 63;
    const int w     = tid >> 6;
    const int waveM = w >> 1;
    const int waveN = w & 1;
    const int lm    = lane & 15;
    const int quad  = lane >> 4;
    const int bm    = blockIdx.y * 128;
    const int bn    = blockIdx.x * 128;

    const int srow = w * 16 + (lane >> 2);
    const int scol = (lane & 3) * 8;

    const u16* agp0 = A  + (size_t)(bm + srow)      * K + scol;
    const u16* agp1 = A  + (size_t)(bm + srow + 64) * K + scol;
    const u16* bgp0 = Bt + (size_t)(bn + srow)      * K + scol;
    const u16* bgp1 = Bt + (size_t)(bn + srow + 64) * K + scol;

    u16* al0 = &As[(w * 16)      * 32];
    u16* al1 = &As[(w * 16 + 64) * 32];
    u16* bl0 = &Bs[(w * 16)      * 32];
    u16* bl1 = &Bs[(w * 16 + 64) * 32];

    f32x4 acc[4][4];
#pragma unroll
    for (int i = 0; i < 4; ++i)
#pragma unroll
        for (int j = 0; j < 4; ++j) acc[i][j] = (f32x4){0.f, 0.f, 0.f, 0.f};

    for (int k0 = 0; k0 < K; k0 += 32) {
        gload_lds16(agp0 + k0, al0);
        gload_lds16(agp1 + k0, al1);
        gload_lds16(bgp0 + k0, bl0);
        gload_lds16(bgp1 + k0, bl1);
        __syncthreads();   // drains vmcnt -> tiles resident

        bf16x8 af[4], bfv[4];
#pragma unroll
        for (int i = 0; i < 4; ++i)
            af[i] = *(const bf16x8*)&As[(waveM * 64 + i * 16 + lm) * 32 + quad * 8];
#pragma unroll
        for (int j = 0; j < 4; ++j)
            bfv[j] = *(const bf16x8*)&Bs[(waveN * 64 + j * 16 + lm) * 32 + quad * 8];
#pragma unroll
        for (int i = 0; i < 4; ++i)
#pragma unroll
            for (int j = 0; j < 4; ++j)
                acc[i][j] = __builtin_amdgcn_mfma_f32_16x16x32_bf16(af[i], bfv[j], acc[i][j], 0, 0, 0);
        __syncthreads();   // frags consumed -> safe to overwrite
    }

    // C/D layout: col = lane&15, row = quad*4 + reg  [m89-verified]
    if (TRC1 && DUAL && blockIdx.z) {
#pragma unroll
        for (int i = 0; i < 4; ++i) {
            int row0 = bm + waveM * 64 + i * 16 + quad * 4;
#pragma unroll
            for (int j = 0; j < 4; ++j) {
                int col = bn + waveN * 64 + j * 16 + lm;
#pragma unroll
                for (int rr = 0; rr < 4; ++rr)
                    storeC(&C[(size_t)col * M + row0 + rr], acc[i][j][rr]);
            }
        }
    } else {
#pragma unroll
        for (int i = 0; i < 4; ++i) {
            int row0 = bm + waveM * 64 + i * 16 + quad * 4;
#pragma unroll
            for (int j = 0; j < 4; ++j) {
                int col = bn + waveN * 64 + j * 16 + lm;
#pragma unroll
                for (int rr = 0; rr < 4; ++rr)
                    storeC(&C[(size_t)(row0 + rr) * N + col], acc[i][j][rr]);
            }
        }
    }
}

// ===========================================================================
// LEGACY (fallback) GEMM — fused fp32->bf16 conversion. ws_size < 56 MiB.
// ===========================================================================
#define LSTR 40

template <typename TA, typename TB, typename TC, bool DUAL, bool TRC1>
__global__ __launch_bounds__(256) void gemm_mfma(const TA* __restrict__ A,
                                                 const TB* __restrict__ B0,
                                                 TC* __restrict__ C0,
                                                 const TB* __restrict__ B1,
                                                 TC* __restrict__ C1,
                                                 int M, int N, int K) {
    const TB* __restrict__ B = (DUAL && blockIdx.z) ? B1 : B0;
    TC* __restrict__ C       = (DUAL && blockIdx.z) ? C1 : C0;

    __shared__ unsigned short As[128 * LSTR];
    __shared__ unsigned short Bs[128 * LSTR];

    const int tid   = threadIdx.x;
    const int lane  = tid & 63;
    const int wv    = tid >> 6;
    const int waveM = wv >> 1;
    const int waveN = wv & 1;
    const int lm    = lane & 15;
    const int quad  = lane >> 4;
    const int bm    = blockIdx.y * 128;
    const int bn    = blockIdx.x * 128;

    f32x4 acc[4][4];
#pragma unroll
    for (int i = 0; i < 4; ++i)
#pragma unroll
        for (int j = 0; j < 4; ++j) acc[i][j] = (f32x4){0.f, 0.f, 0.f, 0.f};

    for (int k0 = 0; k0 < K; k0 += 32) {
#pragma unroll
        for (int e = 0; e < 8; ++e) {
            int p  = tid + e * 256;
            int r  = p >> 4, c2 = (p & 15) * 2;
            const TA* ap = A + (size_t)(bm + r) * K + k0 + c2;
            ushort2 t;
            t.x = f2bf(toF(ap[0]));
            t.y = f2bf(toF(ap[1]));
            *(ushort2*)&As[r * LSTR + c2] = t;
        }
#pragma unroll
        for (int e = 0; e < 8; ++e) {
            int p  = tid + e * 256;
            int n  = p & 127, k2 = (p >> 7) * 2;
            const TB* bp = B + (size_t)(k0 + k2) * N + bn + n;
            ushort2 t;
            t.x = f2bf(toF(bp[0]));
            t.y = f2bf(toF(bp[N]));
            *(ushort2*)&Bs[n * LSTR + k2] = t;
        }
        __syncthreads();

        bf16x8 af[4], bfr[4];
#pragma unroll
        for (int i = 0; i < 4; ++i)
            af[i] = *(const bf16x8*)&As[(waveM * 64 + i * 16 + lm) * LSTR + quad * 8];
#pragma unroll
        for (int j = 0; j < 4; ++j)
            bfr[j] = *(const bf16x8*)&Bs[(waveN * 64 + j * 16 + lm) * LSTR + quad * 8];
#pragma unroll
        for (int i = 0; i < 4; ++i)
#pragma unroll
            for (int j = 0; j < 4; ++j)
                acc[i][j] = __builtin_amdgcn_mfma_f32_16x16x32_bf16(af[i], bfr[j], acc[i][j], 0, 0, 0);
        __syncthreads();
    }

    if (TRC1 && DUAL && blockIdx.z) {
#pragma unroll
        for (int i = 0; i < 4; ++i) {
            int row0 = bm + waveM * 64 + i * 16 + quad * 4;
#pragma unroll
            for (int j = 0; j < 4; ++j) {
                int col = bn + waveN * 64 + j * 16 + lm;
#pragma unroll
                for (int rr = 0; rr < 4; ++rr)
                    storeC(&C[(size_t)col * M + row0 + rr], acc[i][j][rr]);
            }
        }
    } else {
#pragma unroll
        for (int i = 0; i < 4; ++i) {
            int row0 = bm + waveM * 64 + i * 16 + quad * 4;
#pragma unroll
            for (int j = 0; j < 4; ++j) {
                int col = bn + waveN * 64 + j * 16 + lm;
#pragma unroll
                for (int rr = 0; rr < 4; ++rr)
                    storeC(&C[(size_t)(row0 + rr) * N + col], acc[i][j][rr]);
            }
        }
    }
}

// ---------------------------------------------------------------------------
// RoPE (fast path): one block per token; 64 fp32 sincos into LDS (shared by
// all 40 heads), vectorized bf16x8 apply to Q[4096] + K[1024] in-place.
// ---------------------------------------------------------------------------
__device__ inline void rope_apply8(__hip_bfloat16* p, const float* cs,
                                   const float* sn, int t0) {
    union { int4 v; u16 u[8]; } in, outv;
    in.v = *(const int4*)p;
    float x[8];
#pragma unroll
    for (int i = 0; i < 8; ++i) x[i] = bf2f(in.u[i]);
#pragma unroll
    for (int pr = 0; pr < 4; ++pr) {
        float c0 = cs[t0 + 2 * pr],     s0 = sn[t0 + 2 * pr];
        float c1 = cs[t0 + 2 * pr + 1], s1 = sn[t0 + 2 * pr + 1];
        float e = x[2 * pr], o = x[2 * pr + 1];
        outv.u[2 * pr]     = f2bf(e * c0 - o * s0);
        outv.u[2 * pr + 1] = f2bf(o * c1 + e * s1);
    }
    *(int4*)p = outv.v;
}

__global__ __launch_bounds__(256) void rope_tok(__hip_bfloat16* __restrict__ Q,
                                                __hip_bfloat16* __restrict__ K,
                                                const int* __restrict__ start_pos) {
    __shared__ float cs[64], sn[64];
    const int n   = blockIdx.x;          // token row 0..2047
    const int tid = threadIdx.x;
    const int pos = *start_pos + (n % T_);

    if (tid < 64) {
        // inv_freq = 10000^(-2*tid/128) = exp2(-tid * log2(10000)/64)
        float invf = exp2f(-(float)tid * 0.20762050593045232f);
        float ang  = (float)pos * invf;
        float s, c;
        __sincosf(ang, &s, &c);
        // use precise sincos for safety:
        s = sinf(ang); c = cosf(ang);
        cs[tid] = c; sn[tid] = s;
    }
    __syncthreads();

    __hip_bfloat16* qrow = Q + (size_t)n * (H_ * HD_);
    __hip_bfloat16* krow = K + (size_t)n * (KVH_ * HD_);
#pragma unroll
    for (int e = 0; e < 2; ++e) {
        int g = tid + e * 256;
        rope_apply8(qrow + g * 8, cs, sn, (g * 8) & 63);
    }
    if (tid < 128)
        rope_apply8(krow + tid * 8, cs, sn, (tid * 8) & 63);
}

// ---------------------------------------------------------------------------
// RoPE (legacy fallback): per-element double-precision version.
// ---------------------------------------------------------------------------
template <typename TQ, typename TK>
__global__ __launch_bounds__(256) void rope_kernel(TQ* __restrict__ Q,
                                                   TK* __restrict__ Kt,
                                                   const int* __restrict__ start_pos) {
    int w    = blockIdx.x * 4 + (threadIdx.x >> 6);
    int lane = threadIdx.x & 63;
    int hh = w % (H_ + KVH_);
    int n  = w / (H_ + KVH_);
    int t  = n % T_;
    int pos = *start_pos + t;

    int e0 = 2 * lane, e1 = 2 * lane + 1;
    int j0 = e0 & 63,  j1 = e1 & 63;
    const double LN_BASE = 9.210340371976184; // ln(10000)
    double a0 = (double)pos * exp(-((double)(2 * j0) / 128.0) * LN_BASE);
    double a1 = (double)pos * exp(-((double)(2 * j1) / 128.0) * LN_BASE);
    float c0 = (float)cos(a0), s0 = (float)sin(a0);
    float c1 = (float)cos(a1), s1 = (float)sin(a1);

    if (hh < H_) {
        TQ* base = Q + (size_t)n * (H_ * HD_) + hh * HD_;
        float x0 = toF(base[e0]), x1 = toF(base[e1]);
        storeC(&base[e0], x0 * c0 - x1 * s0);
        storeC(&base[e1], x1 * c1 + x0 * s1);
    } else {
        TK* base = Kt + (size_t)n * (KVH_ * HD_) + (hh - H_) * HD_;
        float x0 = toF(base[e0]), x1 = toF(base[e1]);
        storeC(&base[e0], x0 * c0 - x1 * s0);
        storeC(&base[e1], x1 * c1 + x0 * s1);
    }
}

// ---------------------------------------------------------------------------
// Flash attention (causal, GQA) — 64-q-row blocks, XCD-decorrelated q-tiles.
// Templated on Q dtype: bf16 (fast path, direct frag load) or fp32 (legacy).
// SCORE_SCALE applied to scores (not Q).
// ---------------------------------------------------------------------------
#define KSTR 136   // Ks row stride (ushorts)
#define VSTR 72    // Vs row stride
#define PSTR 72    // Ps row stride

template <typename TQ>
__global__ __launch_bounds__(256, 2) void flash_attn(
        const TQ* __restrict__ Q,
        const __hip_bfloat16* __restrict__ K,
        const __hip_bfloat16* __restrict__ Vt,
        __hip_bfloat16* __restrict__ AO) {
    __shared__ unsigned short Ks[64 * KSTR];       // 17408 B
    __shared__ unsigned short Vs[128 * VSTR];      // 18432 B
    __shared__ unsigned short Ps[4][16 * PSTR];    //  9216 B (per-wave private)

    const int tid  = threadIdx.x;
    const int lane = tid & 63;
    const int w    = tid >> 6;
    const int quad = lane >> 4;
    const int lm   = lane & 15;

    const int qt  = (blockIdx.x + blockIdx.y) & 15;  // XCD-decorrelated q-tile
    const int qb  = qt * 64;
    const int h   = blockIdx.y;
    const int b   = blockIdx.z;
    const int kvh = h >> 2;           // GROUP_=4 query heads per KV head

    const int qw = qb + w * 16;       // wave's 16 q-rows

    bf16x8 qf[4];
    {
        const TQ* qrow = Q + (size_t)(b * T_ + qw + lm) * (H_ * HD_) + h * HD_;
        if constexpr (sizeof(TQ) == 2) {
#pragma unroll
            for (int ks = 0; ks < 4; ++ks)
                qf[ks] = *(const bf16x8*)(qrow + ks * 32 + quad * 8);
        } else {
#pragma unroll
            for (int ks = 0; ks < 4; ++ks) {
                const TQ* p4 = qrow + ks * 32 + quad * 8;
                float4 f0 = *(const float4*)(p4);
                float4 f1 = *(const float4*)(p4 + 4);
                union { bf16x8 v; unsigned short u[8]; } t;
                t.u[0] = f2bf(toF(f0.x)); t.u[1] = f2bf(toF(f0.y));
                t.u[2] = f2bf(toF(f0.z)); t.u[3] = f2bf(toF(f0.w));
                t.u[4] = f2bf(toF(f1.x)); t.u[5] = f2bf(toF(f1.y));
                t.u[6] = f2bf(toF(f1.z)); t.u[7] = f2bf(toF(f1.w));
                qf[ks] = t.v;
            }
        }
    }

    float mI[4], lI[4];
    f32x4 o[8];
#pragma unroll
    for (int rr = 0; rr < 4; ++rr) { mI[rr] = -1e30f; lI[rr] = 0.f; }
#pragma unroll
    for (int dc = 0; dc < 8; ++dc) o[dc] = (f32x4){0.f, 0.f, 0.f, 0.f};

    const int nkt = qt + 1;

    for (int kt = 0; kt < nkt; ++kt) {
        const int t0 = kt * 64;
#pragma unroll
        for (int e = 0; e < 4; ++e) {
            int p = tid + e * 256;
            int tt = p >> 4, d0 = (p & 15) * 8;
            int4 v = *(const int4*)(K + (size_t)(b * T_ + t0 + tt) * (KVH_ * HD_) + kvh * HD_ + d0);
            *(int4*)&Ks[tt * KSTR + d0] = v;
        }
#pragma unroll
        for (int e = 0; e < 4; ++e) {
            int p = tid + e * 256;
            int d = p >> 3, tm = (p & 7) * 8;
            int4 v = *(const int4*)(Vt + (size_t)(kvh * HD_ + d) * (B_ * T_) + b * T_ + t0 + tm);
            *(int4*)&Vs[d * VSTR + tm] = v;
        }
        __syncthreads();

        // --- S = Q K^T ------------------------------------------------------
        f32x4 s[4];
#pragma unroll
        for (int tc = 0; tc < 4; ++tc) s[tc] = (f32x4){0.f, 0.f, 0.f, 0.f};
        __builtin_amdgcn_s_setprio(1);
#pragma unroll
        for (int ks = 0; ks < 4; ++ks) {
            bf16x8 kf[4];
#pragma unroll
            for (int tc = 0; tc < 4; ++tc)
                kf[tc] = *(const bf16x8*)&Ks[(tc * 16 + lm) * KSTR + ks * 32 + quad * 8];
#pragma unroll
            for (int tc = 0; tc < 4; ++tc)
                s[tc] = __builtin_amdgcn_mfma_f32_16x16x32_bf16(qf[ks], kf[tc], s[tc], 0, 0, 0);
        }
        __builtin_amdgcn_s_setprio(0);

        // --- scale + causal mask -------------------------------------------
#pragma unroll
        for (int tc = 0; tc < 4; ++tc)
#pragma unroll
            for (int rr = 0; rr < 4; ++rr) s[tc][rr] *= SCORE_SCALE;

        if (t0 + 63 > qw) {
            int qrow = qw + quad * 4;
#pragma unroll
            for (int tc = 0; tc < 4; ++tc) {
                int tcol = t0 + tc * 16 + lm;
#pragma unroll
                for (int rr = 0; rr < 4; ++rr)
                    if (tcol > qrow + rr) s[tc][rr] = -1e30f;
            }
        }

        // --- online softmax -------------------------------------------------
#pragma unroll
        for (int rr = 0; rr < 4; ++rr) {
            float tmx = fmaxf(fmaxf(s[0][rr], s[1][rr]),
                              fmaxf(s[2][rr], s[3][rr]));
#pragma unroll
            for (int off = 8; off >= 1; off >>= 1)
                tmx = fmaxf(tmx, __shfl_xor(tmx, off, 64));
            float mn    = fmaxf(mI[rr], tmx);
            float alpha = __expf(mI[rr] - mn);
            mI[rr]  = mn;
            float rs = 0.f;
#pragma unroll
            for (int tc = 0; tc < 4; ++tc) {
                float p = __expf(s[tc][rr] - mn);
                s[tc][rr] = p;
                rs += p;
            }
#pragma unroll
            for (int off = 8; off >= 1; off >>= 1)
                rs += __shfl_xor(rs, off, 64);
            lI[rr] = lI[rr] * alpha + rs;
#pragma unroll
            for (int dc = 0; dc < 8; ++dc)
                o[dc][rr] *= alpha;
        }

        // --- P -> LDS (C/D layout -> A layout round trip) -------------------
#pragma unroll
        for (int tc = 0; tc < 4; ++tc)
#pragma unroll
            for (int rr = 0; rr < 4; ++rr)
                Ps[w][(quad * 4 + rr) * PSTR + tc * 16 + lm] = f2bf(s[tc][rr]);

        // --- O += P V -------------------------------------------------------
        __builtin_amdgcn_s_setprio(1);
#pragma unroll
        for (int ss = 0; ss < 2; ++ss) {
            bf16x8 pf = *(const bf16x8*)&Ps[w][lm * PSTR + ss * 32 + quad * 8];
#pragma unroll
            for (int dc = 0; dc < 8; ++dc) {
                bf16x8 vf = *(const bf16x8*)&Vs[(dc * 16 + lm) * VSTR + ss * 32 + quad * 8];
                o[dc] = __builtin_amdgcn_mfma_f32_16x16x32_bf16(pf, vf, o[dc], 0, 0, 0);
            }
        }
        __builtin_amdgcn_s_setprio(0);
        __syncthreads();
    }

    // --- epilogue ----------------------------------------------------------
#pragma unroll
    for (int rr = 0; rr < 4; ++rr) {
        float inv = 1.f / lI[rr];
        size_t row = (size_t)(b * T_ + qw + quad * 4 + rr) * (H_ * HD_) + h * HD_;
#pragma unroll
        for (int dc = 0; dc < 8; ++dc)
            AO[row + dc * 16 + lm] = __float2bfloat16(o[dc][rr] * inv);
    }
}

// ---------------------------------------------------------------------------
extern "C" void kernel_launch(void* const* d_in, const int* in_sizes, int n_in,
                              void* d_out, int out_size, void* d_ws, size_t ws_size,
                              hipStream_t stream) {
    const float* x  = (const float*)d_in[0];
    const float* wq = (const float*)d_in[1];
    const float* wk = (const float*)d_in[2];
    const float* wv = (const float*)d_in[3];
    const float* wo = (const float*)d_in[4];
    const int* start_pos = (const int*)d_in[5];
    float* out = (float*)d_out;

    dim3 blk(256);
    const int M   = B_ * T_;      // 2048
    const int NQ  = H_ * HD_;     // 4096
    const int NKV = KVH_ * HD_;   // 1024

    const size_t NEED = 58720256; // 56 MiB

    if (ws_size >= NEED) {
        // Workspace map (56 MiB) — identical to the R3 verified layout:
        //   w+ 0M: Kb  bf16 [2048][1024]                 (4 MiB)
        //   w+ 4M: Vtb bf16 [1024][2048] (V^T)           (4 MiB)
        //   w+ 8M: xb  bf16 [2048][4096] -> AOb (flash)  (16 MiB)
        //   w+24M: wS 32 MiB shared: wqb -> wkb+wvb -> wob
        //   d_out: Qb bf16 [2048][4096] (dead before out-proj)
        char* w = (char*)d_ws;
        __hip_bfloat16* Kb  = (__hip_bfloat16*)(w);
        __hip_bfloat16* Vtb = (__hip_bfloat16*)(w + (4u  << 20));
        u16*            xb  = (u16*)(w + (8u  << 20));
        __hip_bfloat16* AOb = (__hip_bfloat16*)(w + (8u  << 20));   // reuses xb slot
        u16*            wS  = (u16*)(w + (24u << 20));
        u16* wqb = wS;                       // [4096][4096] transposed
        u16* wkb = wS;                       // [1024][4096] transposed
        u16* wvb = wS + (size_t)NKV * D_;    // [1024][4096] transposed
        u16* wob = wS;                       // [4096][4096] transposed
        __hip_bfloat16* Qb = (__hip_bfloat16*)d_out;   // 16 MiB of 32, dead before out-proj

        // 1. x -> bf16
        lconv<<<(M * D_ / 8 + 255) / 256, blk, 0, stream>>>(x, xb, M * D_ / 8);
        // 2. wq -> bf16 transposed
        tconv<false><<<dim3(NQ / 64, D_ / 64, 1), blk, 0, stream>>>(wq, wqb, nullptr, nullptr, D_, NQ);
        // 3. Q projection -> bf16 Qb (in d_out)
        gemm_bf16<__hip_bfloat16, false, false>
            <<<dim3(NQ / 128, M / 128, 1), blk, 0, stream>>>(xb, wqb, Qb, nullptr, nullptr, M, NQ, D_);
        // 4. wk, wv -> bf16 transposed (wqb slot dead)
        tconv<true><<<dim3(NKV / 64, D_ / 64, 2), blk, 0, stream>>>(wk, wkb, wv, wvb, D_, NKV);
        // 5. K and V projections fused; V stored transposed
        gemm_bf16<__hip_bfloat16, true, true>
            <<<dim3(NKV / 128, M / 128, 2), blk, 0, stream>>>(xb, wkb, Kb, wvb, Vtb, M, NKV, D_);
        // 6. RoPE on Q and K (per-token shared trig, bf16 vectorized)
        rope_tok<<<M, blk, 0, stream>>>(Qb, Kb, start_pos);
        // 7. wo -> bf16 transposed (wkb/wvb dead)
        tconv<false><<<dim3(NQ / 64, NQ / 64, 1), blk, 0, stream>>>(wo, wob, nullptr, nullptr, NQ, D_);
        // 8. Flash attention -> AOb (xb slot dead)
        flash_attn<__hip_bfloat16><<<dim3(T_ / 64, H_, B_), blk, 0, stream>>>(Qb, Kb, Vtb, AOb);
        // 9. Output projection -> fp32 out (Qb region dead)
        gemm_bf16<float, false, false>
            <<<dim3(D_ / 128, M / 128, 1), blk, 0, stream>>>((const u16*)AOb, wob, out, nullptr, nullptr, M, D_, NQ);
    } else {
        // ------- legacy fallback (24 MiB ws) -------
        float* Qf           = out;
        __hip_bfloat16* Kb  = (__hip_bfloat16*)d_ws;
        __hip_bfloat16* Vtb = Kb + (size_t)B_ * T_ * KVH_ * HD_;
        __hip_bfloat16* AOb = Vtb + (size_t)B_ * T_ * KVH_ * HD_;

        gemm_mfma<float, float, float, false, false>
            <<<dim3(NQ / 128, M / 128, 1), blk, 0, stream>>>(x, wq, Qf, nullptr, nullptr, M, NQ, D_);
        gemm_mfma<float, float, __hip_bfloat16, true, true>
            <<<dim3(NKV / 128, M / 128, 2), blk, 0, stream>>>(x, wk, Kb, wv, Vtb, M, NKV, D_);
        rope_kernel<<<(M * (H_ + KVH_)) / 4, blk, 0, stream>>>(Qf, Kb, start_pos);
        flash_attn<float><<<dim3(T_ / 64, H_, B_), blk, 0, stream>>>(Qf, Kb, Vtb, AOb);
        gemm_mfma<__hip_bfloat16, float, float, false, false>
            <<<dim3(D_ / 128, M / 128, 1), blk, 0, stream>>>(AOb, wo, out, nullptr, nullptr, M, D_, NQ);
    }
}

// Round 7
// 495.108 us; speedup vs baseline: 4.8520x; 1.1058x over previous
//
#include <hip/hip_runtime.h>
#include <hip/hip_bf16.h>
#include <math.h>

// Problem constants
#define B_    2
#define T_    1024
#define D_    4096
#define H_    32
#define KVH_  8
#define HD_   128
#define GROUP_ 4

static constexpr float SCORE_SCALE = 0.08838834764831845f; // 1/sqrt(128)

typedef __bf16 bf16x8 __attribute__((ext_vector_type(8)));
typedef float  f32x4  __attribute__((ext_vector_type(4)));
typedef unsigned short u16;

__device__ inline float toF(const __hip_bfloat16 v) { return __bfloat162float(v); }
__device__ inline float toF(const float v)          { return v; }

__device__ inline void storeC(float* p, float v)          { *p = v; }
__device__ inline void storeC(__hip_bfloat16* p, float v) { *p = __float2bfloat16(v); }

// fp32 -> bf16 bit pattern, round-to-nearest-even (finite inputs)
__device__ inline unsigned short f2bf(float f) {
    union { float f; unsigned u; } v; v.f = f;
    unsigned r = v.u + 0x7FFFu + ((v.u >> 16) & 1u);
    return (unsigned short)(r >> 16);
}

__device__ inline float bf2f(u16 u) {
    union { float f; unsigned u; } v; v.u = (unsigned)u << 16; return v.f;
}

// Direct global->LDS async copy, 16 B per lane. LDS dest is WAVE-UNIFORM
// base; HW adds lane*16. Global src is per-lane. [m97 pattern]
__device__ inline void gload_lds16(const u16* g, u16* l) {
    __builtin_amdgcn_global_load_lds(
        (const __attribute__((address_space(1))) void*)g,
        (__attribute__((address_space(3))) void*)l, 16, 0, 0);
}

// ===========================================================================
// FAST PATH
// ===========================================================================

// ---------------------------------------------------------------------------
// Linear fp32 -> bf16 convert (8 elems/thread, float4 in, int4 out)
// ---------------------------------------------------------------------------
__global__ __launch_bounds__(256) void lconv(const float* __restrict__ S,
                                             u16* __restrict__ D, int n8) {
    int i = blockIdx.x * 256 + threadIdx.x;
    if (i >= n8) return;
    const float4 a = *(const float4*)(S + (size_t)i * 8);
    const float4 b = *(const float4*)(S + (size_t)i * 8 + 4);
    union { int4 v; u16 u[8]; } t;
    t.u[0] = f2bf(a.x); t.u[1] = f2bf(a.y); t.u[2] = f2bf(a.z); t.u[3] = f2bf(a.w);
    t.u[4] = f2bf(b.x); t.u[5] = f2bf(b.y); t.u[6] = f2bf(b.z); t.u[7] = f2bf(b.w);
    *(int4*)(D + (size_t)i * 8) = t.v;
}

// ---------------------------------------------------------------------------
// Transpose + convert: src fp32 [R][Cc] row-major -> dst bf16 [Cc][R].
// ---------------------------------------------------------------------------
template <bool DUAL>
__global__ __launch_bounds__(256) void tconv(const float* __restrict__ S0,
                                             u16* __restrict__ D0,
                                             const float* __restrict__ S1,
                                             u16* __restrict__ D1,
                                             int R, int Cc) {
    const float* __restrict__ S = (DUAL && blockIdx.z) ? S1 : S0;
    u16* __restrict__ D         = (DUAL && blockIdx.z) ? D1 : D0;
    __shared__ u16 Tt[64][72];
    const int tid = threadIdx.x;
    const int r0 = blockIdx.y * 64, c0 = blockIdx.x * 64;
    {
        const int rr = tid >> 4, cc4 = (tid & 15) * 4;
#pragma unroll
        for (int e = 0; e < 4; ++e) {
            const int row = rr + e * 16;
            float4 v = *(const float4*)(S + (size_t)(r0 + row) * Cc + c0 + cc4);
            union { int2 w; u16 u[4]; } t;
            t.u[0] = f2bf(v.x); t.u[1] = f2bf(v.y); t.u[2] = f2bf(v.z); t.u[3] = f2bf(v.w);
            *(int2*)&Tt[row][cc4] = t.w;
        }
    }
    __syncthreads();
    {
        const int cc = tid >> 2, r8 = (tid & 3) * 8;
#pragma unroll
        for (int e = 0; e < 2; ++e) {
            const int rb = r8 + e * 32;
            union { int4 v; u16 u[8]; } t;
#pragma unroll
            for (int j = 0; j < 8; ++j) t.u[j] = Tt[rb + j][cc];
            *(int4*)(D + (size_t)(c0 + cc) * R + r0 + rb) = t.v;
        }
    }
}

// ---------------------------------------------------------------------------
// Tri-transpose: wq/wk/wv fp32 [4096][Cc] -> bf16 [Cc][4096], one dispatch.
// z=0: wq (Cc=4096), z=1: wk (Cc=1024), z=2: wv (Cc=1024). Early-exit
// (blockIdx-uniform) for out-of-range x-blocks on the narrow matrices.
// ---------------------------------------------------------------------------
__global__ __launch_bounds__(256) void tconv3(const float* __restrict__ wq,
                                              const float* __restrict__ wk,
                                              const float* __restrict__ wv,
                                              u16* __restrict__ dq,
                                              u16* __restrict__ dk,
                                              u16* __restrict__ dv) {
    const int z = blockIdx.z;
    const float* __restrict__ S;
    u16* __restrict__ D;
    int Cc;
    if (z == 0)      { S = wq; D = dq; Cc = 4096; }
    else if (z == 1) { S = wk; D = dk; Cc = 1024; }
    else             { S = wv; D = dv; Cc = 1024; }
    if (blockIdx.x * 64 >= Cc) return;
    const int R = 4096;

    __shared__ u16 Tt[64][72];
    const int tid = threadIdx.x;
    const int r0 = blockIdx.y * 64, c0 = blockIdx.x * 64;
    {
        const int rr = tid >> 4, cc4 = (tid & 15) * 4;
#pragma unroll
        for (int e = 0; e < 4; ++e) {
            const int row = rr + e * 16;
            float4 v = *(const float4*)(S + (size_t)(r0 + row) * Cc + c0 + cc4);
            union { int2 w; u16 u[4]; } t;
            t.u[0] = f2bf(v.x); t.u[1] = f2bf(v.y); t.u[2] = f2bf(v.z); t.u[3] = f2bf(v.w);
            *(int2*)&Tt[row][cc4] = t.w;
        }
    }
    __syncthreads();
    {
        const int cc = tid >> 2, r8 = (tid & 3) * 8;
#pragma unroll
        for (int e = 0; e < 2; ++e) {
            const int rb = r8 + e * 32;
            union { int4 v; u16 u[8]; } t;
#pragma unroll
            for (int j = 0; j < 8; ++j) t.u[j] = Tt[rb + j][cc];
            *(int4*)(D + (size_t)(c0 + cc) * R + r0 + rb) = t.v;
        }
    }
}

// ---------------------------------------------------------------------------
// Fused QKV projection GEMM (m97 structure, 768 blocks = 3/CU):
//   swz 0..511:   Qb[2048][4096]   = xb @ wqb^T   (bf16, row-major)
//   swz 512..639: Kb[2048][1024]   = xb @ wkb^T   (bf16, row-major)
//   swz 640..767: Vtb[1024][2048]  = (xb @ wvb^T)^T (bf16, transposed)
// Bijective XCD swizzle (768 % 8 == 0).
// ---------------------------------------------------------------------------
__global__ __launch_bounds__(256, 3) void gemm_qkv(const u16* __restrict__ A,
                                                   const u16* __restrict__ wqb,
                                                   const u16* __restrict__ wkb,
                                                   const u16* __restrict__ wvb,
                                                   __hip_bfloat16* __restrict__ Qb,
                                                   __hip_bfloat16* __restrict__ Kb,
                                                   __hip_bfloat16* __restrict__ Vtb) {
    const int K = D_;          // 4096
    const int M = B_ * T_;     // 2048

    const int bid = blockIdx.x;
    const int swz = (bid & 7) * 96 + (bid >> 3);   // XCD chunking, bijective

    const u16* __restrict__ Bt;
    __hip_bfloat16* __restrict__ C;
    int bm, bn, N;
    bool tr;
    if (swz < 512)      { Bt = wqb; C = Qb;  N = 4096; bm = (swz >> 5) * 128; bn = (swz & 31) * 128; tr = false; }
    else if (swz < 640) { int i = swz - 512; Bt = wkb; C = Kb;  N = 1024; bm = (i >> 3) * 128; bn = (i & 7) * 128; tr = false; }
    else                { int i = swz - 640; Bt = wvb; C = Vtb; N = 1024; bm = (i >> 3) * 128; bn = (i & 7) * 128; tr = true; }

    __shared__ u16 As[128 * 32];   // 8 KiB
    __shared__ u16 Bs[128 * 32];   // 8 KiB

    const int tid   = threadIdx.x;
    const int lane  = tid & 63;
    const int w     = tid >> 6;
    const int waveM = w >> 1;
    const int waveN = w & 1;
    const int lm    = lane & 15;
    const int quad  = lane >> 4;

    const int srow = w * 16 + (lane >> 2);
    const int scol = (lane & 3) * 8;

    const u16* agp0 = A  + (size_t)(bm + srow)      * K + scol;
    const u16* agp1 = A  + (size_t)(bm + srow + 64) * K + scol;
    const u16* bgp0 = Bt + (size_t)(bn + srow)      * K + scol;
    const u16* bgp1 = Bt + (size_t)(bn + srow + 64) * K + scol;

    u16* al0 = &As[(w * 16)      * 32];
    u16* al1 = &As[(w * 16 + 64) * 32];
    u16* bl0 = &Bs[(w * 16)      * 32];
    u16* bl1 = &Bs[(w * 16 + 64) * 32];

    f32x4 acc[4][4];
#pragma unroll
    for (int i = 0; i < 4; ++i)
#pragma unroll
        for (int j = 0; j < 4; ++j) acc[i][j] = (f32x4){0.f, 0.f, 0.f, 0.f};

    for (int k0 = 0; k0 < K; k0 += 32) {
        gload_lds16(agp0 + k0, al0);
        gload_lds16(agp1 + k0, al1);
        gload_lds16(bgp0 + k0, bl0);
        gload_lds16(bgp1 + k0, bl1);
        __syncthreads();

        bf16x8 af[4], bfv[4];
#pragma unroll
        for (int i = 0; i < 4; ++i)
            af[i] = *(const bf16x8*)&As[(waveM * 64 + i * 16 + lm) * 32 + quad * 8];
#pragma unroll
        for (int j = 0; j < 4; ++j)
            bfv[j] = *(const bf16x8*)&Bs[(waveN * 64 + j * 16 + lm) * 32 + quad * 8];
#pragma unroll
        for (int i = 0; i < 4; ++i)
#pragma unroll
            for (int j = 0; j < 4; ++j)
                acc[i][j] = __builtin_amdgcn_mfma_f32_16x16x32_bf16(af[i], bfv[j], acc[i][j], 0, 0, 0);
        __syncthreads();
    }

    // C/D layout: col = lane&15, row = quad*4 + reg  [m89-verified]
    if (tr) {
#pragma unroll
        for (int i = 0; i < 4; ++i) {
            int row0 = bm + waveM * 64 + i * 16 + quad * 4;
#pragma unroll
            for (int j = 0; j < 4; ++j) {
                int col = bn + waveN * 64 + j * 16 + lm;
#pragma unroll
                for (int rr = 0; rr < 4; ++rr)
                    C[(size_t)col * M + row0 + rr] = __float2bfloat16(acc[i][j][rr]);
            }
        }
    } else {
#pragma unroll
        for (int i = 0; i < 4; ++i) {
            int row0 = bm + waveM * 64 + i * 16 + quad * 4;
#pragma unroll
            for (int j = 0; j < 4; ++j) {
                int col = bn + waveN * 64 + j * 16 + lm;
#pragma unroll
                for (int rr = 0; rr < 4; ++rr)
                    C[(size_t)(row0 + rr) * N + col] = __float2bfloat16(acc[i][j][rr]);
            }
        }
    }
}

// ---------------------------------------------------------------------------
// bf16 GEMM (m97 structure): C[M,N] = A[M,K] @ Bt[N,K]^T.
// DUAL: blockIdx.z picks (Bt0,C0)/(Bt1,C1). TRC1: z=1 output transposed.
// ---------------------------------------------------------------------------
template <typename TC, bool DUAL, bool TRC1>
__global__ __launch_bounds__(256, 2) void gemm_bf16(const u16* __restrict__ A,
                                                    const u16* __restrict__ Bt0,
                                                    TC* __restrict__ C0,
                                                    const u16* __restrict__ Bt1,
                                                    TC* __restrict__ C1,
                                                    int M, int N, int K) {
    const u16* __restrict__ Bt = (DUAL && blockIdx.z) ? Bt1 : Bt0;
    TC* __restrict__ C         = (DUAL && blockIdx.z) ? C1 : C0;

    __shared__ u16 As[128 * 32];   // 8 KiB
    __shared__ u16 Bs[128 * 32];   // 8 KiB

    const int tid   = threadIdx.x;
    const int lane  = tid & 63;
    const int w     = tid >> 6;
    const int waveM = w >> 1;
    const int waveN = w & 1;
    const int lm    = lane & 15;
    const int quad  = lane >> 4;
    const int bm    = blockIdx.y * 128;
    const int bn    = blockIdx.x * 128;

    const int srow = w * 16 + (lane >> 2);
    const int scol = (lane & 3) * 8;

    const u16* agp0 = A  + (size_t)(bm + srow)      * K + scol;
    const u16* agp1 = A  + (size_t)(bm + srow + 64) * K + scol;
    const u16* bgp0 = Bt + (size_t)(bn + srow)      * K + scol;
    const u16* bgp1 = Bt + (size_t)(bn + srow + 64) * K + scol;

    u16* al0 = &As[(w * 16)      * 32];
    u16* al1 = &As[(w * 16 + 64) * 32];
    u16* bl0 = &Bs[(w * 16)      * 32];
    u16* bl1 = &Bs[(w * 16 + 64) * 32];

    f32x4 acc[4][4];
#pragma unroll
    for (int i = 0; i < 4; ++i)
#pragma unroll
        for (int j = 0; j < 4; ++j) acc[i][j] = (f32x4){0.f, 0.f, 0.f, 0.f};

    for (int k0 = 0; k0 < K; k0 += 32) {
        gload_lds16(agp0 + k0, al0);
        gload_lds16(agp1 + k0, al1);
        gload_lds16(bgp0 + k0, bl0);
        gload_lds16(bgp1 + k0, bl1);
        __syncthreads();   // drains vmcnt -> tiles resident

        bf16x8 af[4], bfv[4];
#pragma unroll
        for (int i = 0; i < 4; ++i)
            af[i] = *(const bf16x8*)&As[(waveM * 64 + i * 16 + lm) * 32 + quad * 8];
#pragma unroll
        for (int j = 0; j < 4; ++j)
            bfv[j] = *(const bf16x8*)&Bs[(waveN * 64 + j * 16 + lm) * 32 + quad * 8];
#pragma unroll
        for (int i = 0; i < 4; ++i)
#pragma unroll
            for (int j = 0; j < 4; ++j)
                acc[i][j] = __builtin_amdgcn_mfma_f32_16x16x32_bf16(af[i], bfv[j], acc[i][j], 0, 0, 0);
        __syncthreads();   // frags consumed -> safe to overwrite
    }

    // C/D layout: col = lane&15, row = quad*4 + reg  [m89-verified]
    if (TRC1 && DUAL && blockIdx.z) {
#pragma unroll
        for (int i = 0; i < 4; ++i) {
            int row0 = bm + waveM * 64 + i * 16 + quad * 4;
#pragma unroll
            for (int j = 0; j < 4; ++j) {
                int col = bn + waveN * 64 + j * 16 + lm;
#pragma unroll
                for (int rr = 0; rr < 4; ++rr)
                    storeC(&C[(size_t)col * M + row0 + rr], acc[i][j][rr]);
            }
        }
    } else {
#pragma unroll
        for (int i = 0; i < 4; ++i) {
            int row0 = bm + waveM * 64 + i * 16 + quad * 4;
#pragma unroll
            for (int j = 0; j < 4; ++j) {
                int col = bn + waveN * 64 + j * 16 + lm;
#pragma unroll
                for (int rr = 0; rr < 4; ++rr)
                    storeC(&C[(size_t)(row0 + rr) * N + col], acc[i][j][rr]);
            }
        }
    }
}

// ===========================================================================
// LEGACY (fallback) GEMM — fused fp32->bf16 conversion. ws_size < 56 MiB.
// ===========================================================================
#define LSTR 40

template <typename TA, typename TB, typename TC, bool DUAL, bool TRC1>
__global__ __launch_bounds__(256) void gemm_mfma(const TA* __restrict__ A,
                                                 const TB* __restrict__ B0,
                                                 TC* __restrict__ C0,
                                                 const TB* __restrict__ B1,
                                                 TC* __restrict__ C1,
                                                 int M, int N, int K) {
    const TB* __restrict__ B = (DUAL && blockIdx.z) ? B1 : B0;
    TC* __restrict__ C       = (DUAL && blockIdx.z) ? C1 : C0;

    __shared__ unsigned short As[128 * LSTR];
    __shared__ unsigned short Bs[128 * LSTR];

    const int tid   = threadIdx.x;
    const int lane  = tid & 63;
    const int wv    = tid >> 6;
    const int waveM = wv >> 1;
    const int waveN = wv & 1;
    const int lm    = lane & 15;
    const int quad  = lane >> 4;
    const int bm    = blockIdx.y * 128;
    const int bn    = blockIdx.x * 128;

    f32x4 acc[4][4];
#pragma unroll
    for (int i = 0; i < 4; ++i)
#pragma unroll
        for (int j = 0; j < 4; ++j) acc[i][j] = (f32x4){0.f, 0.f, 0.f, 0.f};

    for (int k0 = 0; k0 < K; k0 += 32) {
#pragma unroll
        for (int e = 0; e < 8; ++e) {
            int p  = tid + e * 256;
            int r  = p >> 4, c2 = (p & 15) * 2;
            const TA* ap = A + (size_t)(bm + r) * K + k0 + c2;
            ushort2 t;
            t.x = f2bf(toF(ap[0]));
            t.y = f2bf(toF(ap[1]));
            *(ushort2*)&As[r * LSTR + c2] = t;
        }
#pragma unroll
        for (int e = 0; e < 8; ++e) {
            int p  = tid + e * 256;
            int n  = p & 127, k2 = (p >> 7) * 2;
            const TB* bp = B + (size_t)(k0 + k2) * N + bn + n;
            ushort2 t;
            t.x = f2bf(toF(bp[0]));
            t.y = f2bf(toF(bp[N]));
            *(ushort2*)&Bs[n * LSTR + k2] = t;
        }
        __syncthreads();

        bf16x8 af[4], bfr[4];
#pragma unroll
        for (int i = 0; i < 4; ++i)
            af[i] = *(const bf16x8*)&As[(waveM * 64 + i * 16 + lm) * LSTR + quad * 8];
#pragma unroll
        for (int j = 0; j < 4; ++j)
            bfr[j] = *(const bf16x8*)&Bs[(waveN * 64 + j * 16 + lm) * LSTR + quad * 8];
#pragma unroll
        for (int i = 0; i < 4; ++i)
#pragma unroll
            for (int j = 0; j < 4; ++j)
                acc[i][j] = __builtin_amdgcn_mfma_f32_16x16x32_bf16(af[i], bfr[j], acc[i][j], 0, 0, 0);
        __syncthreads();
    }

    if (TRC1 && DUAL && blockIdx.z) {
#pragma unroll
        for (int i = 0; i < 4; ++i) {
            int row0 = bm + waveM * 64 + i * 16 + quad * 4;
#pragma unroll
            for (int j = 0; j < 4; ++j) {
                int col = bn + waveN * 64 + j * 16 + lm;
#pragma unroll
                for (int rr = 0; rr < 4; ++rr)
                    storeC(&C[(size_t)col * M + row0 + rr], acc[i][j][rr]);
            }
        }
    } else {
#pragma unroll
        for (int i = 0; i < 4; ++i) {
            int row0 = bm + waveM * 64 + i * 16 + quad * 4;
#pragma unroll
            for (int j = 0; j < 4; ++j) {
                int col = bn + waveN * 64 + j * 16 + lm;
#pragma unroll
                for (int rr = 0; rr < 4; ++rr)
                    storeC(&C[(size_t)(row0 + rr) * N + col], acc[i][j][rr]);
            }
        }
    }
}

// ---------------------------------------------------------------------------
// RoPE (fast path): one block per token; 64 fp32 sincos into LDS (shared by
// all 40 heads), vectorized bf16x8 apply to Q[4096] + K[1024] in-place.
// ---------------------------------------------------------------------------
__device__ inline void rope_apply8(__hip_bfloat16* p, const float* cs,
                                   const float* sn, int t0) {
    union { int4 v; u16 u[8]; } in, outv;
    in.v = *(const int4*)p;
    float x[8];
#pragma unroll
    for (int i = 0; i < 8; ++i) x[i] = bf2f(in.u[i]);
#pragma unroll
    for (int pr = 0; pr < 4; ++pr) {
        float c0 = cs[t0 + 2 * pr],     s0 = sn[t0 + 2 * pr];
        float c1 = cs[t0 + 2 * pr + 1], s1 = sn[t0 + 2 * pr + 1];
        float e = x[2 * pr], o = x[2 * pr + 1];
        outv.u[2 * pr]     = f2bf(e * c0 - o * s0);
        outv.u[2 * pr + 1] = f2bf(o * c1 + e * s1);
    }
    *(int4*)p = outv.v;
}

__global__ __launch_bounds__(256) void rope_tok(__hip_bfloat16* __restrict__ Q,
                                                __hip_bfloat16* __restrict__ K,
                                                const int* __restrict__ start_pos) {
    __shared__ float cs[64], sn[64];
    const int n   = blockIdx.x;          // token row 0..2047
    const int tid = threadIdx.x;
    const int pos = *start_pos + (n % T_);

    if (tid < 64) {
        // inv_freq = 10000^(-2*tid/128) = exp2(-tid * log2(10000)/64)
        float invf = exp2f(-(float)tid * 0.20762050593045232f);
        float ang  = (float)pos * invf;
        cs[tid] = cosf(ang); sn[tid] = sinf(ang);
    }
    __syncthreads();

    __hip_bfloat16* qrow = Q + (size_t)n * (H_ * HD_);
    __hip_bfloat16* krow = K + (size_t)n * (KVH_ * HD_);
#pragma unroll
    for (int e = 0; e < 2; ++e) {
        int g = tid + e * 256;
        rope_apply8(qrow + g * 8, cs, sn, (g * 8) & 63);
    }
    if (tid < 128)
        rope_apply8(krow + tid * 8, cs, sn, (tid * 8) & 63);
}

// ---------------------------------------------------------------------------
// RoPE (legacy fallback): per-element double-precision version.
// ---------------------------------------------------------------------------
template <typename TQ, typename TK>
__global__ __launch_bounds__(256) void rope_kernel(TQ* __restrict__ Q,
                                                   TK* __restrict__ Kt,
                                                   const int* __restrict__ start_pos) {
    int w    = blockIdx.x * 4 + (threadIdx.x >> 6);
    int lane = threadIdx.x & 63;
    int hh = w % (H_ + KVH_);
    int n  = w / (H_ + KVH_);
    int t  = n % T_;
    int pos = *start_pos + t;

    int e0 = 2 * lane, e1 = 2 * lane + 1;
    int j0 = e0 & 63,  j1 = e1 & 63;
    const double LN_BASE = 9.210340371976184; // ln(10000)
    double a0 = (double)pos * exp(-((double)(2 * j0) / 128.0) * LN_BASE);
    double a1 = (double)pos * exp(-((double)(2 * j1) / 128.0) * LN_BASE);
    float c0 = (float)cos(a0), s0 = (float)sin(a0);
    float c1 = (float)cos(a1), s1 = (float)sin(a1);

    if (hh < H_) {
        TQ* base = Q + (size_t)n * (H_ * HD_) + hh * HD_;
        float x0 = toF(base[e0]), x1 = toF(base[e1]);
        storeC(&base[e0], x0 * c0 - x1 * s0);
        storeC(&base[e1], x1 * c1 + x0 * s1);
    } else {
        TK* base = Kt + (size_t)n * (KVH_ * HD_) + (hh - H_) * HD_;
        float x0 = toF(base[e0]), x1 = toF(base[e1]);
        storeC(&base[e0], x0 * c0 - x1 * s0);
        storeC(&base[e1], x1 * c1 + x0 * s1);
    }
}

// ---------------------------------------------------------------------------
// Flash attention (causal, GQA) — 64-q-row blocks, XCD-decorrelated q-tiles.
// Templated on Q dtype: bf16 (fast path) or fp32 (legacy).
// ---------------------------------------------------------------------------
#define KSTR 136   // Ks row stride (ushorts)
#define VSTR 72    // Vs row stride
#define PSTR 72    // Ps row stride

template <typename TQ>
__global__ __launch_bounds__(256, 2) void flash_attn(
        const TQ* __restrict__ Q,
        const __hip_bfloat16* __restrict__ K,
        const __hip_bfloat16* __restrict__ Vt,
        __hip_bfloat16* __restrict__ AO) {
    __shared__ unsigned short Ks[64 * KSTR];       // 17408 B
    __shared__ unsigned short Vs[128 * VSTR];      // 18432 B
    __shared__ unsigned short Ps[4][16 * PSTR];    //  9216 B (per-wave private)

    const int tid  = threadIdx.x;
    const int lane = tid & 63;
    const int w    = tid >> 6;
    const int quad = lane >> 4;
    const int lm   = lane & 15;

    const int qt  = (blockIdx.x + blockIdx.y) & 15;  // XCD-decorrelated q-tile
    const int qb  = qt * 64;
    const int h   = blockIdx.y;
    const int b   = blockIdx.z;
    const int kvh = h >> 2;           // GROUP_=4 query heads per KV head

    const int qw = qb + w * 16;       // wave's 16 q-rows

    bf16x8 qf[4];
    {
        const TQ* qrow = Q + (size_t)(b * T_ + qw + lm) * (H_ * HD_) + h * HD_;
        if constexpr (sizeof(TQ) == 2) {
#pragma unroll
            for (int ks = 0; ks < 4; ++ks)
                qf[ks] = *(const bf16x8*)(qrow + ks * 32 + quad * 8);
        } else {
#pragma unroll
            for (int ks = 0; ks < 4; ++ks) {
                const TQ* p4 = qrow + ks * 32 + quad * 8;
                float4 f0 = *(const float4*)(p4);
                float4 f1 = *(const float4*)(p4 + 4);
                union { bf16x8 v; unsigned short u[8]; } t;
                t.u[0] = f2bf(toF(f0.x)); t.u[1] = f2bf(toF(f0.y));
                t.u[2] = f2bf(toF(f0.z)); t.u[3] = f2bf(toF(f0.w));
                t.u[4] = f2bf(toF(f1.x)); t.u[5] = f2bf(toF(f1.y));
                t.u[6] = f2bf(toF(f1.z)); t.u[7] = f2bf(toF(f1.w));
                qf[ks] = t.v;
            }
        }
    }

    float mI[4], lI[4];
    f32x4 o[8];
#pragma unroll
    for (int rr = 0; rr < 4; ++rr) { mI[rr] = -1e30f; lI[rr] = 0.f; }
#pragma unroll
    for (int dc = 0; dc < 8; ++dc) o[dc] = (f32x4){0.f, 0.f, 0.f, 0.f};

    const int nkt = qt + 1;

    for (int kt = 0; kt < nkt; ++kt) {
        const int t0 = kt * 64;
#pragma unroll
        for (int e = 0; e < 4; ++e) {
            int p = tid + e * 256;
            int tt = p >> 4, d0 = (p & 15) * 8;
            int4 v = *(const int4*)(K + (size_t)(b * T_ + t0 + tt) * (KVH_ * HD_) + kvh * HD_ + d0);
            *(int4*)&Ks[tt * KSTR + d0] = v;
        }
#pragma unroll
        for (int e = 0; e < 4; ++e) {
            int p = tid + e * 256;
            int d = p >> 3, tm = (p & 7) * 8;
            int4 v = *(const int4*)(Vt + (size_t)(kvh * HD_ + d) * (B_ * T_) + b * T_ + t0 + tm);
            *(int4*)&Vs[d * VSTR + tm] = v;
        }
        __syncthreads();

        // --- S = Q K^T ------------------------------------------------------
        f32x4 s[4];
#pragma unroll
        for (int tc = 0; tc < 4; ++tc) s[tc] = (f32x4){0.f, 0.f, 0.f, 0.f};
        __builtin_amdgcn_s_setprio(1);
#pragma unroll
        for (int ks = 0; ks < 4; ++ks) {
            bf16x8 kf[4];
#pragma unroll
            for (int tc = 0; tc < 4; ++tc)
                kf[tc] = *(const bf16x8*)&Ks[(tc * 16 + lm) * KSTR + ks * 32 + quad * 8];
#pragma unroll
            for (int tc = 0; tc < 4; ++tc)
                s[tc] = __builtin_amdgcn_mfma_f32_16x16x32_bf16(qf[ks], kf[tc], s[tc], 0, 0, 0);
        }
        __builtin_amdgcn_s_setprio(0);

        // --- scale + causal mask -------------------------------------------
#pragma unroll
        for (int tc = 0; tc < 4; ++tc)
#pragma unroll
            for (int rr = 0; rr < 4; ++rr) s[tc][rr] *= SCORE_SCALE;

        if (t0 + 63 > qw) {
            int qrow = qw + quad * 4;
#pragma unroll
            for (int tc = 0; tc < 4; ++tc) {
                int tcol = t0 + tc * 16 + lm;
#pragma unroll
                for (int rr = 0; rr < 4; ++rr)
                    if (tcol > qrow + rr) s[tc][rr] = -1e30f;
            }
        }

        // --- online softmax -------------------------------------------------
#pragma unroll
        for (int rr = 0; rr < 4; ++rr) {
            float tmx = fmaxf(fmaxf(s[0][rr], s[1][rr]),
                              fmaxf(s[2][rr], s[3][rr]));
#pragma unroll
            for (int off = 8; off >= 1; off >>= 1)
                tmx = fmaxf(tmx, __shfl_xor(tmx, off, 64));
            float mn    = fmaxf(mI[rr], tmx);
            float alpha = __expf(mI[rr] - mn);
            mI[rr]  = mn;
            float rs = 0.f;
#pragma unroll
            for (int tc = 0; tc < 4; ++tc) {
                float p = __expf(s[tc][rr] - mn);
                s[tc][rr] = p;
                rs += p;
            }
#pragma unroll
            for (int off = 8; off >= 1; off >>= 1)
                rs += __shfl_xor(rs, off, 64);
            lI[rr] = lI[rr] * alpha + rs;
#pragma unroll
            for (int dc = 0; dc < 8; ++dc)
                o[dc][rr] *= alpha;
        }

        // --- P -> LDS (C/D layout -> A layout round trip) -------------------
#pragma unroll
        for (int tc = 0; tc < 4; ++tc)
#pragma unroll
            for (int rr = 0; rr < 4; ++rr)
                Ps[w][(quad * 4 + rr) * PSTR + tc * 16 + lm] = f2bf(s[tc][rr]);

        // --- O += P V -------------------------------------------------------
        __builtin_amdgcn_s_setprio(1);
#pragma unroll
        for (int ss = 0; ss < 2; ++ss) {
            bf16x8 pf = *(const bf16x8*)&Ps[w][lm * PSTR + ss * 32 + quad * 8];
#pragma unroll
            for (int dc = 0; dc < 8; ++dc) {
                bf16x8 vf = *(const bf16x8*)&Vs[(dc * 16 + lm) * VSTR + ss * 32 + quad * 8];
                o[dc] = __builtin_amdgcn_mfma_f32_16x16x32_bf16(pf, vf, o[dc], 0, 0, 0);
            }
        }
        __builtin_amdgcn_s_setprio(0);
        __syncthreads();
    }

    // --- epilogue ----------------------------------------------------------
#pragma unroll
    for (int rr = 0; rr < 4; ++rr) {
        float inv = 1.f / lI[rr];
        size_t row = (size_t)(b * T_ + qw + quad * 4 + rr) * (H_ * HD_) + h * HD_;
#pragma unroll
        for (int dc = 0; dc < 8; ++dc)
            AO[row + dc * 16 + lm] = __float2bfloat16(o[dc][rr] * inv);
    }
}

// ---------------------------------------------------------------------------
extern "C" void kernel_launch(void* const* d_in, const int* in_sizes, int n_in,
                              void* d_out, int out_size, void* d_ws, size_t ws_size,
                              hipStream_t stream) {
    const float* x  = (const float*)d_in[0];
    const float* wq = (const float*)d_in[1];
    const float* wk = (const float*)d_in[2];
    const float* wv = (const float*)d_in[3];
    const float* wo = (const float*)d_in[4];
    const int* start_pos = (const int*)d_in[5];
    float* out = (float*)d_out;

    dim3 blk(256);
    const int M   = B_ * T_;      // 2048
    const int NQ  = H_ * HD_;     // 4096
    const int NKV = KVH_ * HD_;   // 1024

    const size_t NEED_A = 75497472; // 72 MiB — fused-QKV tier
    const size_t NEED_B = 58720256; // 56 MiB — verified R6 tier

    if (ws_size >= NEED_A) {
        // Tier A (72 MiB):
        //   w+ 0M: Kb  bf16 [2048][1024]                  (4 MiB)
        //   w+ 4M: Vtb bf16 [1024][2048] (V^T)            (4 MiB)
        //   w+ 8M: xb  bf16 [2048][4096] -> AOb (flash)   (16 MiB)
        //   w+24M: wqb bf16 [4096][4096]T -> wob          (32 MiB)
        //   w+56M: wkb bf16 [1024][4096]T                 (8 MiB)
        //   w+64M: wvb bf16 [1024][4096]T                 (8 MiB)
        //   d_out: Qb  bf16 [2048][4096] (dead before out-proj)
        char* w = (char*)d_ws;
        __hip_bfloat16* Kb  = (__hip_bfloat16*)(w);
        __hip_bfloat16* Vtb = (__hip_bfloat16*)(w + (4u  << 20));
        u16*            xb  = (u16*)(w + (8u  << 20));
        __hip_bfloat16* AOb = (__hip_bfloat16*)(w + (8u  << 20));
        u16*            wqb = (u16*)(w + (24u << 20));
        u16*            wob = (u16*)(w + (24u << 20));   // overlays wqb (dead after gemm_qkv)
        u16*            wkb = (u16*)(w + (56u << 20));
        u16*            wvb = (u16*)(w + (64u << 20));
        __hip_bfloat16* Qb  = (__hip_bfloat16*)d_out;

        // 1. x -> bf16
        lconv<<<(M * D_ / 8 + 255) / 256, blk, 0, stream>>>(x, xb, M * D_ / 8);
        // 2. wq/wk/wv -> bf16 transposed (one dispatch)
        tconv3<<<dim3(NQ / 64, D_ / 64, 3), blk, 0, stream>>>(wq, wk, wv, wqb, wkb, wvb);
        // 3. Fused QKV projection (768 blocks, 3/CU)
        gemm_qkv<<<768, blk, 0, stream>>>(xb, wqb, wkb, wvb, Qb, Kb, Vtb);
        // 4. RoPE on Q and K
        rope_tok<<<M, blk, 0, stream>>>(Qb, Kb, start_pos);
        // 5. wo -> bf16 transposed (wqb dead)
        tconv<false><<<dim3(NQ / 64, NQ / 64, 1), blk, 0, stream>>>(wo, wob, nullptr, nullptr, NQ, D_);
        // 6. Flash attention -> AOb (xb dead)
        flash_attn<__hip_bfloat16><<<dim3(T_ / 64, H_, B_), blk, 0, stream>>>(Qb, Kb, Vtb, AOb);
        // 7. Output projection -> fp32 out (Qb dead)
        gemm_bf16<float, false, false>
            <<<dim3(D_ / 128, M / 128, 1), blk, 0, stream>>>((const u16*)AOb, wob, out, nullptr, nullptr, M, D_, NQ);
    } else if (ws_size >= NEED_B) {
        // Tier B — R6-verified path, verbatim.
        char* w = (char*)d_ws;
        __hip_bfloat16* Kb  = (__hip_bfloat16*)(w);
        __hip_bfloat16* Vtb = (__hip_bfloat16*)(w + (4u  << 20));
        u16*            xb  = (u16*)(w + (8u  << 20));
        __hip_bfloat16* AOb = (__hip_bfloat16*)(w + (8u  << 20));
        u16*            wS  = (u16*)(w + (24u << 20));
        u16* wqb = wS;
        u16* wkb = wS;
        u16* wvb = wS + (size_t)NKV * D_;
        u16* wob = wS;
        __hip_bfloat16* Qb = (__hip_bfloat16*)d_out;

        lconv<<<(M * D_ / 8 + 255) / 256, blk, 0, stream>>>(x, xb, M * D_ / 8);
        tconv<false><<<dim3(NQ / 64, D_ / 64, 1), blk, 0, stream>>>(wq, wqb, nullptr, nullptr, D_, NQ);
        gemm_bf16<__hip_bfloat16, false, false>
            <<<dim3(NQ / 128, M / 128, 1), blk, 0, stream>>>(xb, wqb, Qb, nullptr, nullptr, M, NQ, D_);
        tconv<true><<<dim3(NKV / 64, D_ / 64, 2), blk, 0, stream>>>(wk, wkb, wv, wvb, D_, NKV);
        gemm_bf16<__hip_bfloat16, true, true>
            <<<dim3(NKV / 128, M / 128, 2), blk, 0, stream>>>(xb, wkb, Kb, wvb, Vtb, M, NKV, D_);
        rope_tok<<<M, blk, 0, stream>>>(Qb, Kb, start_pos);
        tconv<false><<<dim3(NQ / 64, NQ / 64, 1), blk, 0, stream>>>(wo, wob, nullptr, nullptr, NQ, D_);
        flash_attn<__hip_bfloat16><<<dim3(T_ / 64, H_, B_), blk, 0, stream>>>(Qb, Kb, Vtb, AOb);
        gemm_bf16<float, false, false>
            <<<dim3(D_ / 128, M / 128, 1), blk, 0, stream>>>((const u16*)AOb, wob, out, nullptr, nullptr, M, D_, NQ);
    } else {
        // ------- legacy fallback (24 MiB ws) -------
        float* Qf           = out;
        __hip_bfloat16* Kb  = (__hip_bfloat16*)d_ws;
        __hip_bfloat16* Vtb = Kb + (size_t)B_ * T_ * KVH_ * HD_;
        __hip_bfloat16* AOb = Vtb + (size_t)B_ * T_ * KVH_ * HD_;

        gemm_mfma<float, float, float, false, false>
            <<<dim3(NQ / 128, M / 128, 1), blk, 0, stream>>>(x, wq, Qf, nullptr, nullptr, M, NQ, D_);
        gemm_mfma<float, float, __hip_bfloat16, true, true>
            <<<dim3(NKV / 128, M / 128, 2), blk, 0, stream>>>(x, wk, Kb, wv, Vtb, M, NKV, D_);
        rope_kernel<<<(M * (H_ + KVH_)) / 4, blk, 0, stream>>>(Qf, Kb, start_pos);
        flash_attn<float><<<dim3(T_ / 64, H_, B_), blk, 0, stream>>>(Qf, Kb, Vtb, AOb);
        gemm_mfma<__hip_bfloat16, float, float, false, false>
            <<<dim3(D_ / 128, M / 128, 1), blk, 0, stream>>>(AOb, wo, out, nullptr, nullptr, M, D_, NQ);
    }
}

// Round 8
// 482.032 us; speedup vs baseline: 4.9836x; 1.0271x over previous
//
#include <hip/hip_runtime.h>
#include <hip/hip_bf16.h>
#include <math.h>

// Problem constants
#define B_    2
#define T_    1024
#define D_    4096
#define H_    32
#define KVH_  8
#define HD_   128
#define GROUP_ 4

static constexpr float SCORE_SCALE = 0.08838834764831845f; // 1/sqrt(128)

typedef __bf16 bf16x8 __attribute__((ext_vector_type(8)));
typedef float  f32x4  __attribute__((ext_vector_type(4)));
typedef unsigned short u16;

__device__ inline float toF(const __hip_bfloat16 v) { return __bfloat162float(v); }
__device__ inline float toF(const float v)          { return v; }

__device__ inline void storeC(float* p, float v)          { *p = v; }
__device__ inline void storeC(__hip_bfloat16* p, float v) { *p = __float2bfloat16(v); }

// fp32 -> bf16 bit pattern, round-to-nearest-even (finite inputs)
__device__ inline unsigned short f2bf(float f) {
    union { float f; unsigned u; } v; v.f = f;
    unsigned r = v.u + 0x7FFFu + ((v.u >> 16) & 1u);
    return (unsigned short)(r >> 16);
}

__device__ inline float bf2f(u16 u) {
    union { float f; unsigned u; } v; v.u = (unsigned)u << 16; return v.f;
}

// Direct global->LDS async copy, 16 B per lane. LDS dest is WAVE-UNIFORM
// base; HW adds lane*16. Global src is per-lane. [m97 pattern]
__device__ inline void gload_lds16(const u16* g, u16* l) {
    __builtin_amdgcn_global_load_lds(
        (const __attribute__((address_space(1))) void*)g,
        (__attribute__((address_space(3))) void*)l, 16, 0, 0);
}

// ===========================================================================
// FAST PATH
// ===========================================================================

// ---------------------------------------------------------------------------
// Linear fp32 -> bf16 convert (8 elems/thread) — used by Tier B.
// ---------------------------------------------------------------------------
__global__ __launch_bounds__(256) void lconv(const float* __restrict__ S,
                                             u16* __restrict__ D, int n8) {
    int i = blockIdx.x * 256 + threadIdx.x;
    if (i >= n8) return;
    const float4 a = *(const float4*)(S + (size_t)i * 8);
    const float4 b = *(const float4*)(S + (size_t)i * 8 + 4);
    union { int4 v; u16 u[8]; } t;
    t.u[0] = f2bf(a.x); t.u[1] = f2bf(a.y); t.u[2] = f2bf(a.z); t.u[3] = f2bf(a.w);
    t.u[4] = f2bf(b.x); t.u[5] = f2bf(b.y); t.u[6] = f2bf(b.z); t.u[7] = f2bf(b.w);
    *(int4*)(D + (size_t)i * 8) = t.v;
}

// ---------------------------------------------------------------------------
// Transpose + convert: src fp32 [R][Cc] row-major -> dst bf16 [Cc][R].
// ---------------------------------------------------------------------------
template <bool DUAL>
__global__ __launch_bounds__(256) void tconv(const float* __restrict__ S0,
                                             u16* __restrict__ D0,
                                             const float* __restrict__ S1,
                                             u16* __restrict__ D1,
                                             int R, int Cc) {
    const float* __restrict__ S = (DUAL && blockIdx.z) ? S1 : S0;
    u16* __restrict__ D         = (DUAL && blockIdx.z) ? D1 : D0;
    __shared__ u16 Tt[64][72];
    const int tid = threadIdx.x;
    const int r0 = blockIdx.y * 64, c0 = blockIdx.x * 64;
    {
        const int rr = tid >> 4, cc4 = (tid & 15) * 4;
#pragma unroll
        for (int e = 0; e < 4; ++e) {
            const int row = rr + e * 16;
            float4 v = *(const float4*)(S + (size_t)(r0 + row) * Cc + c0 + cc4);
            union { int2 w; u16 u[4]; } t;
            t.u[0] = f2bf(v.x); t.u[1] = f2bf(v.y); t.u[2] = f2bf(v.z); t.u[3] = f2bf(v.w);
            *(int2*)&Tt[row][cc4] = t.w;
        }
    }
    __syncthreads();
    {
        const int cc = tid >> 2, r8 = (tid & 3) * 8;
#pragma unroll
        for (int e = 0; e < 2; ++e) {
            const int rb = r8 + e * 32;
            union { int4 v; u16 u[8]; } t;
#pragma unroll
            for (int j = 0; j < 8; ++j) t.u[j] = Tt[rb + j][cc];
            *(int4*)(D + (size_t)(c0 + cc) * R + r0 + rb) = t.v;
        }
    }
}

// ---------------------------------------------------------------------------
// tconv4: one dispatch for wq/wk/wv transpose-convert AND x linear convert.
// grid (64, 64, 4):
//   z=0: wq [4096][4096] -> dq[4096][4096]T
//   z=1: wk [4096][1024] -> dk[1024][4096]T  (x-blocks >= 16 early-exit)
//   z=2: wv [4096][1024] -> dv[1024][4096]T  (x-blocks >= 16 early-exit)
//   z=3: x  [2048][4096] fp32 -> dx bf16 linear (4096 blocks, exact cover)
// ---------------------------------------------------------------------------
__global__ __launch_bounds__(256) void tconv4(const float* __restrict__ wq,
                                              const float* __restrict__ wk,
                                              const float* __restrict__ wv,
                                              const float* __restrict__ x,
                                              u16* __restrict__ dq,
                                              u16* __restrict__ dk,
                                              u16* __restrict__ dv,
                                              u16* __restrict__ dx) {
    const int z = blockIdx.z;
    const int tid = threadIdx.x;

    if (z == 3) {
        // linear convert: 4096 blocks x 256 threads x 8 elems = 8M = 2048*4096
        const size_t i = ((size_t)(blockIdx.y * 64 + blockIdx.x) * 256 + tid) * 8;
        const float4 a = *(const float4*)(x + i);
        const float4 b = *(const float4*)(x + i + 4);
        union { int4 v; u16 u[8]; } t;
        t.u[0] = f2bf(a.x); t.u[1] = f2bf(a.y); t.u[2] = f2bf(a.z); t.u[3] = f2bf(a.w);
        t.u[4] = f2bf(b.x); t.u[5] = f2bf(b.y); t.u[6] = f2bf(b.z); t.u[7] = f2bf(b.w);
        *(int4*)(dx + i) = t.v;
        return;
    }

    const float* __restrict__ S;
    u16* __restrict__ D;
    int Cc;
    if (z == 0)      { S = wq; D = dq; Cc = 4096; }
    else if (z == 1) { S = wk; D = dk; Cc = 1024; }
    else             { S = wv; D = dv; Cc = 1024; }
    if (blockIdx.x * 64 >= Cc) return;
    const int R = 4096;

    __shared__ u16 Tt[64][72];
    const int r0 = blockIdx.y * 64, c0 = blockIdx.x * 64;
    {
        const int rr = tid >> 4, cc4 = (tid & 15) * 4;
#pragma unroll
        for (int e = 0; e < 4; ++e) {
            const int row = rr + e * 16;
            float4 v = *(const float4*)(S + (size_t)(r0 + row) * Cc + c0 + cc4);
            union { int2 w; u16 u[4]; } t;
            t.u[0] = f2bf(v.x); t.u[1] = f2bf(v.y); t.u[2] = f2bf(v.z); t.u[3] = f2bf(v.w);
            *(int2*)&Tt[row][cc4] = t.w;
        }
    }
    __syncthreads();
    {
        const int cc = tid >> 2, r8 = (tid & 3) * 8;
#pragma unroll
        for (int e = 0; e < 2; ++e) {
            const int rb = r8 + e * 32;
            union { int4 v; u16 u[8]; } t;
#pragma unroll
            for (int j = 0; j < 8; ++j) t.u[j] = Tt[rb + j][cc];
            *(int4*)(D + (size_t)(c0 + cc) * R + r0 + rb) = t.v;
        }
    }
}

// ---------------------------------------------------------------------------
// Fused QKV projection GEMM (m97 structure, 768 blocks = 3/CU):
//   swz 0..511:   Qb[2048][4096]   = xb @ wqb^T   (bf16, row-major)
//   swz 512..639: Kb[2048][1024]   = xb @ wkb^T   (bf16, row-major)
//   swz 640..767: Vtb[1024][2048]  = (xb @ wvb^T)^T (bf16, transposed)
// Bijective XCD swizzle (768 % 8 == 0).
// ---------------------------------------------------------------------------
__global__ __launch_bounds__(256, 3) void gemm_qkv(const u16* __restrict__ A,
                                                   const u16* __restrict__ wqb,
                                                   const u16* __restrict__ wkb,
                                                   const u16* __restrict__ wvb,
                                                   __hip_bfloat16* __restrict__ Qb,
                                                   __hip_bfloat16* __restrict__ Kb,
                                                   __hip_bfloat16* __restrict__ Vtb) {
    const int K = D_;          // 4096
    const int M = B_ * T_;     // 2048

    const int bid = blockIdx.x;
    const int swz = (bid & 7) * 96 + (bid >> 3);   // XCD chunking, bijective

    const u16* __restrict__ Bt;
    __hip_bfloat16* __restrict__ C;
    int bm, bn, N;
    bool tr;
    if (swz < 512)      { Bt = wqb; C = Qb;  N = 4096; bm = (swz >> 5) * 128; bn = (swz & 31) * 128; tr = false; }
    else if (swz < 640) { int i = swz - 512; Bt = wkb; C = Kb;  N = 1024; bm = (i >> 3) * 128; bn = (i & 7) * 128; tr = false; }
    else                { int i = swz - 640; Bt = wvb; C = Vtb; N = 1024; bm = (i >> 3) * 128; bn = (i & 7) * 128; tr = true; }

    __shared__ u16 As[128 * 32];   // 8 KiB
    __shared__ u16 Bs[128 * 32];   // 8 KiB

    const int tid   = threadIdx.x;
    const int lane  = tid & 63;
    const int w     = tid >> 6;
    const int waveM = w >> 1;
    const int waveN = w & 1;
    const int lm    = lane & 15;
    const int quad  = lane >> 4;

    const int srow = w * 16 + (lane >> 2);
    const int scol = (lane & 3) * 8;

    const u16* agp0 = A  + (size_t)(bm + srow)      * K + scol;
    const u16* agp1 = A  + (size_t)(bm + srow + 64) * K + scol;
    const u16* bgp0 = Bt + (size_t)(bn + srow)      * K + scol;
    const u16* bgp1 = Bt + (size_t)(bn + srow + 64) * K + scol;

    u16* al0 = &As[(w * 16)      * 32];
    u16* al1 = &As[(w * 16 + 64) * 32];
    u16* bl0 = &Bs[(w * 16)      * 32];
    u16* bl1 = &Bs[(w * 16 + 64) * 32];

    f32x4 acc[4][4];
#pragma unroll
    for (int i = 0; i < 4; ++i)
#pragma unroll
        for (int j = 0; j < 4; ++j) acc[i][j] = (f32x4){0.f, 0.f, 0.f, 0.f};

    for (int k0 = 0; k0 < K; k0 += 32) {
        gload_lds16(agp0 + k0, al0);
        gload_lds16(agp1 + k0, al1);
        gload_lds16(bgp0 + k0, bl0);
        gload_lds16(bgp1 + k0, bl1);
        __syncthreads();

        bf16x8 af[4], bfv[4];
#pragma unroll
        for (int i = 0; i < 4; ++i)
            af[i] = *(const bf16x8*)&As[(waveM * 64 + i * 16 + lm) * 32 + quad * 8];
#pragma unroll
        for (int j = 0; j < 4; ++j)
            bfv[j] = *(const bf16x8*)&Bs[(waveN * 64 + j * 16 + lm) * 32 + quad * 8];
#pragma unroll
        for (int i = 0; i < 4; ++i)
#pragma unroll
            for (int j = 0; j < 4; ++j)
                acc[i][j] = __builtin_amdgcn_mfma_f32_16x16x32_bf16(af[i], bfv[j], acc[i][j], 0, 0, 0);
        __syncthreads();
    }

    // C/D layout: col = lane&15, row = quad*4 + reg  [m89-verified]
    if (tr) {
#pragma unroll
        for (int i = 0; i < 4; ++i) {
            int row0 = bm + waveM * 64 + i * 16 + quad * 4;
#pragma unroll
            for (int j = 0; j < 4; ++j) {
                int col = bn + waveN * 64 + j * 16 + lm;
#pragma unroll
                for (int rr = 0; rr < 4; ++rr)
                    C[(size_t)col * M + row0 + rr] = __float2bfloat16(acc[i][j][rr]);
            }
        }
    } else {
#pragma unroll
        for (int i = 0; i < 4; ++i) {
            int row0 = bm + waveM * 64 + i * 16 + quad * 4;
#pragma unroll
            for (int j = 0; j < 4; ++j) {
                int col = bn + waveN * 64 + j * 16 + lm;
#pragma unroll
                for (int rr = 0; rr < 4; ++rr)
                    C[(size_t)(row0 + rr) * N + col] = __float2bfloat16(acc[i][j][rr]);
            }
        }
    }
}

// ---------------------------------------------------------------------------
// bf16 GEMM (m97 structure): C[M,N] = A[M,K] @ Bt[N,K]^T.
// DUAL: blockIdx.z picks (Bt0,C0)/(Bt1,C1). TRC1: z=1 output transposed.
// ---------------------------------------------------------------------------
template <typename TC, bool DUAL, bool TRC1>
__global__ __launch_bounds__(256, 2) void gemm_bf16(const u16* __restrict__ A,
                                                    const u16* __restrict__ Bt0,
                                                    TC* __restrict__ C0,
                                                    const u16* __restrict__ Bt1,
                                                    TC* __restrict__ C1,
                                                    int M, int N, int K) {
    const u16* __restrict__ Bt = (DUAL && blockIdx.z) ? Bt1 : Bt0;
    TC* __restrict__ C         = (DUAL && blockIdx.z) ? C1 : C0;

    __shared__ u16 As[128 * 32];   // 8 KiB
    __shared__ u16 Bs[128 * 32];   // 8 KiB

    const int tid   = threadIdx.x;
    const int lane  = tid & 63;
    const int w     = tid >> 6;
    const int waveM = w >> 1;
    const int waveN = w & 1;
    const int lm    = lane & 15;
    const int quad  = lane >> 4;
    const int bm    = blockIdx.y * 128;
    const int bn    = blockIdx.x * 128;

    const int srow = w * 16 + (lane >> 2);
    const int scol = (lane & 3) * 8;

    const u16* agp0 = A  + (size_t)(bm + srow)      * K + scol;
    const u16* agp1 = A  + (size_t)(bm + srow + 64) * K + scol;
    const u16* bgp0 = Bt + (size_t)(bn + srow)      * K + scol;
    const u16* bgp1 = Bt + (size_t)(bn + srow + 64) * K + scol;

    u16* al0 = &As[(w * 16)      * 32];
    u16* al1 = &As[(w * 16 + 64) * 32];
    u16* bl0 = &Bs[(w * 16)      * 32];
    u16* bl1 = &Bs[(w * 16 + 64) * 32];

    f32x4 acc[4][4];
#pragma unroll
    for (int i = 0; i < 4; ++i)
#pragma unroll
        for (int j = 0; j < 4; ++j) acc[i][j] = (f32x4){0.f, 0.f, 0.f, 0.f};

    for (int k0 = 0; k0 < K; k0 += 32) {
        gload_lds16(agp0 + k0, al0);
        gload_lds16(agp1 + k0, al1);
        gload_lds16(bgp0 + k0, bl0);
        gload_lds16(bgp1 + k0, bl1);
        __syncthreads();   // drains vmcnt -> tiles resident

        bf16x8 af[4], bfv[4];
#pragma unroll
        for (int i = 0; i < 4; ++i)
            af[i] = *(const bf16x8*)&As[(waveM * 64 + i * 16 + lm) * 32 + quad * 8];
#pragma unroll
        for (int j = 0; j < 4; ++j)
            bfv[j] = *(const bf16x8*)&Bs[(waveN * 64 + j * 16 + lm) * 32 + quad * 8];
#pragma unroll
        for (int i = 0; i < 4; ++i)
#pragma unroll
            for (int j = 0; j < 4; ++j)
                acc[i][j] = __builtin_amdgcn_mfma_f32_16x16x32_bf16(af[i], bfv[j], acc[i][j], 0, 0, 0);
        __syncthreads();   // frags consumed -> safe to overwrite
    }

    if (TRC1 && DUAL && blockIdx.z) {
#pragma unroll
        for (int i = 0; i < 4; ++i) {
            int row0 = bm + waveM * 64 + i * 16 + quad * 4;
#pragma unroll
            for (int j = 0; j < 4; ++j) {
                int col = bn + waveN * 64 + j * 16 + lm;
#pragma unroll
                for (int rr = 0; rr < 4; ++rr)
                    storeC(&C[(size_t)col * M + row0 + rr], acc[i][j][rr]);
            }
        }
    } else {
#pragma unroll
        for (int i = 0; i < 4; ++i) {
            int row0 = bm + waveM * 64 + i * 16 + quad * 4;
#pragma unroll
            for (int j = 0; j < 4; ++j) {
                int col = bn + waveN * 64 + j * 16 + lm;
#pragma unroll
                for (int rr = 0; rr < 4; ++rr)
                    storeC(&C[(size_t)(row0 + rr) * N + col], acc[i][j][rr]);
            }
        }
    }
}

// ===========================================================================
// LEGACY (fallback) GEMM — fused fp32->bf16 conversion. ws_size < 56 MiB.
// ===========================================================================
#define LSTR 40

template <typename TA, typename TB, typename TC, bool DUAL, bool TRC1>
__global__ __launch_bounds__(256) void gemm_mfma(const TA* __restrict__ A,
                                                 const TB* __restrict__ B0,
                                                 TC* __restrict__ C0,
                                                 const TB* __restrict__ B1,
                                                 TC* __restrict__ C1,
                                                 int M, int N, int K) {
    const TB* __restrict__ B = (DUAL && blockIdx.z) ? B1 : B0;
    TC* __restrict__ C       = (DUAL && blockIdx.z) ? C1 : C0;

    __shared__ unsigned short As[128 * LSTR];
    __shared__ unsigned short Bs[128 * LSTR];

    const int tid   = threadIdx.x;
    const int lane  = tid & 63;
    const int wv    = tid >> 6;
    const int waveM = wv >> 1;
    const int waveN = wv & 1;
    const int lm    = lane & 15;
    const int quad  = lane >> 4;
    const int bm    = blockIdx.y * 128;
    const int bn    = blockIdx.x * 128;

    f32x4 acc[4][4];
#pragma unroll
    for (int i = 0; i < 4; ++i)
#pragma unroll
        for (int j = 0; j < 4; ++j) acc[i][j] = (f32x4){0.f, 0.f, 0.f, 0.f};

    for (int k0 = 0; k0 < K; k0 += 32) {
#pragma unroll
        for (int e = 0; e < 8; ++e) {
            int p  = tid + e * 256;
            int r  = p >> 4, c2 = (p & 15) * 2;
            const TA* ap = A + (size_t)(bm + r) * K + k0 + c2;
            ushort2 t;
            t.x = f2bf(toF(ap[0]));
            t.y = f2bf(toF(ap[1]));
            *(ushort2*)&As[r * LSTR + c2] = t;
        }
#pragma unroll
        for (int e = 0; e < 8; ++e) {
            int p  = tid + e * 256;
            int n  = p & 127, k2 = (p >> 7) * 2;
            const TB* bp = B + (size_t)(k0 + k2) * N + bn + n;
            ushort2 t;
            t.x = f2bf(toF(bp[0]));
            t.y = f2bf(toF(bp[N]));
            *(ushort2*)&Bs[n * LSTR + k2] = t;
        }
        __syncthreads();

        bf16x8 af[4], bfr[4];
#pragma unroll
        for (int i = 0; i < 4; ++i)
            af[i] = *(const bf16x8*)&As[(waveM * 64 + i * 16 + lm) * LSTR + quad * 8];
#pragma unroll
        for (int j = 0; j < 4; ++j)
            bfr[j] = *(const bf16x8*)&Bs[(waveN * 64 + j * 16 + lm) * LSTR + quad * 8];
#pragma unroll
        for (int i = 0; i < 4; ++i)
#pragma unroll
            for (int j = 0; j < 4; ++j)
                acc[i][j] = __builtin_amdgcn_mfma_f32_16x16x32_bf16(af[i], bfr[j], acc[i][j], 0, 0, 0);
        __syncthreads();
    }

    if (TRC1 && DUAL && blockIdx.z) {
#pragma unroll
        for (int i = 0; i < 4; ++i) {
            int row0 = bm + waveM * 64 + i * 16 + quad * 4;
#pragma unroll
            for (int j = 0; j < 4; ++j) {
                int col = bn + waveN * 64 + j * 16 + lm;
#pragma unroll
                for (int rr = 0; rr < 4; ++rr)
                    storeC(&C[(size_t)col * M + row0 + rr], acc[i][j][rr]);
            }
        }
    } else {
#pragma unroll
        for (int i = 0; i < 4; ++i) {
            int row0 = bm + waveM * 64 + i * 16 + quad * 4;
#pragma unroll
            for (int j = 0; j < 4; ++j) {
                int col = bn + waveN * 64 + j * 16 + lm;
#pragma unroll
                for (int rr = 0; rr < 4; ++rr)
                    storeC(&C[(size_t)(row0 + rr) * N + col], acc[i][j][rr]);
            }
        }
    }
}

// ---------------------------------------------------------------------------
// RoPE (fast path): one block per token; 64 fp32 sincos into LDS (shared by
// all 40 heads), vectorized bf16x8 apply to Q[4096] + K[1024] in-place.
// ---------------------------------------------------------------------------
__device__ inline void rope_apply8(__hip_bfloat16* p, const float* cs,
                                   const float* sn, int t0) {
    union { int4 v; u16 u[8]; } in, outv;
    in.v = *(const int4*)p;
    float x[8];
#pragma unroll
    for (int i = 0; i < 8; ++i) x[i] = bf2f(in.u[i]);
#pragma unroll
    for (int pr = 0; pr < 4; ++pr) {
        float c0 = cs[t0 + 2 * pr],     s0 = sn[t0 + 2 * pr];
        float c1 = cs[t0 + 2 * pr + 1], s1 = sn[t0 + 2 * pr + 1];
        float e = x[2 * pr], o = x[2 * pr + 1];
        outv.u[2 * pr]     = f2bf(e * c0 - o * s0);
        outv.u[2 * pr + 1] = f2bf(o * c1 + e * s1);
    }
    *(int4*)p = outv.v;
}

__global__ __launch_bounds__(256) void rope_tok(__hip_bfloat16* __restrict__ Q,
                                                __hip_bfloat16* __restrict__ K,
                                                const int* __restrict__ start_pos) {
    __shared__ float cs[64], sn[64];
    const int n   = blockIdx.x;          // token row 0..2047
    const int tid = threadIdx.x;
    const int pos = *start_pos + (n % T_);

    if (tid < 64) {
        // inv_freq = 10000^(-2*tid/128) = exp2(-tid * log2(10000)/64)
        float invf = exp2f(-(float)tid * 0.20762050593045232f);
        float ang  = (float)pos * invf;
        cs[tid] = cosf(ang); sn[tid] = sinf(ang);
    }
    __syncthreads();

    __hip_bfloat16* qrow = Q + (size_t)n * (H_ * HD_);
    __hip_bfloat16* krow = K + (size_t)n * (KVH_ * HD_);
#pragma unroll
    for (int e = 0; e < 2; ++e) {
        int g = tid + e * 256;
        rope_apply8(qrow + g * 8, cs, sn, (g * 8) & 63);
    }
    if (tid < 128)
        rope_apply8(krow + tid * 8, cs, sn, (tid * 8) & 63);
}

// ---------------------------------------------------------------------------
// RoPE (legacy fallback): per-element double-precision version.
// ---------------------------------------------------------------------------
template <typename TQ, typename TK>
__global__ __launch_bounds__(256) void rope_kernel(TQ* __restrict__ Q,
                                                   TK* __restrict__ Kt,
                                                   const int* __restrict__ start_pos) {
    int w    = blockIdx.x * 4 + (threadIdx.x >> 6);
    int lane = threadIdx.x & 63;
    int hh = w % (H_ + KVH_);
    int n  = w / (H_ + KVH_);
    int t  = n % T_;
    int pos = *start_pos + t;

    int e0 = 2 * lane, e1 = 2 * lane + 1;
    int j0 = e0 & 63,  j1 = e1 & 63;
    const double LN_BASE = 9.210340371976184; // ln(10000)
    double a0 = (double)pos * exp(-((double)(2 * j0) / 128.0) * LN_BASE);
    double a1 = (double)pos * exp(-((double)(2 * j1) / 128.0) * LN_BASE);
    float c0 = (float)cos(a0), s0 = (float)sin(a0);
    float c1 = (float)cos(a1), s1 = (float)sin(a1);

    if (hh < H_) {
        TQ* base = Q + (size_t)n * (H_ * HD_) + hh * HD_;
        float x0 = toF(base[e0]), x1 = toF(base[e1]);
        storeC(&base[e0], x0 * c0 - x1 * s0);
        storeC(&base[e1], x1 * c1 + x0 * s1);
    } else {
        TK* base = Kt + (size_t)n * (KVH_ * HD_) + (hh - H_) * HD_;
        float x0 = toF(base[e0]), x1 = toF(base[e1]);
        storeC(&base[e0], x0 * c0 - x1 * s0);
        storeC(&base[e1], x1 * c1 + x0 * s1);
    }
}

// ---------------------------------------------------------------------------
// Flash attention (causal, GQA) — standalone (Tier B / legacy).
// ---------------------------------------------------------------------------
#define KSTR 136   // Ks row stride (ushorts)
#define VSTR 72    // Vs row stride
#define PSTR 72    // Ps row stride

template <typename TQ>
__global__ __launch_bounds__(256, 2) void flash_attn(
        const TQ* __restrict__ Q,
        const __hip_bfloat16* __restrict__ K,
        const __hip_bfloat16* __restrict__ Vt,
        __hip_bfloat16* __restrict__ AO) {
    __shared__ unsigned short Ks[64 * KSTR];       // 17408 B
    __shared__ unsigned short Vs[128 * VSTR];      // 18432 B
    __shared__ unsigned short Ps[4][16 * PSTR];    //  9216 B (per-wave private)

    const int tid  = threadIdx.x;
    const int lane = tid & 63;
    const int w    = tid >> 6;
    const int quad = lane >> 4;
    const int lm   = lane & 15;

    const int qt  = (blockIdx.x + blockIdx.y) & 15;  // XCD-decorrelated q-tile
    const int qb  = qt * 64;
    const int h   = blockIdx.y;
    const int b   = blockIdx.z;
    const int kvh = h >> 2;

    const int qw = qb + w * 16;

    bf16x8 qf[4];
    {
        const TQ* qrow = Q + (size_t)(b * T_ + qw + lm) * (H_ * HD_) + h * HD_;
        if constexpr (sizeof(TQ) == 2) {
#pragma unroll
            for (int ks = 0; ks < 4; ++ks)
                qf[ks] = *(const bf16x8*)(qrow + ks * 32 + quad * 8);
        } else {
#pragma unroll
            for (int ks = 0; ks < 4; ++ks) {
                const TQ* p4 = qrow + ks * 32 + quad * 8;
                float4 f0 = *(const float4*)(p4);
                float4 f1 = *(const float4*)(p4 + 4);
                union { bf16x8 v; unsigned short u[8]; } t;
                t.u[0] = f2bf(toF(f0.x)); t.u[1] = f2bf(toF(f0.y));
                t.u[2] = f2bf(toF(f0.z)); t.u[3] = f2bf(toF(f0.w));
                t.u[4] = f2bf(toF(f1.x)); t.u[5] = f2bf(toF(f1.y));
                t.u[6] = f2bf(toF(f1.z)); t.u[7] = f2bf(toF(f1.w));
                qf[ks] = t.v;
            }
        }
    }

    float mI[4], lI[4];
    f32x4 o[8];
#pragma unroll
    for (int rr = 0; rr < 4; ++rr) { mI[rr] = -1e30f; lI[rr] = 0.f; }
#pragma unroll
    for (int dc = 0; dc < 8; ++dc) o[dc] = (f32x4){0.f, 0.f, 0.f, 0.f};

    const int nkt = qt + 1;

    for (int kt = 0; kt < nkt; ++kt) {
        const int t0 = kt * 64;
#pragma unroll
        for (int e = 0; e < 4; ++e) {
            int p = tid + e * 256;
            int tt = p >> 4, d0 = (p & 15) * 8;
            int4 v = *(const int4*)(K + (size_t)(b * T_ + t0 + tt) * (KVH_ * HD_) + kvh * HD_ + d0);
            *(int4*)&Ks[tt * KSTR + d0] = v;
        }
#pragma unroll
        for (int e = 0; e < 4; ++e) {
            int p = tid + e * 256;
            int d = p >> 3, tm = (p & 7) * 8;
            int4 v = *(const int4*)(Vt + (size_t)(kvh * HD_ + d) * (B_ * T_) + b * T_ + t0 + tm);
            *(int4*)&Vs[d * VSTR + tm] = v;
        }
        __syncthreads();

        f32x4 s[4];
#pragma unroll
        for (int tc = 0; tc < 4; ++tc) s[tc] = (f32x4){0.f, 0.f, 0.f, 0.f};
        __builtin_amdgcn_s_setprio(1);
#pragma unroll
        for (int ks = 0; ks < 4; ++ks) {
            bf16x8 kf[4];
#pragma unroll
            for (int tc = 0; tc < 4; ++tc)
                kf[tc] = *(const bf16x8*)&Ks[(tc * 16 + lm) * KSTR + ks * 32 + quad * 8];
#pragma unroll
            for (int tc = 0; tc < 4; ++tc)
                s[tc] = __builtin_amdgcn_mfma_f32_16x16x32_bf16(qf[ks], kf[tc], s[tc], 0, 0, 0);
        }
        __builtin_amdgcn_s_setprio(0);

#pragma unroll
        for (int tc = 0; tc < 4; ++tc)
#pragma unroll
            for (int rr = 0; rr < 4; ++rr) s[tc][rr] *= SCORE_SCALE;

        if (t0 + 63 > qw) {
            int qrow = qw + quad * 4;
#pragma unroll
            for (int tc = 0; tc < 4; ++tc) {
                int tcol = t0 + tc * 16 + lm;
#pragma unroll
                for (int rr = 0; rr < 4; ++rr)
                    if (tcol > qrow + rr) s[tc][rr] = -1e30f;
            }
        }

#pragma unroll
        for (int rr = 0; rr < 4; ++rr) {
            float tmx = fmaxf(fmaxf(s[0][rr], s[1][rr]),
                              fmaxf(s[2][rr], s[3][rr]));
#pragma unroll
            for (int off = 8; off >= 1; off >>= 1)
                tmx = fmaxf(tmx, __shfl_xor(tmx, off, 64));
            float mn    = fmaxf(mI[rr], tmx);
            float alpha = __expf(mI[rr] - mn);
            mI[rr]  = mn;
            float rs = 0.f;
#pragma unroll
            for (int tc = 0; tc < 4; ++tc) {
                float p = __expf(s[tc][rr] - mn);
                s[tc][rr] = p;
                rs += p;
            }
#pragma unroll
            for (int off = 8; off >= 1; off >>= 1)
                rs += __shfl_xor(rs, off, 64);
            lI[rr] = lI[rr] * alpha + rs;
#pragma unroll
            for (int dc = 0; dc < 8; ++dc)
                o[dc][rr] *= alpha;
        }

#pragma unroll
        for (int tc = 0; tc < 4; ++tc)
#pragma unroll
            for (int rr = 0; rr < 4; ++rr)
                Ps[w][(quad * 4 + rr) * PSTR + tc * 16 + lm] = f2bf(s[tc][rr]);

        __builtin_amdgcn_s_setprio(1);
#pragma unroll
        for (int ss = 0; ss < 2; ++ss) {
            bf16x8 pf = *(const bf16x8*)&Ps[w][lm * PSTR + ss * 32 + quad * 8];
#pragma unroll
            for (int dc = 0; dc < 8; ++dc) {
                bf16x8 vf = *(const bf16x8*)&Vs[(dc * 16 + lm) * VSTR + ss * 32 + quad * 8];
                o[dc] = __builtin_amdgcn_mfma_f32_16x16x32_bf16(pf, vf, o[dc], 0, 0, 0);
            }
        }
        __builtin_amdgcn_s_setprio(0);
        __syncthreads();
    }

#pragma unroll
    for (int rr = 0; rr < 4; ++rr) {
        float inv = 1.f / lI[rr];
        size_t row = (size_t)(b * T_ + qw + quad * 4 + rr) * (H_ * HD_) + h * HD_;
#pragma unroll
        for (int dc = 0; dc < 8; ++dc)
            AO[row + dc * 16 + lm] = __float2bfloat16(o[dc][rr] * inv);
    }
}

// ---------------------------------------------------------------------------
// flash_fused: flash attention (bf16 Q) + wo transpose-convert in ONE
// dispatch. grid.x = 4096 (tconv part) + 1024 (flash part) = 5120.
//   bid <  4096: transpose wo[4096][4096] fp32 -> wob[4096][4096] bf16
//   bid >= 4096: flash block fid = bid-4096: qx=fid&15, h=(fid>>4)&31, b=fid>>9
// The tconv blocks' HBM traffic hides under flash's latency-bound phases.
// LDS: Tt aliases Ks (tconv branch uses 9216 B of flash's 45056 B).
// 3 blocks/CU (135 KiB LDS).
// ---------------------------------------------------------------------------
__global__ __launch_bounds__(256, 3) void flash_fused(
        const __hip_bfloat16* __restrict__ Q,
        const __hip_bfloat16* __restrict__ K,
        const __hip_bfloat16* __restrict__ Vt,
        __hip_bfloat16* __restrict__ AO,
        const float* __restrict__ wo,
        u16* __restrict__ wob) {
    __shared__ unsigned short Ks[64 * KSTR];       // 17408 B
    __shared__ unsigned short Vs[128 * VSTR];      // 18432 B
    __shared__ unsigned short Ps[4][16 * PSTR];    //  9216 B

    const int tid = threadIdx.x;

    if (blockIdx.x < 4096) {
        // ---- wo transpose tile (same as tconv, R=Cc=4096) ------------------
        u16 (*Tt)[72] = (u16(*)[72])Ks;   // alias: 9216 B <= 17408 B
        const int tb = blockIdx.x;
        const int c0 = (tb & 63) * 64, r0 = (tb >> 6) * 64;
        const int R = 4096, Cc = 4096;
        {
            const int rr = tid >> 4, cc4 = (tid & 15) * 4;
#pragma unroll
            for (int e = 0; e < 4; ++e) {
                const int row = rr + e * 16;
                float4 v = *(const float4*)(wo + (size_t)(r0 + row) * Cc + c0 + cc4);
                union { int2 w; u16 u[4]; } t;
                t.u[0] = f2bf(v.x); t.u[1] = f2bf(v.y); t.u[2] = f2bf(v.z); t.u[3] = f2bf(v.w);
                *(int2*)&Tt[row][cc4] = t.w;
            }
        }
        __syncthreads();
        {
            const int cc = tid >> 2, r8 = (tid & 3) * 8;
#pragma unroll
            for (int e = 0; e < 2; ++e) {
                const int rb = r8 + e * 32;
                union { int4 v; u16 u[8]; } t;
#pragma unroll
                for (int j = 0; j < 8; ++j) t.u[j] = Tt[rb + j][cc];
                *(int4*)(wob + (size_t)(c0 + cc) * R + r0 + rb) = t.v;
            }
        }
        return;
    }

    // ---- flash part --------------------------------------------------------
    const int fid  = blockIdx.x - 4096;
    const int lane = tid & 63;
    const int w    = tid >> 6;
    const int quad = lane >> 4;
    const int lm   = lane & 15;

    const int qx  = fid & 15;
    const int h   = (fid >> 4) & 31;
    const int b   = fid >> 9;
    const int qt  = (qx + h) & 15;    // XCD-decorrelated q-tile
    const int qb  = qt * 64;
    const int kvh = h >> 2;

    const int qw = qb + w * 16;       // wave's 16 q-rows

    bf16x8 qf[4];
    {
        const __hip_bfloat16* qrow = Q + (size_t)(b * T_ + qw + lm) * (H_ * HD_) + h * HD_;
#pragma unroll
        for (int ks = 0; ks < 4; ++ks)
            qf[ks] = *(const bf16x8*)(qrow + ks * 32 + quad * 8);
    }

    float mI[4], lI[4];
    f32x4 o[8];
#pragma unroll
    for (int rr = 0; rr < 4; ++rr) { mI[rr] = -1e30f; lI[rr] = 0.f; }
#pragma unroll
    for (int dc = 0; dc < 8; ++dc) o[dc] = (f32x4){0.f, 0.f, 0.f, 0.f};

    const int nkt = qt + 1;

    for (int kt = 0; kt < nkt; ++kt) {
        const int t0 = kt * 64;
#pragma unroll
        for (int e = 0; e < 4; ++e) {
            int p = tid + e * 256;
            int tt = p >> 4, d0 = (p & 15) * 8;
            int4 v = *(const int4*)(K + (size_t)(b * T_ + t0 + tt) * (KVH_ * HD_) + kvh * HD_ + d0);
            *(int4*)&Ks[tt * KSTR + d0] = v;
        }
#pragma unroll
        for (int e = 0; e < 4; ++e) {
            int p = tid + e * 256;
            int d = p >> 3, tm = (p & 7) * 8;
            int4 v = *(const int4*)(Vt + (size_t)(kvh * HD_ + d) * (B_ * T_) + b * T_ + t0 + tm);
            *(int4*)&Vs[d * VSTR + tm] = v;
        }
        __syncthreads();

        // --- S = Q K^T ------------------------------------------------------
        f32x4 s[4];
#pragma unroll
        for (int tc = 0; tc < 4; ++tc) s[tc] = (f32x4){0.f, 0.f, 0.f, 0.f};
        __builtin_amdgcn_s_setprio(1);
#pragma unroll
        for (int ks = 0; ks < 4; ++ks) {
            bf16x8 kf[4];
#pragma unroll
            for (int tc = 0; tc < 4; ++tc)
                kf[tc] = *(const bf16x8*)&Ks[(tc * 16 + lm) * KSTR + ks * 32 + quad * 8];
#pragma unroll
            for (int tc = 0; tc < 4; ++tc)
                s[tc] = __builtin_amdgcn_mfma_f32_16x16x32_bf16(qf[ks], kf[tc], s[tc], 0, 0, 0);
        }
        __builtin_amdgcn_s_setprio(0);

        // --- scale + causal mask -------------------------------------------
#pragma unroll
        for (int tc = 0; tc < 4; ++tc)
#pragma unroll
            for (int rr = 0; rr < 4; ++rr) s[tc][rr] *= SCORE_SCALE;

        if (t0 + 63 > qw) {
            int qrow = qw + quad * 4;
#pragma unroll
            for (int tc = 0; tc < 4; ++tc) {
                int tcol = t0 + tc * 16 + lm;
#pragma unroll
                for (int rr = 0; rr < 4; ++rr)
                    if (tcol > qrow + rr) s[tc][rr] = -1e30f;
            }
        }

        // --- online softmax -------------------------------------------------
#pragma unroll
        for (int rr = 0; rr < 4; ++rr) {
            float tmx = fmaxf(fmaxf(s[0][rr], s[1][rr]),
                              fmaxf(s[2][rr], s[3][rr]));
#pragma unroll
            for (int off = 8; off >= 1; off >>= 1)
                tmx = fmaxf(tmx, __shfl_xor(tmx, off, 64));
            float mn    = fmaxf(mI[rr], tmx);
            float alpha = __expf(mI[rr] - mn);
            mI[rr]  = mn;
            float rs = 0.f;
#pragma unroll
            for (int tc = 0; tc < 4; ++tc) {
                float p = __expf(s[tc][rr] - mn);
                s[tc][rr] = p;
                rs += p;
            }
#pragma unroll
            for (int off = 8; off >= 1; off >>= 1)
                rs += __shfl_xor(rs, off, 64);
            lI[rr] = lI[rr] * alpha + rs;
#pragma unroll
            for (int dc = 0; dc < 8; ++dc)
                o[dc][rr] *= alpha;
        }

        // --- P -> LDS (C/D layout -> A layout round trip) -------------------
#pragma unroll
        for (int tc = 0; tc < 4; ++tc)
#pragma unroll
            for (int rr = 0; rr < 4; ++rr)
                Ps[w][(quad * 4 + rr) * PSTR + tc * 16 + lm] = f2bf(s[tc][rr]);

        // --- O += P V -------------------------------------------------------
        __builtin_amdgcn_s_setprio(1);
#pragma unroll
        for (int ss = 0; ss < 2; ++ss) {
            bf16x8 pf = *(const bf16x8*)&Ps[w][lm * PSTR + ss * 32 + quad * 8];
#pragma unroll
            for (int dc = 0; dc < 8; ++dc) {
                bf16x8 vf = *(const bf16x8*)&Vs[(dc * 16 + lm) * VSTR + ss * 32 + quad * 8];
                o[dc] = __builtin_amdgcn_mfma_f32_16x16x32_bf16(pf, vf, o[dc], 0, 0, 0);
            }
        }
        __builtin_amdgcn_s_setprio(0);
        __syncthreads();
    }

    // --- epilogue ----------------------------------------------------------
#pragma unroll
    for (int rr = 0; rr < 4; ++rr) {
        float inv = 1.f / lI[rr];
        size_t row = (size_t)(b * T_ + qw + quad * 4 + rr) * (H_ * HD_) + h * HD_;
#pragma unroll
        for (int dc = 0; dc < 8; ++dc)
            AO[row + dc * 16 + lm] = __float2bfloat16(o[dc][rr] * inv);
    }
}

// ---------------------------------------------------------------------------
extern "C" void kernel_launch(void* const* d_in, const int* in_sizes, int n_in,
                              void* d_out, int out_size, void* d_ws, size_t ws_size,
                              hipStream_t stream) {
    const float* x  = (const float*)d_in[0];
    const float* wq = (const float*)d_in[1];
    const float* wk = (const float*)d_in[2];
    const float* wv = (const float*)d_in[3];
    const float* wo = (const float*)d_in[4];
    const int* start_pos = (const int*)d_in[5];
    float* out = (float*)d_out;

    dim3 blk(256);
    const int M   = B_ * T_;      // 2048
    const int NQ  = H_ * HD_;     // 4096
    const int NKV = KVH_ * HD_;   // 1024

    const size_t NEED_A = 75497472; // 72 MiB — fused tier
    const size_t NEED_B = 58720256; // 56 MiB — R6-verified tier

    if (ws_size >= NEED_A) {
        // Tier A (72 MiB):
        //   w+ 0M: Kb  bf16 [2048][1024]                  (4 MiB)
        //   w+ 4M: Vtb bf16 [1024][2048] (V^T)            (4 MiB)
        //   w+ 8M: xb  bf16 [2048][4096] -> AOb (flash)   (16 MiB)
        //   w+24M: wqb bf16 [4096][4096]T -> wob          (32 MiB)
        //   w+56M: wkb bf16 [1024][4096]T                 (8 MiB)
        //   w+64M: wvb bf16 [1024][4096]T                 (8 MiB)
        //   d_out: Qb  bf16 [2048][4096] (dead before out-proj)
        char* w = (char*)d_ws;
        __hip_bfloat16* Kb  = (__hip_bfloat16*)(w);
        __hip_bfloat16* Vtb = (__hip_bfloat16*)(w + (4u  << 20));
        u16*            xb  = (u16*)(w + (8u  << 20));
        __hip_bfloat16* AOb = (__hip_bfloat16*)(w + (8u  << 20));
        u16*            wqb = (u16*)(w + (24u << 20));
        u16*            wob = (u16*)(w + (24u << 20));   // overlays wqb (dead after gemm_qkv)
        u16*            wkb = (u16*)(w + (56u << 20));
        u16*            wvb = (u16*)(w + (64u << 20));
        __hip_bfloat16* Qb  = (__hip_bfloat16*)d_out;

        // 1. wq/wk/wv transposed + x linear -> bf16 (ONE dispatch)
        tconv4<<<dim3(64, 64, 4), blk, 0, stream>>>(wq, wk, wv, x, wqb, wkb, wvb, xb);
        // 2. Fused QKV projection (768 blocks, 3/CU)
        gemm_qkv<<<768, blk, 0, stream>>>(xb, wqb, wkb, wvb, Qb, Kb, Vtb);
        // 3. RoPE on Q and K
        rope_tok<<<M, blk, 0, stream>>>(Qb, Kb, start_pos);
        // 4. Flash attention + wo transpose (ONE dispatch; wqb dead -> wob ok)
        flash_fused<<<5120, blk, 0, stream>>>(Qb, Kb, Vtb, AOb, wo, wob);
        // 5. Output projection -> fp32 out (Qb dead)
        gemm_bf16<float, false, false>
            <<<dim3(D_ / 128, M / 128, 1), blk, 0, stream>>>((const u16*)AOb, wob, out, nullptr, nullptr, M, D_, NQ);
    } else if (ws_size >= NEED_B) {
        // Tier B — R6-verified path, verbatim.
        char* w = (char*)d_ws;
        __hip_bfloat16* Kb  = (__hip_bfloat16*)(w);
        __hip_bfloat16* Vtb = (__hip_bfloat16*)(w + (4u  << 20));
        u16*            xb  = (u16*)(w + (8u  << 20));
        __hip_bfloat16* AOb = (__hip_bfloat16*)(w + (8u  << 20));
        u16*            wS  = (u16*)(w + (24u << 20));
        u16* wqb = wS;
        u16* wkb = wS;
        u16* wvb = wS + (size_t)NKV * D_;
        u16* wob = wS;
        __hip_bfloat16* Qb = (__hip_bfloat16*)d_out;

        lconv<<<(M * D_ / 8 + 255) / 256, blk, 0, stream>>>(x, xb, M * D_ / 8);
        tconv<false><<<dim3(NQ / 64, D_ / 64, 1), blk, 0, stream>>>(wq, wqb, nullptr, nullptr, D_, NQ);
        gemm_bf16<__hip_bfloat16, false, false>
            <<<dim3(NQ / 128, M / 128, 1), blk, 0, stream>>>(xb, wqb, Qb, nullptr, nullptr, M, NQ, D_);
        tconv<true><<<dim3(NKV / 64, D_ / 64, 2), blk, 0, stream>>>(wk, wkb, wv, wvb, D_, NKV);
        gemm_bf16<__hip_bfloat16, true, true>
            <<<dim3(NKV / 128, M / 128, 2), blk, 0, stream>>>(xb, wkb, Kb, wvb, Vtb, M, NKV, D_);
        rope_tok<<<M, blk, 0, stream>>>(Qb, Kb, start_pos);
        tconv<false><<<dim3(NQ / 64, NQ / 64, 1), blk, 0, stream>>>(wo, wob, nullptr, nullptr, NQ, D_);
        flash_attn<__hip_bfloat16><<<dim3(T_ / 64, H_, B_), blk, 0, stream>>>(Qb, Kb, Vtb, AOb);
        gemm_bf16<float, false, false>
            <<<dim3(D_ / 128, M / 128, 1), blk, 0, stream>>>((const u16*)AOb, wob, out, nullptr, nullptr, M, D_, NQ);
    } else {
        // ------- legacy fallback (24 MiB ws) -------
        float* Qf           = out;
        __hip_bfloat16* Kb  = (__hip_bfloat16*)d_ws;
        __hip_bfloat16* Vtb = Kb + (size_t)B_ * T_ * KVH_ * HD_;
        __hip_bfloat16* AOb = Vtb + (size_t)B_ * T_ * KVH_ * HD_;

        gemm_mfma<float, float, float, false, false>
            <<<dim3(NQ / 128, M / 128, 1), blk, 0, stream>>>(x, wq, Qf, nullptr, nullptr, M, NQ, D_);
        gemm_mfma<float, float, __hip_bfloat16, true, true>
            <<<dim3(NKV / 128, M / 128, 2), blk, 0, stream>>>(x, wk, Kb, wv, Vtb, M, NKV, D_);
        rope_kernel<<<(M * (H_ + KVH_)) / 4, blk, 0, stream>>>(Qf, Kb, start_pos);
        flash_attn<float><<<dim3(T_ / 64, H_, B_), blk, 0, stream>>>(Qf, Kb, Vtb, AOb);
        gemm_mfma<__hip_bfloat16, float, float, false, false>
            <<<dim3(D_ / 128, M / 128, 1), blk, 0, stream>>>(AOb, wo, out, nullptr, nullptr, M, D_, NQ);
    }
}